// Round 2
// baseline (5460.959 us; speedup 1.0000x reference)
//
#include <hip/hip_runtime.h>

#define B_  2
#define S_  2048
#define D_  1024
#define H_  16
#define KV_ 8
#define HD_ 128
#define FF_ 3072

typedef short bf16x8 __attribute__((ext_vector_type(8)));
typedef float f32x4 __attribute__((ext_vector_type(4)));

__device__ __forceinline__ float bf2f(unsigned short u) {
    union { float f; unsigned int i; } c; c.i = ((unsigned int)u) << 16; return c.f;
}
__device__ __forceinline__ unsigned short f2bf(float f) {
    union { float f; unsigned int i; } c; c.f = f;
    unsigned int r = c.i + 0x7fffu + ((c.i >> 16) & 1u);
    return (unsigned short)(r >> 16);
}

// ---------------- rmsnorm: fp32 in -> bf16 out, D=1024, one block per row ----------------
__global__ __launch_bounds__(256)
void rmsnorm_kernel(const float* __restrict__ in, const float* __restrict__ scale,
                    unsigned short* __restrict__ out) {
    const int row = blockIdx.x;
    const int t = threadIdx.x;
    const float4 v = *reinterpret_cast<const float4*>(in + (size_t)row * D_ + t * 4);
    float s = v.x * v.x + v.y * v.y + v.z * v.z + v.w * v.w;
    #pragma unroll
    for (int o = 32; o; o >>= 1) s += __shfl_down(s, o);
    __shared__ float red[4];
    const int lane = t & 63, wid = t >> 6;
    if (lane == 0) red[wid] = s;
    __syncthreads();
    s = red[0] + red[1] + red[2] + red[3];
    const float rn = rsqrtf(s * (1.0f / D_) + 1e-6f);
    const float4 sc = *reinterpret_cast<const float4*>(scale + t * 4);
    unsigned short o4[4];
    o4[0] = f2bf(v.x * rn * sc.x);
    o4[1] = f2bf(v.y * rn * sc.y);
    o4[2] = f2bf(v.z * rn * sc.z);
    o4[3] = f2bf(v.w * rn * sc.w);
    *reinterpret_cast<ushort4*>(out + (size_t)row * D_ + t * 4) =
        *reinterpret_cast<ushort4*>(o4);
}

// ---------------- GEMM: C[M,N] = A(bf16)[M,K] @ B(fp32->bf16)[K,N] ----------------
// EPI 0: store bf16.  EPI 1: store fp32 = resid(fp32) + acc.
template<int EPI>
__global__ __launch_bounds__(256)
void gemm_kernel(const unsigned short* __restrict__ A, const float* __restrict__ B,
                 void* __restrict__ Cout, const float* __restrict__ resid,
                 int M, int N, int K) {
    __shared__ __align__(16) unsigned short As[64][40];  // [m][k]
    __shared__ __align__(16) unsigned short Bs[64][40];  // [n][k] (transposed)
    const int t = threadIdx.x;
    const int m0 = blockIdx.x * 64, n0 = blockIdx.y * 64;
    const int lane = t & 63, wid = t >> 6;
    const int wr = wid >> 1, wc = wid & 1;
    const int lm = lane & 15, lg = lane >> 4;

    f32x4 acc[2][2];
    #pragma unroll
    for (int i = 0; i < 2; i++)
        #pragma unroll
        for (int j = 0; j < 2; j++) acc[i][j] = (f32x4){0.f, 0.f, 0.f, 0.f};

    const int ar = t >> 2, ac = (t & 3) * 8;   // A tile: 64 rows x 32 k
    const int bk = t >> 3, bn = (t & 7) * 8;   // B tile: 32 k x 64 n

    for (int k0 = 0; k0 < K; k0 += 32) {
        uint4 av = *reinterpret_cast<const uint4*>(A + (size_t)(m0 + ar) * K + k0 + ac);
        *reinterpret_cast<uint4*>(&As[ar][ac]) = av;
        const float* bp = B + (size_t)(k0 + bk) * N + n0 + bn;
        float4 b0 = *reinterpret_cast<const float4*>(bp);
        float4 b1 = *reinterpret_cast<const float4*>(bp + 4);
        Bs[bn + 0][bk] = f2bf(b0.x); Bs[bn + 1][bk] = f2bf(b0.y);
        Bs[bn + 2][bk] = f2bf(b0.z); Bs[bn + 3][bk] = f2bf(b0.w);
        Bs[bn + 4][bk] = f2bf(b1.x); Bs[bn + 5][bk] = f2bf(b1.y);
        Bs[bn + 6][bk] = f2bf(b1.z); Bs[bn + 7][bk] = f2bf(b1.w);
        __syncthreads();
        bf16x8 aF[2], bF[2];
        #pragma unroll
        for (int i = 0; i < 2; i++)
            aF[i] = *reinterpret_cast<const bf16x8*>(&As[wr * 32 + i * 16 + lm][lg * 8]);
        #pragma unroll
        for (int j = 0; j < 2; j++)
            bF[j] = *reinterpret_cast<const bf16x8*>(&Bs[wc * 32 + j * 16 + lm][lg * 8]);
        #pragma unroll
        for (int i = 0; i < 2; i++)
            #pragma unroll
            for (int j = 0; j < 2; j++)
                acc[i][j] = __builtin_amdgcn_mfma_f32_16x16x32_bf16(aF[i], bF[j], acc[i][j], 0, 0, 0);
        __syncthreads();
    }

    #pragma unroll
    for (int i = 0; i < 2; i++) {
        #pragma unroll
        for (int j = 0; j < 2; j++) {
            #pragma unroll
            for (int r = 0; r < 4; r++) {
                const int row = m0 + wr * 32 + i * 16 + lg * 4 + r;
                const int col = n0 + wc * 32 + j * 16 + lm;
                const size_t idx = (size_t)row * N + col;
                if (EPI == 0) {
                    reinterpret_cast<unsigned short*>(Cout)[idx] = f2bf(acc[i][j][r]);
                } else {
                    reinterpret_cast<float*>(Cout)[idx] = resid[idx] + acc[i][j][r];
                }
            }
        }
    }
}

// ---------------- per-head rmsnorm + rope, in-place on bf16 q/k ----------------
__global__ __launch_bounds__(128)
void qknorm_rope_kernel(unsigned short* __restrict__ qk, const float* __restrict__ scale,
                        const float* __restrict__ cosb, const float* __restrict__ sinb,
                        int nheads) {
    const int row = blockIdx.x;            // b*S + s
    const int head = blockIdx.y;
    const int s = row & (S_ - 1);
    const int t = threadIdx.x;             // 0..127
    unsigned short* p = qk + ((size_t)row * nheads + head) * HD_;
    const float v = bf2f(p[t]);
    float ss = v * v;
    #pragma unroll
    for (int o = 32; o; o >>= 1) ss += __shfl_down(ss, o);
    __shared__ float red[2];
    __shared__ float vals[HD_];
    const int lane = t & 63, wid = t >> 6;
    if (lane == 0) red[wid] = ss;
    __syncthreads();
    ss = red[0] + red[1];
    const float rn = rsqrtf(ss * (1.0f / HD_) + 1e-6f);
    const float nv = v * rn * scale[t];
    vals[t] = nv;
    __syncthreads();
    const float rot = (t < 64) ? -vals[t + 64] : vals[t - 64];
    const float c = cosb[(size_t)s * HD_ + t];
    const float sn = sinb[(size_t)s * HD_ + t];
    p[t] = f2bf(nv * c + rot * sn);
}

// ---------------- causal GQA attention: one wave per q-row, online softmax ----------------
__global__ __launch_bounds__(256)
void attn_kernel(const unsigned short* __restrict__ q, const unsigned short* __restrict__ k,
                 const unsigned short* __restrict__ v, unsigned short* __restrict__ ctx) {
    const int t = threadIdx.x;
    const int lane = t & 63, wid = t >> 6;
    const int qt = blockIdx.x, h = blockIdx.y, b = blockIdx.z;
    const int qrow = qt * 4 + wid;
    const int d0 = lane * 2;
    const float qscale = 0.08838834764831845f;  // 1/sqrt(128)
    const unsigned short* qp = q + ((size_t)(b * S_ + qrow) * H_ + h) * HD_ + d0;
    const unsigned int qu = *reinterpret_cast<const unsigned int*>(qp);
    const float q0 = bf2f((unsigned short)(qu & 0xffff)) * qscale;
    const float q1 = bf2f((unsigned short)(qu >> 16)) * qscale;
    const size_t kvstride = (size_t)KV_ * HD_;
    const unsigned short* kb = k + (size_t)b * S_ * kvstride + (size_t)(h >> 1) * HD_ + d0;
    const unsigned short* vb = v + (size_t)b * S_ * kvstride + (size_t)(h >> 1) * HD_ + d0;
    float m = -1e30f, l = 0.f, o0 = 0.f, o1 = 0.f;
    for (int tk = 0; tk <= qrow; ++tk) {
        const unsigned int ku = *reinterpret_cast<const unsigned int*>(kb + (size_t)tk * kvstride);
        float dot = q0 * bf2f((unsigned short)(ku & 0xffff)) +
                    q1 * bf2f((unsigned short)(ku >> 16));
        #pragma unroll
        for (int o = 32; o; o >>= 1) dot += __shfl_xor(dot, o);
        const float mn = fmaxf(m, dot);
        const float corr = __expf(m - mn);
        const float p = __expf(dot - mn);
        const unsigned int vu = *reinterpret_cast<const unsigned int*>(vb + (size_t)tk * kvstride);
        l = l * corr + p;
        o0 = o0 * corr + p * bf2f((unsigned short)(vu & 0xffff));
        o1 = o1 * corr + p * bf2f((unsigned short)(vu >> 16));
        m = mn;
    }
    const float inv = 1.0f / l;
    const unsigned short r0 = f2bf(o0 * inv), r1 = f2bf(o1 * inv);
    const unsigned int ru = ((unsigned int)r1 << 16) | (unsigned int)r0;
    *reinterpret_cast<unsigned int*>(ctx + ((size_t)(b * S_ + qrow) * H_ + h) * HD_ + d0) = ru;
}

// ---------------- silu(g1) * g2 -> g1 (bf16, in place) ----------------
__global__ __launch_bounds__(256)
void silu_mul_kernel(unsigned short* __restrict__ g1, const unsigned short* __restrict__ g2, int n4) {
    const int i = blockIdx.x * 256 + threadIdx.x;
    if (i >= n4) return;
    const uint2 a = reinterpret_cast<const uint2*>(g1)[i];
    const uint2 bv = reinterpret_cast<const uint2*>(g2)[i];
    const unsigned int au[2] = {a.x, a.y}, bu[2] = {bv.x, bv.y};
    unsigned int r[2];
    #pragma unroll
    for (int j = 0; j < 2; j++) {
        const float a0 = bf2f((unsigned short)(au[j] & 0xffff));
        const float a1 = bf2f((unsigned short)(au[j] >> 16));
        const float b0 = bf2f((unsigned short)(bu[j] & 0xffff));
        const float b1 = bf2f((unsigned short)(bu[j] >> 16));
        const float s0 = a0 / (1.f + __expf(-a0)) * b0;
        const float s1 = a1 / (1.f + __expf(-a1)) * b1;
        r[j] = ((unsigned int)f2bf(s1) << 16) | (unsigned int)f2bf(s0);
    }
    reinterpret_cast<uint2*>(g1)[i] = make_uint2(r[0], r[1]);
}

extern "C" void kernel_launch(void* const* d_in, const int* in_sizes, int n_in,
                              void* d_out, int out_size, void* d_ws, size_t ws_size,
                              hipStream_t stream) {
    const float* x    = (const float*)d_in[0];
    // d_in[1] = mask (causal, known analytically; ignored)
    const float* cosb = (const float*)d_in[2];
    const float* sinb = (const float*)d_in[3];
    const float* wq   = (const float*)d_in[4];
    const float* wk   = (const float*)d_in[5];
    const float* wv   = (const float*)d_in[6];
    const float* wo   = (const float*)d_in[7];
    const float* fc1  = (const float*)d_in[8];
    const float* fc2  = (const float*)d_in[9];
    const float* fc3  = (const float*)d_in[10];
    const float* n1s  = (const float*)d_in[11];
    const float* n2s  = (const float*)d_in[12];
    const float* qns  = (const float*)d_in[13];
    const float* kns  = (const float*)d_in[14];

    char* ws = (char*)d_ws;
    const int M = B_ * S_;  // 4096
    // ws layout (bytes):
    //   h   @ 0         :  8,388,608  (bf16 4096x1024) -- reused as h2
    //   q   @ 8388608   : 16,777,216  (bf16 4096x2048) -- reused as ctx (in-place), then g1
    //   k   @ 25165824  :  8,388,608  (bf16 4096x1024) -- tail of g1 alias
    //   v   @ 33554432  :  8,388,608  (bf16 4096x1024)
    //   x2  @ 41943040  : 16,777,216  (fp32 4096x1024)
    //   g2  @ 58720256  : 25,165,824  (bf16 4096x3072)   total = 83,886,080
    unsigned short* h  = (unsigned short*)(ws);
    unsigned short* qb = (unsigned short*)(ws + 8388608);
    unsigned short* kb = (unsigned short*)(ws + 25165824);
    unsigned short* vb = (unsigned short*)(ws + 33554432);
    float*          x2 = (float*)(ws + 41943040);
    unsigned short* g1 = (unsigned short*)(ws + 8388608);   // alias q+k (dead by then)
    unsigned short* g2 = (unsigned short*)(ws + 58720256);
    float* outf = (float*)d_out;

    rmsnorm_kernel<<<M, 256, 0, stream>>>(x, n1s, h);
    gemm_kernel<0><<<dim3(M / 64, (H_ * HD_) / 64), 256, 0, stream>>>(h, wq, qb, nullptr, M, H_ * HD_, D_);
    gemm_kernel<0><<<dim3(M / 64, (KV_ * HD_) / 64), 256, 0, stream>>>(h, wk, kb, nullptr, M, KV_ * HD_, D_);
    gemm_kernel<0><<<dim3(M / 64, (KV_ * HD_) / 64), 256, 0, stream>>>(h, wv, vb, nullptr, M, KV_ * HD_, D_);
    qknorm_rope_kernel<<<dim3(M, H_), 128, 0, stream>>>(qb, qns, cosb, sinb, H_);
    qknorm_rope_kernel<<<dim3(M, KV_), 128, 0, stream>>>(kb, kns, cosb, sinb, KV_);
    attn_kernel<<<dim3(S_ / 4, H_, B_), 256, 0, stream>>>(qb, kb, vb, qb /*ctx in-place*/);
    gemm_kernel<1><<<dim3(M / 64, D_ / 64), 256, 0, stream>>>(qb, wo, x2, x, M, D_, H_ * HD_);
    rmsnorm_kernel<<<M, 256, 0, stream>>>(x2, n2s, h);
    gemm_kernel<0><<<dim3(M / 64, FF_ / 64), 256, 0, stream>>>(h, fc1, g1, nullptr, M, FF_, D_);
    gemm_kernel<0><<<dim3(M / 64, FF_ / 64), 256, 0, stream>>>(h, fc2, g2, nullptr, M, FF_, D_);
    silu_mul_kernel<<<(M * FF_ / 4 + 255) / 256, 256, 0, stream>>>(g1, g2, M * FF_ / 4);
    gemm_kernel<1><<<dim3(M / 64, D_ / 64), 256, 0, stream>>>(g1, fc3, outf, x2, M, D_, FF_);
}

// Round 3
// 921.006 us; speedup vs baseline: 5.9293x; 5.9293x over previous
//
#include <hip/hip_runtime.h>

#define B_  2
#define S_  2048
#define D_  1024
#define H_  16
#define KV_ 8
#define HD_ 128
#define FF_ 3072
#define KVB 32

typedef short bf16x8 __attribute__((ext_vector_type(8)));
typedef short bf16x4 __attribute__((ext_vector_type(4)));
typedef float f32x4 __attribute__((ext_vector_type(4)));

__device__ __forceinline__ float bf2f(unsigned short u) {
    union { float f; unsigned int i; } c; c.i = ((unsigned int)u) << 16; return c.f;
}
__device__ __forceinline__ unsigned short f2bf(float f) {
    union { float f; unsigned int i; } c; c.f = f;
    unsigned int r = c.i + 0x7fffu + ((c.i >> 16) & 1u);
    return (unsigned short)(r >> 16);
}

__device__ __forceinline__ f32x4 pv_mfma(bf16x4 a, bf16x4 b, f32x4 c) {
#if __has_builtin(__builtin_amdgcn_mfma_f32_16x16x16bf16_1k)
    return __builtin_amdgcn_mfma_f32_16x16x16bf16_1k(a, b, c, 0, 0, 0);
#elif __has_builtin(__builtin_amdgcn_mfma_f32_16x16x16_bf16)
    return __builtin_amdgcn_mfma_f32_16x16x16_bf16(a, b, c, 0, 0, 0);
#else
    f32x4 d;
    asm("v_mfma_f32_16x16x16_bf16 %0, %1, %2, %3" : "=v"(d) : "v"(a), "v"(b), "v"(c));
    return d;
#endif
}

// ---------------- rmsnorm: fp32 in -> bf16 out, D=1024, one block per row ----------------
__global__ __launch_bounds__(256)
void rmsnorm_kernel(const float* __restrict__ in, const float* __restrict__ scale,
                    unsigned short* __restrict__ out) {
    const int row = blockIdx.x;
    const int t = threadIdx.x;
    const float4 v = *reinterpret_cast<const float4*>(in + (size_t)row * D_ + t * 4);
    float s = v.x * v.x + v.y * v.y + v.z * v.z + v.w * v.w;
    #pragma unroll
    for (int o = 32; o; o >>= 1) s += __shfl_down(s, o);
    __shared__ float red[4];
    const int lane = t & 63, wid = t >> 6;
    if (lane == 0) red[wid] = s;
    __syncthreads();
    s = red[0] + red[1] + red[2] + red[3];
    const float rn = rsqrtf(s * (1.0f / D_) + 1e-6f);
    const float4 sc = *reinterpret_cast<const float4*>(scale + t * 4);
    unsigned short o4[4];
    o4[0] = f2bf(v.x * rn * sc.x);
    o4[1] = f2bf(v.y * rn * sc.y);
    o4[2] = f2bf(v.z * rn * sc.z);
    o4[3] = f2bf(v.w * rn * sc.w);
    *reinterpret_cast<ushort4*>(out + (size_t)row * D_ + t * 4) =
        *reinterpret_cast<ushort4*>(o4);
}

// ---------------- GEMM: C[M,N] = A(bf16)[M,K] @ B(fp32->bf16)[K,N] ----------------
// EPI 0: store bf16.  EPI 1: store fp32 = resid + acc.  EPI 2: store bf16 TRANSPOSED [N][M].
template<int EPI>
__global__ __launch_bounds__(256)
void gemm_kernel(const unsigned short* __restrict__ A, const float* __restrict__ B,
                 void* __restrict__ Cout, const float* __restrict__ resid,
                 int M, int N, int K) {
    __shared__ __align__(16) unsigned short sm[5120];
    unsigned short (*As)[40] = reinterpret_cast<unsigned short(*)[40]>(sm);
    unsigned short (*Bs)[40] = reinterpret_cast<unsigned short(*)[40]>(sm + 2560);
    const int t = threadIdx.x;
    const int m0 = blockIdx.x * 64, n0 = blockIdx.y * 64;
    const int lane = t & 63, wid = t >> 6;
    const int wr = wid >> 1, wc = wid & 1;
    const int lm = lane & 15, lg = lane >> 4;

    f32x4 acc[2][2];
    #pragma unroll
    for (int i = 0; i < 2; i++)
        #pragma unroll
        for (int j = 0; j < 2; j++) acc[i][j] = (f32x4){0.f, 0.f, 0.f, 0.f};

    const int ar = t >> 2, ac = (t & 3) * 8;   // A tile: 64 rows x 32 k
    const int bk = t >> 3, bn = (t & 7) * 8;   // B tile: 32 k x 64 n

    for (int k0 = 0; k0 < K; k0 += 32) {
        uint4 av = *reinterpret_cast<const uint4*>(A + (size_t)(m0 + ar) * K + k0 + ac);
        *reinterpret_cast<uint4*>(&As[ar][ac]) = av;
        const float* bp = B + (size_t)(k0 + bk) * N + n0 + bn;
        float4 b0 = *reinterpret_cast<const float4*>(bp);
        float4 b1 = *reinterpret_cast<const float4*>(bp + 4);
        Bs[bn + 0][bk] = f2bf(b0.x); Bs[bn + 1][bk] = f2bf(b0.y);
        Bs[bn + 2][bk] = f2bf(b0.z); Bs[bn + 3][bk] = f2bf(b0.w);
        Bs[bn + 4][bk] = f2bf(b1.x); Bs[bn + 5][bk] = f2bf(b1.y);
        Bs[bn + 6][bk] = f2bf(b1.z); Bs[bn + 7][bk] = f2bf(b1.w);
        __syncthreads();
        bf16x8 aF[2], bF[2];
        #pragma unroll
        for (int i = 0; i < 2; i++)
            aF[i] = *reinterpret_cast<const bf16x8*>(&As[wr * 32 + i * 16 + lm][lg * 8]);
        #pragma unroll
        for (int j = 0; j < 2; j++)
            bF[j] = *reinterpret_cast<const bf16x8*>(&Bs[wc * 32 + j * 16 + lm][lg * 8]);
        #pragma unroll
        for (int i = 0; i < 2; i++)
            #pragma unroll
            for (int j = 0; j < 2; j++)
                acc[i][j] = __builtin_amdgcn_mfma_f32_16x16x32_bf16(aF[i], bF[j], acc[i][j], 0, 0, 0);
        __syncthreads();
    }

    if (EPI == 2) {
        // transpose via LDS, then coalesced store to Cout[N][M]
        unsigned short (*Ct)[72] = reinterpret_cast<unsigned short(*)[72]>(sm);
        #pragma unroll
        for (int i = 0; i < 2; i++)
            #pragma unroll
            for (int j = 0; j < 2; j++)
                #pragma unroll
                for (int r = 0; r < 4; r++)
                    Ct[wc * 32 + j * 16 + lm][wr * 32 + i * 16 + lg * 4 + r] = f2bf(acc[i][j][r]);
        __syncthreads();
        const int col = t >> 2, seg = t & 3;
        unsigned short* dst = reinterpret_cast<unsigned short*>(Cout) +
                              (size_t)(n0 + col) * M + m0 + seg * 16;
        const uint4 c0 = *reinterpret_cast<const uint4*>(&Ct[col][seg * 16]);
        const uint4 c1 = *reinterpret_cast<const uint4*>(&Ct[col][seg * 16 + 8]);
        *reinterpret_cast<uint4*>(dst) = c0;
        *reinterpret_cast<uint4*>(dst + 8) = c1;
        return;
    }

    #pragma unroll
    for (int i = 0; i < 2; i++) {
        #pragma unroll
        for (int j = 0; j < 2; j++) {
            #pragma unroll
            for (int r = 0; r < 4; r++) {
                const int row = m0 + wr * 32 + i * 16 + lg * 4 + r;
                const int col = n0 + wc * 32 + j * 16 + lm;
                const size_t idx = (size_t)row * N + col;
                if (EPI == 0) {
                    reinterpret_cast<unsigned short*>(Cout)[idx] = f2bf(acc[i][j][r]);
                } else {
                    reinterpret_cast<float*>(Cout)[idx] = resid[idx] + acc[i][j][r];
                }
            }
        }
    }
}

// ---------------- per-head rmsnorm + rope, in-place on bf16 q/k ----------------
__global__ __launch_bounds__(128)
void qknorm_rope_kernel(unsigned short* __restrict__ qk, const float* __restrict__ scale,
                        const float* __restrict__ cosb, const float* __restrict__ sinb,
                        int nheads) {
    const int row = blockIdx.x;            // b*S + s
    const int head = blockIdx.y;
    const int s = row & (S_ - 1);
    const int t = threadIdx.x;             // 0..127
    unsigned short* p = qk + ((size_t)row * nheads + head) * HD_;
    const float v = bf2f(p[t]);
    float ss = v * v;
    #pragma unroll
    for (int o = 32; o; o >>= 1) ss += __shfl_down(ss, o);
    __shared__ float red[2];
    __shared__ float vals[HD_];
    const int lane = t & 63, wid = t >> 6;
    if (lane == 0) red[wid] = ss;
    __syncthreads();
    ss = red[0] + red[1];
    const float rn = rsqrtf(ss * (1.0f / HD_) + 1e-6f);
    const float nv = v * rn * scale[t];
    vals[t] = nv;
    __syncthreads();
    const float rot = (t < 64) ? -vals[t + 64] : vals[t - 64];
    const float c = cosb[(size_t)s * HD_ + t];
    const float sn = sinb[(size_t)s * HD_ + t];
    p[t] = f2bf(nv * c + rot * sn);
}

// ---------------- MFMA flash attention (swapped QK^T), causal GQA ----------------
// 4 waves/block, 16 q-rows/wave, KVB=32 kv per tile. V consumed from V^T [d][b][s].
__global__ __launch_bounds__(256)
void fattn_kernel(const unsigned short* __restrict__ qg,
                  const unsigned short* __restrict__ kg,
                  const unsigned short* __restrict__ vtg,
                  unsigned short* __restrict__ out) {
    __shared__ __align__(16) unsigned short klds[KVB * 128];   // [kv][128] xor-swizzled
    __shared__ __align__(16) unsigned short vtlds[128 * 40];   // [d][kv] pad 40
    const int t = threadIdx.x;
    const int lane = t & 63, w = t >> 6;
    const int lm = lane & 15, lg = lane >> 4;
    const int qt = blockIdx.x, h = blockIdx.y, b = blockIdx.z;
    const int kvh = h >> 1;
    const int q0b = qt * 64;
    const int q0w = q0b + w * 16;
    const float CS = 0.12752409731504826f;   // (1/sqrt(128)) * log2(e)

    const unsigned short* qbase = qg + ((size_t)(b * S_ + q0w + lm) * H_ + h) * HD_;
    bf16x8 qf[4];
    #pragma unroll
    for (int kk = 0; kk < 4; ++kk)
        qf[kk] = *reinterpret_cast<const bf16x8*>(qbase + kk * 32 + lg * 8);

    f32x4 acc[8];
    #pragma unroll
    for (int i = 0; i < 8; ++i) acc[i] = (f32x4){0.f, 0.f, 0.f, 0.f};
    float m = -3e38f, l = 0.f;

    const int nt = (q0b + 64) >> 5;
    const int skv = t >> 3, sd8 = t & 7;   // K staging: row skv, 32B at sd8*16
    const int vd = t >> 1, vseg = t & 1;   // VT staging: d row vd, 16 kv at vseg*16
    const unsigned short* kgb = kg + ((size_t)b * S_ * KV_ + kvh) * HD_;
    const unsigned short* vgb = vtg + (size_t)(kvh * HD_) * (B_ * S_) + (size_t)b * S_;

    for (int kt = 0; kt < nt; ++kt) {
        const int kv0 = kt * KVB;
        {   // stage K tile (xor-swizzled rows)
            const unsigned short* src = kgb + (size_t)(kv0 + skv) * (KV_ * HD_) + sd8 * 16;
            const uint4 a0 = *reinterpret_cast<const uint4*>(src);
            const uint4 a1 = *reinterpret_cast<const uint4*>(src + 8);
            char* dst = reinterpret_cast<char*>(klds) + skv * 256;
            const int sw = (skv & 7) << 4;
            *reinterpret_cast<uint4*>(dst + ((sd8 * 32) ^ sw)) = a0;
            *reinterpret_cast<uint4*>(dst + ((sd8 * 32 + 16) ^ sw)) = a1;
        }
        {   // stage V^T tile
            const unsigned short* src = vgb + (size_t)vd * (B_ * S_) + kv0 + vseg * 16;
            const uint4 a0 = *reinterpret_cast<const uint4*>(src);
            const uint4 a1 = *reinterpret_cast<const uint4*>(src + 8);
            char* dst = reinterpret_cast<char*>(vtlds) + vd * 80 + vseg * 32;
            *reinterpret_cast<uint4*>(dst) = a0;
            *reinterpret_cast<uint4*>(dst + 16) = a1;
        }
        __syncthreads();
        if (kv0 <= q0w + 15) {
            f32x4 st[2];
            st[0] = (f32x4){0.f, 0.f, 0.f, 0.f};
            st[1] = (f32x4){0.f, 0.f, 0.f, 0.f};
            #pragma unroll
            for (int sub = 0; sub < 2; ++sub) {
                const int kvl = sub * 16 + lm;
                const char* krow = reinterpret_cast<const char*>(klds) + kvl * 256;
                const int sw = (kvl & 7) << 4;
                #pragma unroll
                for (int kk = 0; kk < 4; ++kk) {
                    const bf16x8 kf = *reinterpret_cast<const bf16x8*>(krow + ((kk * 64 + lg * 16) ^ sw));
                    st[sub] = __builtin_amdgcn_mfma_f32_16x16x32_bf16(kf, qf[kk], st[sub], 0, 0, 0);
                }
            }
            if (kv0 + KVB - 1 > q0w) {   // diagonal tile: causal mask (kv > q)
                const int qa = q0w + lm;
                #pragma unroll
                for (int sub = 0; sub < 2; ++sub)
                    #pragma unroll
                    for (int r = 0; r < 4; ++r)
                        if (kv0 + sub * 16 + lg * 4 + r > qa) st[sub][r] = -3e38f;
            }
            float pmax = st[0][0];
            #pragma unroll
            for (int r = 1; r < 4; ++r) pmax = fmaxf(pmax, st[0][r]);
            #pragma unroll
            for (int r = 0; r < 4; ++r) pmax = fmaxf(pmax, st[1][r]);
            pmax = fmaxf(pmax, __shfl_xor(pmax, 16));
            pmax = fmaxf(pmax, __shfl_xor(pmax, 32));
            if (__any(pmax - m > 8.0f)) {   // defer-max (T13): rescale only on real growth
                const float mn = fmaxf(pmax, m);
                const float corr = exp2f((m - mn) * CS);
                l *= corr;
                #pragma unroll
                for (int i = 0; i < 8; ++i) acc[i] *= corr;
                m = mn;
            }
            float ps = 0.f;
            bf16x4 pb[2];
            #pragma unroll
            for (int sub = 0; sub < 2; ++sub)
                #pragma unroll
                for (int r = 0; r < 4; ++r) {
                    const float pv = exp2f((st[sub][r] - m) * CS);
                    ps += pv;
                    pb[sub][r] = (short)f2bf(pv);
                }
            ps += __shfl_xor(ps, 16);
            ps += __shfl_xor(ps, 32);
            l += ps;
            #pragma unroll
            for (int sub = 0; sub < 2; ++sub) {
                const char* vb2 = reinterpret_cast<const char*>(vtlds) + sub * 32 + lg * 8;
                #pragma unroll
                for (int db = 0; db < 8; ++db) {
                    const bf16x4 vf = *reinterpret_cast<const bf16x4*>(vb2 + (db * 16 + lm) * 80);
                    acc[db] = pv_mfma(vf, pb[sub], acc[db]);
                }
            }
        }
        __syncthreads();
    }
    const float inv = 1.0f / l;
    unsigned short* ob = out + ((size_t)(b * S_ + q0w + lm) * H_ + h) * HD_ + lg * 4;
    #pragma unroll
    for (int db = 0; db < 8; ++db) {
        unsigned short r4[4];
        #pragma unroll
        for (int r = 0; r < 4; ++r) r4[r] = f2bf(acc[db][r] * inv);
        *reinterpret_cast<uint2*>(ob + db * 16) = *reinterpret_cast<uint2*>(r4);
    }
}

// ---------------- silu(g1) * g2 -> g1 (bf16, in place) ----------------
__global__ __launch_bounds__(256)
void silu_mul_kernel(unsigned short* __restrict__ g1, const unsigned short* __restrict__ g2, int n4) {
    const int i = blockIdx.x * 256 + threadIdx.x;
    if (i >= n4) return;
    const uint2 a = reinterpret_cast<const uint2*>(g1)[i];
    const uint2 bv = reinterpret_cast<const uint2*>(g2)[i];
    const unsigned int au[2] = {a.x, a.y}, bu[2] = {bv.x, bv.y};
    unsigned int r[2];
    #pragma unroll
    for (int j = 0; j < 2; j++) {
        const float a0 = bf2f((unsigned short)(au[j] & 0xffff));
        const float a1 = bf2f((unsigned short)(au[j] >> 16));
        const float b0 = bf2f((unsigned short)(bu[j] & 0xffff));
        const float b1 = bf2f((unsigned short)(bu[j] >> 16));
        const float s0 = a0 / (1.f + __expf(-a0)) * b0;
        const float s1 = a1 / (1.f + __expf(-a1)) * b1;
        r[j] = ((unsigned int)f2bf(s1) << 16) | (unsigned int)f2bf(s0);
    }
    reinterpret_cast<uint2*>(g1)[i] = make_uint2(r[0], r[1]);
}

extern "C" void kernel_launch(void* const* d_in, const int* in_sizes, int n_in,
                              void* d_out, int out_size, void* d_ws, size_t ws_size,
                              hipStream_t stream) {
    const float* x    = (const float*)d_in[0];
    const float* cosb = (const float*)d_in[2];
    const float* sinb = (const float*)d_in[3];
    const float* wq   = (const float*)d_in[4];
    const float* wk   = (const float*)d_in[5];
    const float* wv   = (const float*)d_in[6];
    const float* wo   = (const float*)d_in[7];
    const float* fc1  = (const float*)d_in[8];
    const float* fc2  = (const float*)d_in[9];
    const float* fc3  = (const float*)d_in[10];
    const float* n1s  = (const float*)d_in[11];
    const float* n2s  = (const float*)d_in[12];
    const float* qns  = (const float*)d_in[13];
    const float* kns  = (const float*)d_in[14];

    char* ws = (char*)d_ws;
    const int M = B_ * S_;  // 4096
    unsigned short* h  = (unsigned short*)(ws);
    unsigned short* qb = (unsigned short*)(ws + 8388608);
    unsigned short* kb = (unsigned short*)(ws + 25165824);
    unsigned short* vtb = (unsigned short*)(ws + 33554432);  // V^T bf16 [KV*HD][B*S]
    float*          x2 = (float*)(ws + 41943040);
    unsigned short* g1 = (unsigned short*)(ws + 8388608);    // alias q+k (dead by then)
    unsigned short* g2 = (unsigned short*)(ws + 58720256);
    float* outf = (float*)d_out;

    rmsnorm_kernel<<<M, 256, 0, stream>>>(x, n1s, h);
    gemm_kernel<0><<<dim3(M / 64, (H_ * HD_) / 64), 256, 0, stream>>>(h, wq, qb, nullptr, M, H_ * HD_, D_);
    gemm_kernel<0><<<dim3(M / 64, (KV_ * HD_) / 64), 256, 0, stream>>>(h, wk, kb, nullptr, M, KV_ * HD_, D_);
    gemm_kernel<2><<<dim3(M / 64, (KV_ * HD_) / 64), 256, 0, stream>>>(h, wv, vtb, nullptr, M, KV_ * HD_, D_);
    qknorm_rope_kernel<<<dim3(M, H_), 128, 0, stream>>>(qb, qns, cosb, sinb, H_);
    qknorm_rope_kernel<<<dim3(M, KV_), 128, 0, stream>>>(kb, kns, cosb, sinb, KV_);
    fattn_kernel<<<dim3(S_ / 64, H_, B_), 256, 0, stream>>>(qb, kb, vtb, qb /*ctx in-place*/);
    gemm_kernel<1><<<dim3(M / 64, D_ / 64), 256, 0, stream>>>(qb, wo, x2, x, M, D_, H_ * HD_);
    rmsnorm_kernel<<<M, 256, 0, stream>>>(x2, n2s, h);
    gemm_kernel<0><<<dim3(M / 64, FF_ / 64), 256, 0, stream>>>(h, fc1, g1, nullptr, M, FF_, D_);
    gemm_kernel<0><<<dim3(M / 64, FF_ / 64), 256, 0, stream>>>(h, fc2, g2, nullptr, M, FF_, D_);
    silu_mul_kernel<<<(M * FF_ / 4 + 255) / 256, 256, 0, stream>>>(g1, g2, M * FF_ / 4);
    gemm_kernel<1><<<dim3(M / 64, D_ / 64), 256, 0, stream>>>(g1, fc3, outf, x2, M, D_, FF_);
}

// Round 4
// 556.931 us; speedup vs baseline: 9.8054x; 1.6537x over previous
//
#include <hip/hip_runtime.h>

#define B_  2
#define S_  2048
#define D_  1024
#define H_  16
#define KV_ 8
#define HD_ 128
#define FF_ 3072
#define KVB 32

typedef short bf16x8 __attribute__((ext_vector_type(8)));
typedef short bf16x4 __attribute__((ext_vector_type(4)));
typedef float f32x4 __attribute__((ext_vector_type(4)));

__device__ __forceinline__ float bf2f(unsigned short u) {
    union { float f; unsigned int i; } c; c.i = ((unsigned int)u) << 16; return c.f;
}
__device__ __forceinline__ unsigned short f2bf(float f) {
    union { float f; unsigned int i; } c; c.f = f;
    unsigned int r = c.i + 0x7fffu + ((c.i >> 16) & 1u);
    return (unsigned short)(r >> 16);
}

__device__ __forceinline__ void gload_lds16(const unsigned short* g, char* ldsbase) {
    __builtin_amdgcn_global_load_lds(
        (const __attribute__((address_space(1))) unsigned int*)g,
        (__attribute__((address_space(3))) unsigned int*)ldsbase, 16, 0, 0);
}

__device__ __forceinline__ f32x4 pv_mfma(bf16x4 a, bf16x4 b, f32x4 c) {
#if __has_builtin(__builtin_amdgcn_mfma_f32_16x16x16bf16_1k)
    return __builtin_amdgcn_mfma_f32_16x16x16bf16_1k(a, b, c, 0, 0, 0);
#elif __has_builtin(__builtin_amdgcn_mfma_f32_16x16x16_bf16)
    return __builtin_amdgcn_mfma_f32_16x16x16_bf16(a, b, c, 0, 0, 0);
#else
    f32x4 d;
    asm("v_mfma_f32_16x16x16_bf16 %0, %1, %2, %3" : "=v"(d) : "v"(a), "v"(b), "v"(c));
    return d;
#endif
}

// ---------------- rmsnorm: fp32 in -> bf16 out, D=1024, one block per row ----------------
__global__ __launch_bounds__(256)
void rmsnorm_kernel(const float* __restrict__ in, const float* __restrict__ scale,
                    unsigned short* __restrict__ out) {
    const int row = blockIdx.x;
    const int t = threadIdx.x;
    const float4 v = *reinterpret_cast<const float4*>(in + (size_t)row * D_ + t * 4);
    float s = v.x * v.x + v.y * v.y + v.z * v.z + v.w * v.w;
    #pragma unroll
    for (int o = 32; o; o >>= 1) s += __shfl_down(s, o);
    __shared__ float red[4];
    const int lane = t & 63, wid = t >> 6;
    if (lane == 0) red[wid] = s;
    __syncthreads();
    s = red[0] + red[1] + red[2] + red[3];
    const float rn = rsqrtf(s * (1.0f / D_) + 1e-6f);
    const float4 sc = *reinterpret_cast<const float4*>(scale + t * 4);
    unsigned short o4[4];
    o4[0] = f2bf(v.x * rn * sc.x);
    o4[1] = f2bf(v.y * rn * sc.y);
    o4[2] = f2bf(v.z * rn * sc.z);
    o4[3] = f2bf(v.w * rn * sc.w);
    *reinterpret_cast<ushort4*>(out + (size_t)row * D_ + t * 4) =
        *reinterpret_cast<ushort4*>(o4);
}

// ---------------- weight convert+transpose: W[K][N] fp32 -> Wt[N][K] bf16 ----------------
__global__ __launch_bounds__(256)
void wtrans_kernel(const float* __restrict__ W, unsigned short* __restrict__ Wt,
                   int K, int N) {
    __shared__ float tile[32][33];
    const int t = threadIdx.x;
    const int kt = blockIdx.x * 32, nt = blockIdx.y * 32;
    {
        const int r = t >> 3, c4 = (t & 7) * 4;
        const float4 v = *reinterpret_cast<const float4*>(W + (size_t)(kt + r) * N + nt + c4);
        tile[r][c4] = v.x; tile[r][c4 + 1] = v.y; tile[r][c4 + 2] = v.z; tile[r][c4 + 3] = v.w;
    }
    __syncthreads();
    {
        const int n = t >> 3, k4 = (t & 7) * 4;
        unsigned short o[4];
        #pragma unroll
        for (int i = 0; i < 4; i++) o[i] = f2bf(tile[k4 + i][n]);
        *reinterpret_cast<ushort4*>(Wt + (size_t)(nt + n) * K + kt + k4) =
            *reinterpret_cast<ushort4*>(o);
    }
}

// ---------------- m97-structure GEMM: C[M,N] = A(bf16 [M][K]) @ Bt(bf16 [N][K])^T --------
// 128x128 tile, BK=32, 4 waves, 4x4 frags/wave, global_load_lds(16B) staging.
// EPI 0: bf16 C.  EPI 1: fp32 C = resid + acc.  EPI 2: bf16 C TRANSPOSED [N][M].
template<int EPI>
__global__ __launch_bounds__(256)
void gemm_bt(const unsigned short* __restrict__ A, const unsigned short* __restrict__ Bt,
             void* __restrict__ Cout, const float* __restrict__ resid,
             int M, int N, int K) {
    constexpr int SMB = (EPI == 2) ? 34816 : 16384;
    __shared__ __align__(16) char sm[SMB];
    const int t = threadIdx.x;
    const int lane = t & 63, w = t >> 6;
    const int m0 = blockIdx.x * 128, n0 = blockIdx.y * 128;
    const int wr = w >> 1, wc = w & 1;
    const int lm = lane & 15, lg = lane >> 4;

    f32x4 acc[4][4];
    #pragma unroll
    for (int i = 0; i < 4; i++)
        #pragma unroll
        for (int j = 0; j < 4; j++) acc[i][j] = (f32x4){0.f, 0.f, 0.f, 0.f};

    // staging: chunk c covers rows [c*64, c*64+64); off16 = c*256 + t
    const int row0 = t >> 2, kseg = (t & 3) * 8;
    const unsigned short* Ab = A + (size_t)(m0 + row0) * K + kseg;
    const unsigned short* Bb = Bt + (size_t)(n0 + row0) * K + kseg;
    const size_t rstep = (size_t)64 * K;
    char* ldsA = sm + w * 1024;
    char* ldsB = sm + 8192 + w * 1024;

    for (int k0 = 0; k0 < K; k0 += 32) {
        gload_lds16(Ab + k0, ldsA);
        gload_lds16(Ab + rstep + k0, ldsA + 4096);
        gload_lds16(Bb + k0, ldsB);
        gload_lds16(Bb + rstep + k0, ldsB + 4096);
        __syncthreads();
        bf16x8 aF[4], bF[4];
        #pragma unroll
        for (int i = 0; i < 4; i++)
            aF[i] = *reinterpret_cast<const bf16x8*>(sm + (wr * 64 + i * 16 + lm) * 64 + lg * 16);
        #pragma unroll
        for (int j = 0; j < 4; j++)
            bF[j] = *reinterpret_cast<const bf16x8*>(sm + 8192 + (wc * 64 + j * 16 + lm) * 64 + lg * 16);
        #pragma unroll
        for (int i = 0; i < 4; i++)
            #pragma unroll
            for (int j = 0; j < 4; j++)
                acc[i][j] = __builtin_amdgcn_mfma_f32_16x16x32_bf16(aF[i], bF[j], acc[i][j], 0, 0, 0);
        __syncthreads();
    }

    if (EPI == 2) {
        unsigned short (*Ct)[136] = reinterpret_cast<unsigned short(*)[136]>(sm);
        #pragma unroll
        for (int i = 0; i < 4; i++)
            #pragma unroll
            for (int j = 0; j < 4; j++)
                #pragma unroll
                for (int r = 0; r < 4; r++)
                    Ct[wc * 64 + j * 16 + lm][wr * 64 + i * 16 + lg * 4 + r] = f2bf(acc[i][j][r]);
        __syncthreads();
        const int colr = t >> 1, seg = t & 1;
        unsigned short* dst = reinterpret_cast<unsigned short*>(Cout) +
                              (size_t)(n0 + colr) * M + m0 + seg * 64;
        const unsigned short* srcp = &Ct[colr][seg * 64];
        #pragma unroll
        for (int i = 0; i < 8; i++)
            reinterpret_cast<uint4*>(dst)[i] = reinterpret_cast<const uint4*>(srcp)[i];
        return;
    }

    #pragma unroll
    for (int i = 0; i < 4; i++) {
        #pragma unroll
        for (int j = 0; j < 4; j++) {
            #pragma unroll
            for (int r = 0; r < 4; r++) {
                const int row = m0 + wr * 64 + i * 16 + lg * 4 + r;
                const int col = n0 + wc * 64 + j * 16 + lm;
                const size_t idx = (size_t)row * N + col;
                if (EPI == 0) {
                    reinterpret_cast<unsigned short*>(Cout)[idx] = f2bf(acc[i][j][r]);
                } else {
                    reinterpret_cast<float*>(Cout)[idx] = resid[idx] + acc[i][j][r];
                }
            }
        }
    }
}

// ---------------- legacy GEMM (fp32 B) — fallback if ws too small ----------------
template<int EPI>
__global__ __launch_bounds__(256)
void gemm_kernel(const unsigned short* __restrict__ A, const float* __restrict__ B,
                 void* __restrict__ Cout, const float* __restrict__ resid,
                 int M, int N, int K) {
    __shared__ __align__(16) unsigned short smw[5120];
    unsigned short (*As)[40] = reinterpret_cast<unsigned short(*)[40]>(smw);
    unsigned short (*Bs)[40] = reinterpret_cast<unsigned short(*)[40]>(smw + 2560);
    const int t = threadIdx.x;
    const int m0 = blockIdx.x * 64, n0 = blockIdx.y * 64;
    const int lane = t & 63, wid = t >> 6;
    const int wr = wid >> 1, wc = wid & 1;
    const int lm = lane & 15, lg = lane >> 4;
    f32x4 acc[2][2];
    #pragma unroll
    for (int i = 0; i < 2; i++)
        #pragma unroll
        for (int j = 0; j < 2; j++) acc[i][j] = (f32x4){0.f, 0.f, 0.f, 0.f};
    const int ar = t >> 2, ac = (t & 3) * 8;
    const int bk = t >> 3, bn = (t & 7) * 8;
    for (int k0 = 0; k0 < K; k0 += 32) {
        uint4 av = *reinterpret_cast<const uint4*>(A + (size_t)(m0 + ar) * K + k0 + ac);
        *reinterpret_cast<uint4*>(&As[ar][ac]) = av;
        const float* bp = B + (size_t)(k0 + bk) * N + n0 + bn;
        float4 b0 = *reinterpret_cast<const float4*>(bp);
        float4 b1 = *reinterpret_cast<const float4*>(bp + 4);
        Bs[bn + 0][bk] = f2bf(b0.x); Bs[bn + 1][bk] = f2bf(b0.y);
        Bs[bn + 2][bk] = f2bf(b0.z); Bs[bn + 3][bk] = f2bf(b0.w);
        Bs[bn + 4][bk] = f2bf(b1.x); Bs[bn + 5][bk] = f2bf(b1.y);
        Bs[bn + 6][bk] = f2bf(b1.z); Bs[bn + 7][bk] = f2bf(b1.w);
        __syncthreads();
        bf16x8 aF[2], bF[2];
        #pragma unroll
        for (int i = 0; i < 2; i++)
            aF[i] = *reinterpret_cast<const bf16x8*>(&As[wr * 32 + i * 16 + lm][lg * 8]);
        #pragma unroll
        for (int j = 0; j < 2; j++)
            bF[j] = *reinterpret_cast<const bf16x8*>(&Bs[wc * 32 + j * 16 + lm][lg * 8]);
        #pragma unroll
        for (int i = 0; i < 2; i++)
            #pragma unroll
            for (int j = 0; j < 2; j++)
                acc[i][j] = __builtin_amdgcn_mfma_f32_16x16x32_bf16(aF[i], bF[j], acc[i][j], 0, 0, 0);
        __syncthreads();
    }
    if (EPI == 2) {
        unsigned short (*Ct)[72] = reinterpret_cast<unsigned short(*)[72]>(smw);
        #pragma unroll
        for (int i = 0; i < 2; i++)
            #pragma unroll
            for (int j = 0; j < 2; j++)
                #pragma unroll
                for (int r = 0; r < 4; r++)
                    Ct[wc * 32 + j * 16 + lm][wr * 32 + i * 16 + lg * 4 + r] = f2bf(acc[i][j][r]);
        __syncthreads();
        const int col = t >> 2, seg = t & 3;
        unsigned short* dst = reinterpret_cast<unsigned short*>(Cout) +
                              (size_t)(n0 + col) * M + m0 + seg * 16;
        const uint4 c0 = *reinterpret_cast<const uint4*>(&Ct[col][seg * 16]);
        const uint4 c1 = *reinterpret_cast<const uint4*>(&Ct[col][seg * 16 + 8]);
        *reinterpret_cast<uint4*>(dst) = c0;
        *reinterpret_cast<uint4*>(dst + 8) = c1;
        return;
    }
    #pragma unroll
    for (int i = 0; i < 2; i++)
        #pragma unroll
        for (int j = 0; j < 2; j++)
            #pragma unroll
            for (int r = 0; r < 4; r++) {
                const int row = m0 + wr * 32 + i * 16 + lg * 4 + r;
                const int col = n0 + wc * 32 + j * 16 + lm;
                const size_t idx = (size_t)row * N + col;
                if (EPI == 0) reinterpret_cast<unsigned short*>(Cout)[idx] = f2bf(acc[i][j][r]);
                else          reinterpret_cast<float*>(Cout)[idx] = resid[idx] + acc[i][j][r];
            }
}

// ---------------- per-head rmsnorm + rope, in-place on bf16 q/k ----------------
__global__ __launch_bounds__(128)
void qknorm_rope_kernel(unsigned short* __restrict__ qk, const float* __restrict__ scale,
                        const float* __restrict__ cosb, const float* __restrict__ sinb,
                        int nheads) {
    const int row = blockIdx.x;
    const int head = blockIdx.y;
    const int s = row & (S_ - 1);
    const int t = threadIdx.x;
    unsigned short* p = qk + ((size_t)row * nheads + head) * HD_;
    const float v = bf2f(p[t]);
    float ss = v * v;
    #pragma unroll
    for (int o = 32; o; o >>= 1) ss += __shfl_down(ss, o);
    __shared__ float red[2];
    __shared__ float vals[HD_];
    const int lane = t & 63, wid = t >> 6;
    if (lane == 0) red[wid] = ss;
    __syncthreads();
    ss = red[0] + red[1];
    const float rn = rsqrtf(ss * (1.0f / HD_) + 1e-6f);
    const float nv = v * rn * scale[t];
    vals[t] = nv;
    __syncthreads();
    const float rot = (t < 64) ? -vals[t + 64] : vals[t - 64];
    const float c = cosb[(size_t)s * HD_ + t];
    const float sn = sinb[(size_t)s * HD_ + t];
    p[t] = f2bf(nv * c + rot * sn);
}

// ---------------- MFMA flash attention (swapped QK^T), causal GQA ----------------
__global__ __launch_bounds__(256)
void fattn_kernel(const unsigned short* __restrict__ qg,
                  const unsigned short* __restrict__ kg,
                  const unsigned short* __restrict__ vtg,
                  unsigned short* __restrict__ out) {
    __shared__ __align__(16) unsigned short klds[KVB * 128];
    __shared__ __align__(16) unsigned short vtlds[128 * 40];
    const int t = threadIdx.x;
    const int lane = t & 63, w = t >> 6;
    const int lm = lane & 15, lg = lane >> 4;
    const int qt = blockIdx.x, h = blockIdx.y, b = blockIdx.z;
    const int kvh = h >> 1;
    const int q0b = qt * 64;
    const int q0w = q0b + w * 16;
    const float CS = 0.12752409731504826f;   // (1/sqrt(128)) * log2(e)

    const unsigned short* qbase = qg + ((size_t)(b * S_ + q0w + lm) * H_ + h) * HD_;
    bf16x8 qf[4];
    #pragma unroll
    for (int kk = 0; kk < 4; ++kk)
        qf[kk] = *reinterpret_cast<const bf16x8*>(qbase + kk * 32 + lg * 8);

    f32x4 acc[8];
    #pragma unroll
    for (int i = 0; i < 8; ++i) acc[i] = (f32x4){0.f, 0.f, 0.f, 0.f};
    float m = -3e38f, l = 0.f;

    const int nt = (q0b + 64) >> 5;
    const int skv = t >> 3, sd8 = t & 7;
    const int vd = t >> 1, vseg = t & 1;
    const unsigned short* kgb = kg + ((size_t)b * S_ * KV_ + kvh) * HD_;
    const unsigned short* vgb = vtg + (size_t)(kvh * HD_) * (B_ * S_) + (size_t)b * S_;

    for (int kt = 0; kt < nt; ++kt) {
        const int kv0 = kt * KVB;
        {
            const unsigned short* src = kgb + (size_t)(kv0 + skv) * (KV_ * HD_) + sd8 * 16;
            const uint4 a0 = *reinterpret_cast<const uint4*>(src);
            const uint4 a1 = *reinterpret_cast<const uint4*>(src + 8);
            char* dst = reinterpret_cast<char*>(klds) + skv * 256;
            const int sw = (skv & 7) << 4;
            *reinterpret_cast<uint4*>(dst + ((sd8 * 32) ^ sw)) = a0;
            *reinterpret_cast<uint4*>(dst + ((sd8 * 32 + 16) ^ sw)) = a1;
        }
        {
            const unsigned short* src = vgb + (size_t)vd * (B_ * S_) + kv0 + vseg * 16;
            const uint4 a0 = *reinterpret_cast<const uint4*>(src);
            const uint4 a1 = *reinterpret_cast<const uint4*>(src + 8);
            char* dst = reinterpret_cast<char*>(vtlds) + vd * 80 + vseg * 32;
            *reinterpret_cast<uint4*>(dst) = a0;
            *reinterpret_cast<uint4*>(dst + 16) = a1;
        }
        __syncthreads();
        if (kv0 <= q0w + 15) {
            f32x4 st[2];
            st[0] = (f32x4){0.f, 0.f, 0.f, 0.f};
            st[1] = (f32x4){0.f, 0.f, 0.f, 0.f};
            #pragma unroll
            for (int sub = 0; sub < 2; ++sub) {
                const int kvl = sub * 16 + lm;
                const char* krow = reinterpret_cast<const char*>(klds) + kvl * 256;
                const int sw = (kvl & 7) << 4;
                #pragma unroll
                for (int kk = 0; kk < 4; ++kk) {
                    const bf16x8 kf = *reinterpret_cast<const bf16x8*>(krow + ((kk * 64 + lg * 16) ^ sw));
                    st[sub] = __builtin_amdgcn_mfma_f32_16x16x32_bf16(kf, qf[kk], st[sub], 0, 0, 0);
                }
            }
            if (kv0 + KVB - 1 > q0w) {
                const int qa = q0w + lm;
                #pragma unroll
                for (int sub = 0; sub < 2; ++sub)
                    #pragma unroll
                    for (int r = 0; r < 4; ++r)
                        if (kv0 + sub * 16 + lg * 4 + r > qa) st[sub][r] = -3e38f;
            }
            float pmax = st[0][0];
            #pragma unroll
            for (int r = 1; r < 4; ++r) pmax = fmaxf(pmax, st[0][r]);
            #pragma unroll
            for (int r = 0; r < 4; ++r) pmax = fmaxf(pmax, st[1][r]);
            pmax = fmaxf(pmax, __shfl_xor(pmax, 16));
            pmax = fmaxf(pmax, __shfl_xor(pmax, 32));
            if (__any(pmax - m > 8.0f)) {
                const float mn = fmaxf(pmax, m);
                const float corr = exp2f((m - mn) * CS);
                l *= corr;
                #pragma unroll
                for (int i = 0; i < 8; ++i) acc[i] *= corr;
                m = mn;
            }
            float ps = 0.f;
            bf16x4 pb[2];
            #pragma unroll
            for (int sub = 0; sub < 2; ++sub)
                #pragma unroll
                for (int r = 0; r < 4; ++r) {
                    const float pv = exp2f((st[sub][r] - m) * CS);
                    ps += pv;
                    pb[sub][r] = (short)f2bf(pv);
                }
            ps += __shfl_xor(ps, 16);
            ps += __shfl_xor(ps, 32);
            l += ps;
            #pragma unroll
            for (int sub = 0; sub < 2; ++sub) {
                const char* vb2 = reinterpret_cast<const char*>(vtlds) + sub * 32 + lg * 8;
                #pragma unroll
                for (int db = 0; db < 8; ++db) {
                    const bf16x4 vf = *reinterpret_cast<const bf16x4*>(vb2 + (db * 16 + lm) * 80);
                    acc[db] = pv_mfma(vf, pb[sub], acc[db]);
                }
            }
        }
        __syncthreads();
    }
    const float inv = 1.0f / l;
    unsigned short* ob = out + ((size_t)(b * S_ + q0w + lm) * H_ + h) * HD_ + lg * 4;
    #pragma unroll
    for (int db = 0; db < 8; ++db) {
        unsigned short r4[4];
        #pragma unroll
        for (int r = 0; r < 4; ++r) r4[r] = f2bf(acc[db][r] * inv);
        *reinterpret_cast<uint2*>(ob + db * 16) = *reinterpret_cast<uint2*>(r4);
    }
}

// ---------------- silu(g1) * g2 -> g1 (bf16, in place) ----------------
__global__ __launch_bounds__(256)
void silu_mul_kernel(unsigned short* __restrict__ g1, const unsigned short* __restrict__ g2, int n4) {
    const int i = blockIdx.x * 256 + threadIdx.x;
    if (i >= n4) return;
    const uint2 a = reinterpret_cast<const uint2*>(g1)[i];
    const uint2 bv = reinterpret_cast<const uint2*>(g2)[i];
    const unsigned int au[2] = {a.x, a.y}, bu[2] = {bv.x, bv.y};
    unsigned int r[2];
    #pragma unroll
    for (int j = 0; j < 2; j++) {
        const float a0 = bf2f((unsigned short)(au[j] & 0xffff));
        const float a1 = bf2f((unsigned short)(au[j] >> 16));
        const float b0 = bf2f((unsigned short)(bu[j] & 0xffff));
        const float b1 = bf2f((unsigned short)(bu[j] >> 16));
        const float s0 = a0 / (1.f + __expf(-a0)) * b0;
        const float s1 = a1 / (1.f + __expf(-a1)) * b1;
        r[j] = ((unsigned int)f2bf(s1) << 16) | (unsigned int)f2bf(s0);
    }
    reinterpret_cast<uint2*>(g1)[i] = make_uint2(r[0], r[1]);
}

extern "C" void kernel_launch(void* const* d_in, const int* in_sizes, int n_in,
                              void* d_out, int out_size, void* d_ws, size_t ws_size,
                              hipStream_t stream) {
    const float* x    = (const float*)d_in[0];
    const float* cosb = (const float*)d_in[2];
    const float* sinb = (const float*)d_in[3];
    const float* wq   = (const float*)d_in[4];
    const float* wk   = (const float*)d_in[5];
    const float* wv   = (const float*)d_in[6];
    const float* wo   = (const float*)d_in[7];
    const float* fc1  = (const float*)d_in[8];
    const float* fc2  = (const float*)d_in[9];
    const float* fc3  = (const float*)d_in[10];
    const float* n1s  = (const float*)d_in[11];
    const float* n2s  = (const float*)d_in[12];
    const float* qns  = (const float*)d_in[13];
    const float* kns  = (const float*)d_in[14];

    char* ws = (char*)d_ws;
    const int M = B_ * S_;  // 4096
    float* outf = (float*)d_out;
    const size_t NEED = 106954752;

    if (ws_size >= NEED) {
        // layout (bytes):
        //  h   @0         8 MiB   qb @8388608 16 MiB   kb @25165824 8 MiB
        //  g1 = [8388608, 33554432) (aliases qb+kb, dead by then)
        //  vtb @33554432  8 MiB    g2 = [33554432, 58720256) (aliases vtb)
        //  x2  @58720256  16 MiB (fp32)
        //  wq_t@75497472 wk_t@79691776 wv_t@81788928 wo_t@83886080
        //  fc1_t@88080384 fc2_t@94371840 fc3_t@100663296   end=106954752
        unsigned short* h   = (unsigned short*)(ws);
        unsigned short* qb  = (unsigned short*)(ws + 8388608);
        unsigned short* kb  = (unsigned short*)(ws + 25165824);
        unsigned short* vtb = (unsigned short*)(ws + 33554432);
        unsigned short* g1  = (unsigned short*)(ws + 8388608);
        unsigned short* g2  = (unsigned short*)(ws + 33554432);
        float*          x2  = (float*)(ws + 58720256);
        unsigned short* wqt = (unsigned short*)(ws + 75497472);
        unsigned short* wkt = (unsigned short*)(ws + 79691776);
        unsigned short* wvt = (unsigned short*)(ws + 81788928);
        unsigned short* wot = (unsigned short*)(ws + 83886080);
        unsigned short* f1t = (unsigned short*)(ws + 88080384);
        unsigned short* f2t = (unsigned short*)(ws + 94371840);
        unsigned short* f3t = (unsigned short*)(ws + 100663296);

        wtrans_kernel<<<dim3(D_ / 32, (H_ * HD_) / 32), 256, 0, stream>>>(wq, wqt, D_, H_ * HD_);
        wtrans_kernel<<<dim3(D_ / 32, (KV_ * HD_) / 32), 256, 0, stream>>>(wk, wkt, D_, KV_ * HD_);
        wtrans_kernel<<<dim3(D_ / 32, (KV_ * HD_) / 32), 256, 0, stream>>>(wv, wvt, D_, KV_ * HD_);
        wtrans_kernel<<<dim3((H_ * HD_) / 32, D_ / 32), 256, 0, stream>>>(wo, wot, H_ * HD_, D_);
        wtrans_kernel<<<dim3(D_ / 32, FF_ / 32), 256, 0, stream>>>(fc1, f1t, D_, FF_);
        wtrans_kernel<<<dim3(D_ / 32, FF_ / 32), 256, 0, stream>>>(fc2, f2t, D_, FF_);
        wtrans_kernel<<<dim3(FF_ / 32, D_ / 32), 256, 0, stream>>>(fc3, f3t, FF_, D_);

        rmsnorm_kernel<<<M, 256, 0, stream>>>(x, n1s, h);
        gemm_bt<0><<<dim3(M / 128, (H_ * HD_) / 128), 256, 0, stream>>>(h, wqt, qb, nullptr, M, H_ * HD_, D_);
        gemm_bt<0><<<dim3(M / 128, (KV_ * HD_) / 128), 256, 0, stream>>>(h, wkt, kb, nullptr, M, KV_ * HD_, D_);
        gemm_bt<2><<<dim3(M / 128, (KV_ * HD_) / 128), 256, 0, stream>>>(h, wvt, vtb, nullptr, M, KV_ * HD_, D_);
        qknorm_rope_kernel<<<dim3(M, H_), 128, 0, stream>>>(qb, qns, cosb, sinb, H_);
        qknorm_rope_kernel<<<dim3(M, KV_), 128, 0, stream>>>(kb, kns, cosb, sinb, KV_);
        fattn_kernel<<<dim3(S_ / 64, H_, B_), 256, 0, stream>>>(qb, kb, vtb, qb);
        gemm_bt<1><<<dim3(M / 128, D_ / 128), 256, 0, stream>>>(qb, wot, x2, x, M, D_, H_ * HD_);
        rmsnorm_kernel<<<M, 256, 0, stream>>>(x2, n2s, h);
        gemm_bt<0><<<dim3(M / 128, FF_ / 128), 256, 0, stream>>>(h, f1t, g1, nullptr, M, FF_, D_);
        gemm_bt<0><<<dim3(M / 128, FF_ / 128), 256, 0, stream>>>(h, f2t, g2, nullptr, M, FF_, D_);
        silu_mul_kernel<<<(M * FF_ / 4 + 255) / 256, 256, 0, stream>>>(g1, g2, M * FF_ / 4);
        gemm_bt<1><<<dim3(M / 128, D_ / 128), 256, 0, stream>>>(g1, f3t, outf, x2, M, D_, FF_);
    } else {
        // fallback: round-3 layout/path (fp32-B GEMMs), known-passing at 84 MiB ws
        unsigned short* h   = (unsigned short*)(ws);
        unsigned short* qb  = (unsigned short*)(ws + 8388608);
        unsigned short* kb  = (unsigned short*)(ws + 25165824);
        unsigned short* vtb = (unsigned short*)(ws + 33554432);
        float*          x2  = (float*)(ws + 41943040);
        unsigned short* g1  = (unsigned short*)(ws + 8388608);
        unsigned short* g2  = (unsigned short*)(ws + 58720256);

        rmsnorm_kernel<<<M, 256, 0, stream>>>(x, n1s, h);
        gemm_kernel<0><<<dim3(M / 64, (H_ * HD_) / 64), 256, 0, stream>>>(h, wq, qb, nullptr, M, H_ * HD_, D_);
        gemm_kernel<0><<<dim3(M / 64, (KV_ * HD_) / 64), 256, 0, stream>>>(h, wk, kb, nullptr, M, KV_ * HD_, D_);
        gemm_kernel<2><<<dim3(M / 64, (KV_ * HD_) / 64), 256, 0, stream>>>(h, wv, vtb, nullptr, M, KV_ * HD_, D_);
        qknorm_rope_kernel<<<dim3(M, H_), 128, 0, stream>>>(qb, qns, cosb, sinb, H_);
        qknorm_rope_kernel<<<dim3(M, KV_), 128, 0, stream>>>(kb, kns, cosb, sinb, KV_);
        fattn_kernel<<<dim3(S_ / 64, H_, B_), 256, 0, stream>>>(qb, kb, vtb, qb);
        gemm_kernel<1><<<dim3(M / 64, D_ / 64), 256, 0, stream>>>(qb, wo, x2, x, M, D_, H_ * HD_);
        rmsnorm_kernel<<<M, 256, 0, stream>>>(x2, n2s, h);
        gemm_kernel<0><<<dim3(M / 64, FF_ / 64), 256, 0, stream>>>(h, fc1, g1, nullptr, M, FF_, D_);
        gemm_kernel<0><<<dim3(M / 64, FF_ / 64), 256, 0, stream>>>(h, fc2, g2, nullptr, M, FF_, D_);
        silu_mul_kernel<<<(M * FF_ / 4 + 255) / 256, 256, 0, stream>>>(g1, g2, M * FF_ / 4);
        gemm_kernel<1><<<dim3(M / 64, D_ / 64), 256, 0, stream>>>(g1, fc3, outf, x2, M, D_, FF_);
    }
}

// Round 5
// 451.144 us; speedup vs baseline: 12.1047x; 1.2345x over previous
//
#include <hip/hip_runtime.h>

#define B_  2
#define S_  2048
#define D_  1024
#define H_  16
#define KV_ 8
#define HD_ 128
#define FF_ 3072
#define KVB 32

typedef short bf16x8 __attribute__((ext_vector_type(8)));
typedef short bf16x4 __attribute__((ext_vector_type(4)));
typedef float f32x4 __attribute__((ext_vector_type(4)));

__device__ __forceinline__ float bf2f(unsigned short u) {
    union { float f; unsigned int i; } c; c.i = ((unsigned int)u) << 16; return c.f;
}
__device__ __forceinline__ unsigned short f2bf(float f) {
    union { float f; unsigned int i; } c; c.f = f;
    unsigned int r = c.i + 0x7fffu + ((c.i >> 16) & 1u);
    return (unsigned short)(r >> 16);
}

__device__ __forceinline__ void gload_lds16(const unsigned short* g, char* ldsbase) {
    __builtin_amdgcn_global_load_lds(
        (const __attribute__((address_space(1))) unsigned int*)g,
        (__attribute__((address_space(3))) unsigned int*)ldsbase, 16, 0, 0);
}

__device__ __forceinline__ f32x4 pv_mfma(bf16x4 a, bf16x4 b, f32x4 c) {
#if __has_builtin(__builtin_amdgcn_mfma_f32_16x16x16bf16_1k)
    return __builtin_amdgcn_mfma_f32_16x16x16bf16_1k(a, b, c, 0, 0, 0);
#elif __has_builtin(__builtin_amdgcn_mfma_f32_16x16x16_bf16)
    return __builtin_amdgcn_mfma_f32_16x16x16_bf16(a, b, c, 0, 0, 0);
#else
    f32x4 d;
    asm("v_mfma_f32_16x16x16_bf16 %0, %1, %2, %3" : "=v"(d) : "v"(a), "v"(b), "v"(c));
    return d;
#endif
}

// ---------------- rmsnorm: fp32 in -> bf16 out, D=1024, one block per row ----------------
__global__ __launch_bounds__(256)
void rmsnorm_kernel(const float* __restrict__ in, const float* __restrict__ scale,
                    unsigned short* __restrict__ out) {
    const int row = blockIdx.x;
    const int t = threadIdx.x;
    const float4 v = *reinterpret_cast<const float4*>(in + (size_t)row * D_ + t * 4);
    float s = v.x * v.x + v.y * v.y + v.z * v.z + v.w * v.w;
    #pragma unroll
    for (int o = 32; o; o >>= 1) s += __shfl_down(s, o);
    __shared__ float red[4];
    const int lane = t & 63, wid = t >> 6;
    if (lane == 0) red[wid] = s;
    __syncthreads();
    s = red[0] + red[1] + red[2] + red[3];
    const float rn = rsqrtf(s * (1.0f / D_) + 1e-6f);
    const float4 sc = *reinterpret_cast<const float4*>(scale + t * 4);
    unsigned short o4[4];
    o4[0] = f2bf(v.x * rn * sc.x);
    o4[1] = f2bf(v.y * rn * sc.y);
    o4[2] = f2bf(v.z * rn * sc.z);
    o4[3] = f2bf(v.w * rn * sc.w);
    *reinterpret_cast<ushort4*>(out + (size_t)row * D_ + t * 4) =
        *reinterpret_cast<ushort4*>(o4);
}

// ---------------- weight convert+transpose: W[K][N] fp32 -> Wt[N][K] bf16 ----------------
__global__ __launch_bounds__(256)
void wtrans_kernel(const float* __restrict__ W, unsigned short* __restrict__ Wt,
                   int K, int N) {
    __shared__ float tile[32][33];
    const int t = threadIdx.x;
    const int kt = blockIdx.x * 32, nt = blockIdx.y * 32;
    {
        const int r = t >> 3, c4 = (t & 7) * 4;
        const float4 v = *reinterpret_cast<const float4*>(W + (size_t)(kt + r) * N + nt + c4);
        tile[r][c4] = v.x; tile[r][c4 + 1] = v.y; tile[r][c4 + 2] = v.z; tile[r][c4 + 3] = v.w;
    }
    __syncthreads();
    {
        const int n = t >> 3, k4 = (t & 7) * 4;
        unsigned short o[4];
        #pragma unroll
        for (int i = 0; i < 4; i++) o[i] = f2bf(tile[k4 + i][n]);
        *reinterpret_cast<ushort4*>(Wt + (size_t)(nt + n) * K + kt + k4) =
            *reinterpret_cast<ushort4*>(o);
    }
}

// ---------------- m97-structure GEMM: C[M,N] = A(bf16 [M][K]) @ Bt(bf16 [N][K])^T --------
template<int EPI>
__global__ __launch_bounds__(256)
void gemm_bt(const unsigned short* __restrict__ A, const unsigned short* __restrict__ Bt,
             void* __restrict__ Cout, const float* __restrict__ resid,
             int M, int N, int K) {
    constexpr int SMB = (EPI == 2) ? 34816 : 16384;
    __shared__ __align__(16) char sm[SMB];
    const int t = threadIdx.x;
    const int lane = t & 63, w = t >> 6;
    const int m0 = blockIdx.x * 128, n0 = blockIdx.y * 128;
    const int wr = w >> 1, wc = w & 1;
    const int lm = lane & 15, lg = lane >> 4;

    f32x4 acc[4][4];
    #pragma unroll
    for (int i = 0; i < 4; i++)
        #pragma unroll
        for (int j = 0; j < 4; j++) acc[i][j] = (f32x4){0.f, 0.f, 0.f, 0.f};

    const int row0 = t >> 2, kseg = (t & 3) * 8;
    const unsigned short* Ab = A + (size_t)(m0 + row0) * K + kseg;
    const unsigned short* Bb = Bt + (size_t)(n0 + row0) * K + kseg;
    const size_t rstep = (size_t)64 * K;
    char* ldsA = sm + w * 1024;
    char* ldsB = sm + 8192 + w * 1024;

    for (int k0 = 0; k0 < K; k0 += 32) {
        gload_lds16(Ab + k0, ldsA);
        gload_lds16(Ab + rstep + k0, ldsA + 4096);
        gload_lds16(Bb + k0, ldsB);
        gload_lds16(Bb + rstep + k0, ldsB + 4096);
        __syncthreads();
        bf16x8 aF[4], bF[4];
        #pragma unroll
        for (int i = 0; i < 4; i++)
            aF[i] = *reinterpret_cast<const bf16x8*>(sm + (wr * 64 + i * 16 + lm) * 64 + lg * 16);
        #pragma unroll
        for (int j = 0; j < 4; j++)
            bF[j] = *reinterpret_cast<const bf16x8*>(sm + 8192 + (wc * 64 + j * 16 + lm) * 64 + lg * 16);
        #pragma unroll
        for (int i = 0; i < 4; i++)
            #pragma unroll
            for (int j = 0; j < 4; j++)
                acc[i][j] = __builtin_amdgcn_mfma_f32_16x16x32_bf16(aF[i], bF[j], acc[i][j], 0, 0, 0);
        __syncthreads();
    }

    if (EPI == 2) {
        unsigned short (*Ct)[136] = reinterpret_cast<unsigned short(*)[136]>(sm);
        #pragma unroll
        for (int i = 0; i < 4; i++)
            #pragma unroll
            for (int j = 0; j < 4; j++)
                #pragma unroll
                for (int r = 0; r < 4; r++)
                    Ct[wc * 64 + j * 16 + lm][wr * 64 + i * 16 + lg * 4 + r] = f2bf(acc[i][j][r]);
        __syncthreads();
        const int colr = t >> 1, seg = t & 1;
        unsigned short* dst = reinterpret_cast<unsigned short*>(Cout) +
                              (size_t)(n0 + colr) * M + m0 + seg * 64;
        const unsigned short* srcp = &Ct[colr][seg * 64];
        #pragma unroll
        for (int i = 0; i < 8; i++)
            reinterpret_cast<uint4*>(dst)[i] = reinterpret_cast<const uint4*>(srcp)[i];
        return;
    }

    #pragma unroll
    for (int i = 0; i < 4; i++) {
        #pragma unroll
        for (int j = 0; j < 4; j++) {
            #pragma unroll
            for (int r = 0; r < 4; r++) {
                const int row = m0 + wr * 64 + i * 16 + lg * 4 + r;
                const int col = n0 + wc * 64 + j * 16 + lm;
                const size_t idx = (size_t)row * N + col;
                if (EPI == 0) {
                    reinterpret_cast<unsigned short*>(Cout)[idx] = f2bf(acc[i][j][r]);
                } else {
                    reinterpret_cast<float*>(Cout)[idx] = resid[idx] + acc[i][j][r];
                }
            }
        }
    }
}

// ---------------- per-head rmsnorm + rope, in-place on bf16 q/k ----------------
__global__ __launch_bounds__(128)
void qknorm_rope_kernel(unsigned short* __restrict__ qk, const float* __restrict__ scale,
                        const float* __restrict__ cosb, const float* __restrict__ sinb,
                        int nheads) {
    const int row = blockIdx.x;
    const int head = blockIdx.y;
    const int s = row & (S_ - 1);
    const int t = threadIdx.x;
    unsigned short* p = qk + ((size_t)row * nheads + head) * HD_;
    const float v = bf2f(p[t]);
    float ss = v * v;
    #pragma unroll
    for (int o = 32; o; o >>= 1) ss += __shfl_down(ss, o);
    __shared__ float red[2];
    __shared__ float vals[HD_];
    const int lane = t & 63, wid = t >> 6;
    if (lane == 0) red[wid] = ss;
    __syncthreads();
    ss = red[0] + red[1];
    const float rn = rsqrtf(ss * (1.0f / HD_) + 1e-6f);
    const float nv = v * rn * scale[t];
    vals[t] = nv;
    __syncthreads();
    const float rot = (t < 64) ? -vals[t + 64] : vals[t - 64];
    const float c = cosb[(size_t)s * HD_ + t];
    const float sn = sinb[(size_t)s * HD_ + t];
    p[t] = f2bf(nv * c + rot * sn);
}

// ---------------- MFMA flash attention v2: LPT order + dbuf pipeline, causal GQA --------
// grid (group=(b,h), qtrev); 4 waves x 16 q-rows; KVB=32; 1 barrier/tile.
__global__ __launch_bounds__(256)
void fattn_kernel(const unsigned short* __restrict__ qg,
                  const unsigned short* __restrict__ kg,
                  const unsigned short* __restrict__ vtg,
                  unsigned short* __restrict__ out) {
    __shared__ __align__(16) char klds[2 * 8192];    // [buf][32 rows x 256B], xor-swizzled
    __shared__ __align__(16) char vtlds[2 * 9216];   // [buf][128 rows x 72B pitch]
    const int t = threadIdx.x;
    const int lane = t & 63, w = t >> 6;
    const int lm = lane & 15, lg = lane >> 4;
    const int g = blockIdx.x;                 // (b,h) group -> XCD locality
    const int h = g & 15, b = g >> 4;
    const int qt = (int)gridDim.y - 1 - (int)blockIdx.y;   // LPT: big blocks first
    const int kvh = h >> 1;
    const int q0b = qt * 64;
    const int q0w = q0b + w * 16;
    const float CS = 0.12752409731504826f;    // (1/sqrt(128)) * log2(e)

    const unsigned short* qbase = qg + ((size_t)(b * S_ + q0w + lm) * H_ + h) * HD_;
    bf16x8 qf[4];
    #pragma unroll
    for (int kk = 0; kk < 4; ++kk)
        qf[kk] = *reinterpret_cast<const bf16x8*>(qbase + kk * 32 + lg * 8);

    f32x4 acc[8];
    #pragma unroll
    for (int i = 0; i < 8; ++i) acc[i] = (f32x4){0.f, 0.f, 0.f, 0.f};
    float m = -3e38f, l = 0.f;

    const int nt = 2 * qt + 2;
    const int skv = t >> 3, sd8 = t & 7;   // K staging coords
    const int vd = t >> 1, vseg = t & 1;   // V staging coords
    const unsigned short* kgb = kg + ((size_t)b * S_ * KV_ + kvh) * HD_;
    const unsigned short* vgb = vtg + (size_t)(kvh * HD_) * (B_ * S_) + (size_t)b * S_;

    uint4 kr0, kr1, vr0, vr1;
    auto LOADR = [&](int kt) {
        const int kv0 = kt * KVB;
        const unsigned short* ksrc = kgb + (size_t)(kv0 + skv) * (KV_ * HD_) + sd8 * 16;
        kr0 = *reinterpret_cast<const uint4*>(ksrc);
        kr1 = *reinterpret_cast<const uint4*>(ksrc + 8);
        const unsigned short* vsrc = vgb + (size_t)vd * (B_ * S_) + kv0 + vseg * 16;
        vr0 = *reinterpret_cast<const uint4*>(vsrc);
        vr1 = *reinterpret_cast<const uint4*>(vsrc + 8);
    };
    auto WRITELDS = [&](int bufi) {
        char* kd = klds + bufi * 8192 + skv * 256;
        const int sw = (skv & 7) << 4;
        *reinterpret_cast<uint4*>(kd + ((sd8 * 32) ^ sw)) = kr0;
        *reinterpret_cast<uint4*>(kd + ((sd8 * 32 + 16) ^ sw)) = kr1;
        char* vdst = vtlds + bufi * 9216 + vd * 72 + vseg * 32;
        *reinterpret_cast<uint2*>(vdst)      = make_uint2(vr0.x, vr0.y);
        *reinterpret_cast<uint2*>(vdst + 8)  = make_uint2(vr0.z, vr0.w);
        *reinterpret_cast<uint2*>(vdst + 16) = make_uint2(vr1.x, vr1.y);
        *reinterpret_cast<uint2*>(vdst + 24) = make_uint2(vr1.z, vr1.w);
    };

    LOADR(0);
    WRITELDS(0);
    __syncthreads();

    for (int kt = 0; kt < nt; ++kt) {
        const int kv0 = kt * KVB;
        const int bufi = kt & 1;
        const bool havenext = (kt + 1 < nt);
        if (havenext) LOADR(kt + 1);            // global latency hides under compute
        if (kv0 <= q0w + 15) {
            f32x4 st[2];
            st[0] = (f32x4){0.f, 0.f, 0.f, 0.f};
            st[1] = (f32x4){0.f, 0.f, 0.f, 0.f};
            #pragma unroll
            for (int sub = 0; sub < 2; ++sub) {
                const int kvl = sub * 16 + lm;
                const char* krow = klds + bufi * 8192 + kvl * 256;
                const int sw = (kvl & 7) << 4;
                #pragma unroll
                for (int kk = 0; kk < 4; ++kk) {
                    const bf16x8 kf = *reinterpret_cast<const bf16x8*>(krow + ((kk * 64 + lg * 16) ^ sw));
                    st[sub] = __builtin_amdgcn_mfma_f32_16x16x32_bf16(kf, qf[kk], st[sub], 0, 0, 0);
                }
            }
            if (kv0 + KVB - 1 > q0w) {
                const int qa = q0w + lm;
                #pragma unroll
                for (int sub = 0; sub < 2; ++sub)
                    #pragma unroll
                    for (int r = 0; r < 4; ++r)
                        if (kv0 + sub * 16 + lg * 4 + r > qa) st[sub][r] = -3e38f;
            }
            float pmax = st[0][0];
            #pragma unroll
            for (int r = 1; r < 4; ++r) pmax = fmaxf(pmax, st[0][r]);
            #pragma unroll
            for (int r = 0; r < 4; ++r) pmax = fmaxf(pmax, st[1][r]);
            pmax = fmaxf(pmax, __shfl_xor(pmax, 16));
            pmax = fmaxf(pmax, __shfl_xor(pmax, 32));
            if (__any(pmax - m > 8.0f)) {       // defer-max (T13)
                const float mn = fmaxf(pmax, m);
                const float corr = exp2f((m - mn) * CS);
                l *= corr;
                #pragma unroll
                for (int i = 0; i < 8; ++i) acc[i] *= corr;
                m = mn;
            }
            float ps = 0.f;
            bf16x4 pb[2];
            #pragma unroll
            for (int sub = 0; sub < 2; ++sub)
                #pragma unroll
                for (int r = 0; r < 4; ++r) {
                    const float pv = exp2f((st[sub][r] - m) * CS);
                    ps += pv;
                    pb[sub][r] = (short)f2bf(pv);
                }
            ps += __shfl_xor(ps, 16);
            ps += __shfl_xor(ps, 32);
            l += ps;
            #pragma unroll
            for (int sub = 0; sub < 2; ++sub) {
                const char* vb2 = vtlds + bufi * 9216 + sub * 32 + lg * 8;
                #pragma unroll
                for (int db = 0; db < 8; ++db) {
                    const bf16x4 vf = *reinterpret_cast<const bf16x4*>(vb2 + (db * 16 + lm) * 72);
                    acc[db] = pv_mfma(vf, pb[sub], acc[db]);
                }
            }
        }
        if (havenext) WRITELDS((kt + 1) & 1);   // other buffer: safe pre-barrier
        __syncthreads();
    }
    const float inv = 1.0f / l;
    unsigned short* ob = out + ((size_t)(b * S_ + q0w + lm) * H_ + h) * HD_ + lg * 4;
    #pragma unroll
    for (int db = 0; db < 8; ++db) {
        unsigned short r4[4];
        #pragma unroll
        for (int r = 0; r < 4; ++r) r4[r] = f2bf(acc[db][r] * inv);
        *reinterpret_cast<uint2*>(ob + db * 16) = *reinterpret_cast<uint2*>(r4);
    }
}

// ---------------- silu(g1) * g2 -> g1 (bf16, in place) ----------------
__global__ __launch_bounds__(256)
void silu_mul_kernel(unsigned short* __restrict__ g1, const unsigned short* __restrict__ g2, int n4) {
    const int i = blockIdx.x * 256 + threadIdx.x;
    if (i >= n4) return;
    const uint2 a = reinterpret_cast<const uint2*>(g1)[i];
    const uint2 bv = reinterpret_cast<const uint2*>(g2)[i];
    const unsigned int au[2] = {a.x, a.y}, bu[2] = {bv.x, bv.y};
    unsigned int r[2];
    #pragma unroll
    for (int j = 0; j < 2; j++) {
        const float a0 = bf2f((unsigned short)(au[j] & 0xffff));
        const float a1 = bf2f((unsigned short)(au[j] >> 16));
        const float b0 = bf2f((unsigned short)(bu[j] & 0xffff));
        const float b1 = bf2f((unsigned short)(bu[j] >> 16));
        const float s0 = a0 / (1.f + __expf(-a0)) * b0;
        const float s1 = a1 / (1.f + __expf(-a1)) * b1;
        r[j] = ((unsigned int)f2bf(s1) << 16) | (unsigned int)f2bf(s0);
    }
    reinterpret_cast<uint2*>(g1)[i] = make_uint2(r[0], r[1]);
}

extern "C" void kernel_launch(void* const* d_in, const int* in_sizes, int n_in,
                              void* d_out, int out_size, void* d_ws, size_t ws_size,
                              hipStream_t stream) {
    const float* x    = (const float*)d_in[0];
    const float* cosb = (const float*)d_in[2];
    const float* sinb = (const float*)d_in[3];
    const float* wq   = (const float*)d_in[4];
    const float* wk   = (const float*)d_in[5];
    const float* wv   = (const float*)d_in[6];
    const float* wo   = (const float*)d_in[7];
    const float* fc1  = (const float*)d_in[8];
    const float* fc2  = (const float*)d_in[9];
    const float* fc3  = (const float*)d_in[10];
    const float* n1s  = (const float*)d_in[11];
    const float* n2s  = (const float*)d_in[12];
    const float* qns  = (const float*)d_in[13];
    const float* kns  = (const float*)d_in[14];

    char* ws = (char*)d_ws;
    const int M = B_ * S_;  // 4096
    float* outf = (float*)d_out;

    // ws layout (verified >= 107 MB by round-4 fast path):
    unsigned short* h   = (unsigned short*)(ws);
    unsigned short* qb  = (unsigned short*)(ws + 8388608);
    unsigned short* kb  = (unsigned short*)(ws + 25165824);
    unsigned short* vtb = (unsigned short*)(ws + 33554432);
    unsigned short* g1  = (unsigned short*)(ws + 8388608);
    unsigned short* g2  = (unsigned short*)(ws + 33554432);
    float*          x2  = (float*)(ws + 58720256);
    unsigned short* wqt = (unsigned short*)(ws + 75497472);
    unsigned short* wkt = (unsigned short*)(ws + 79691776);
    unsigned short* wvt = (unsigned short*)(ws + 81788928);
    unsigned short* wot = (unsigned short*)(ws + 83886080);
    unsigned short* f1t = (unsigned short*)(ws + 88080384);
    unsigned short* f2t = (unsigned short*)(ws + 94371840);
    unsigned short* f3t = (unsigned short*)(ws + 100663296);

    wtrans_kernel<<<dim3(D_ / 32, (H_ * HD_) / 32), 256, 0, stream>>>(wq, wqt, D_, H_ * HD_);
    wtrans_kernel<<<dim3(D_ / 32, (KV_ * HD_) / 32), 256, 0, stream>>>(wk, wkt, D_, KV_ * HD_);
    wtrans_kernel<<<dim3(D_ / 32, (KV_ * HD_) / 32), 256, 0, stream>>>(wv, wvt, D_, KV_ * HD_);
    wtrans_kernel<<<dim3((H_ * HD_) / 32, D_ / 32), 256, 0, stream>>>(wo, wot, H_ * HD_, D_);
    wtrans_kernel<<<dim3(D_ / 32, FF_ / 32), 256, 0, stream>>>(fc1, f1t, D_, FF_);
    wtrans_kernel<<<dim3(D_ / 32, FF_ / 32), 256, 0, stream>>>(fc2, f2t, D_, FF_);
    wtrans_kernel<<<dim3(FF_ / 32, D_ / 32), 256, 0, stream>>>(fc3, f3t, FF_, D_);

    rmsnorm_kernel<<<M, 256, 0, stream>>>(x, n1s, h);
    gemm_bt<0><<<dim3(M / 128, (H_ * HD_) / 128), 256, 0, stream>>>(h, wqt, qb, nullptr, M, H_ * HD_, D_);
    gemm_bt<0><<<dim3(M / 128, (KV_ * HD_) / 128), 256, 0, stream>>>(h, wkt, kb, nullptr, M, KV_ * HD_, D_);
    gemm_bt<2><<<dim3(M / 128, (KV_ * HD_) / 128), 256, 0, stream>>>(h, wvt, vtb, nullptr, M, KV_ * HD_, D_);
    qknorm_rope_kernel<<<dim3(M, H_), 128, 0, stream>>>(qb, qns, cosb, sinb, H_);
    qknorm_rope_kernel<<<dim3(M, KV_), 128, 0, stream>>>(kb, kns, cosb, sinb, KV_);
    fattn_kernel<<<dim3(H_ * B_, S_ / 64), 256, 0, stream>>>(qb, kb, vtb, qb);
    gemm_bt<1><<<dim3(M / 128, D_ / 128), 256, 0, stream>>>(qb, wot, x2, x, M, D_, H_ * HD_);
    rmsnorm_kernel<<<M, 256, 0, stream>>>(x2, n2s, h);
    gemm_bt<0><<<dim3(M / 128, FF_ / 128), 256, 0, stream>>>(h, f1t, g1, nullptr, M, FF_, D_);
    gemm_bt<0><<<dim3(M / 128, FF_ / 128), 256, 0, stream>>>(h, f2t, g2, nullptr, M, FF_, D_);
    silu_mul_kernel<<<(M * FF_ / 4 + 255) / 256, 256, 0, stream>>>(g1, g2, M * FF_ / 4);
    gemm_bt<1><<<dim3(M / 128, D_ / 128), 256, 0, stream>>>(g1, f3t, outf, x2, M, D_, FF_);
}

// Round 7
// 423.892 us; speedup vs baseline: 12.8829x; 1.0643x over previous
//
#include <hip/hip_runtime.h>

#define B_  2
#define S_  2048
#define D_  1024
#define H_  16
#define KV_ 8
#define HD_ 128
#define FF_ 3072
#define KVB 32

typedef short bf16x8 __attribute__((ext_vector_type(8)));
typedef short bf16x4 __attribute__((ext_vector_type(4)));
typedef float f32x4 __attribute__((ext_vector_type(4)));

__device__ __forceinline__ float bf2f(unsigned short u) {
    union { float f; unsigned int i; } c; c.i = ((unsigned int)u) << 16; return c.f;
}
__device__ __forceinline__ unsigned short f2bf(float f) {
    union { float f; unsigned int i; } c; c.f = f;
    unsigned int r = c.i + 0x7fffu + ((c.i >> 16) & 1u);
    return (unsigned short)(r >> 16);
}

__device__ __forceinline__ void gload_lds16(const unsigned short* g, char* ldsbase) {
    __builtin_amdgcn_global_load_lds(
        (const __attribute__((address_space(1))) unsigned int*)g,
        (__attribute__((address_space(3))) unsigned int*)ldsbase, 16, 0, 0);
}

__device__ __forceinline__ f32x4 pv_mfma(bf16x4 a, bf16x4 b, f32x4 c) {
#if __has_builtin(__builtin_amdgcn_mfma_f32_16x16x16bf16_1k)
    return __builtin_amdgcn_mfma_f32_16x16x16bf16_1k(a, b, c, 0, 0, 0);
#elif __has_builtin(__builtin_amdgcn_mfma_f32_16x16x16_bf16)
    return __builtin_amdgcn_mfma_f32_16x16x16_bf16(a, b, c, 0, 0, 0);
#else
    f32x4 d;
    asm("v_mfma_f32_16x16x16_bf16 %0, %1, %2, %3" : "=v"(d) : "v"(a), "v"(b), "v"(c));
    return d;
#endif
}

// ---------------- rmsnorm: fp32 in -> bf16 out, D=1024, one block per row ----------------
__global__ __launch_bounds__(256)
void rmsnorm_kernel(const float* __restrict__ in, const float* __restrict__ scale,
                    unsigned short* __restrict__ out) {
    const int row = blockIdx.x;
    const int t = threadIdx.x;
    const float4 v = *reinterpret_cast<const float4*>(in + (size_t)row * D_ + t * 4);
    float s = v.x * v.x + v.y * v.y + v.z * v.z + v.w * v.w;
    #pragma unroll
    for (int o = 32; o; o >>= 1) s += __shfl_down(s, o);
    __shared__ float red[4];
    const int lane = t & 63, wid = t >> 6;
    if (lane == 0) red[wid] = s;
    __syncthreads();
    s = red[0] + red[1] + red[2] + red[3];
    const float rn = rsqrtf(s * (1.0f / D_) + 1e-6f);
    const float4 sc = *reinterpret_cast<const float4*>(scale + t * 4);
    unsigned short o4[4];
    o4[0] = f2bf(v.x * rn * sc.x);
    o4[1] = f2bf(v.y * rn * sc.y);
    o4[2] = f2bf(v.z * rn * sc.z);
    o4[3] = f2bf(v.w * rn * sc.w);
    *reinterpret_cast<ushort4*>(out + (size_t)row * D_ + t * 4) =
        *reinterpret_cast<ushort4*>(o4);
}

// ---------------- weight convert+transpose: W[K][N] fp32 -> Wt[N][K] bf16 ----------------
__global__ __launch_bounds__(256)
void wtrans_kernel(const float* __restrict__ W, unsigned short* __restrict__ Wt,
                   int K, int N) {
    __shared__ float tile[32][33];
    const int t = threadIdx.x;
    const int kt = blockIdx.x * 32, nt = blockIdx.y * 32;
    {
        const int r = t >> 3, c4 = (t & 7) * 4;
        const float4 v = *reinterpret_cast<const float4*>(W + (size_t)(kt + r) * N + nt + c4);
        tile[r][c4] = v.x; tile[r][c4 + 1] = v.y; tile[r][c4 + 2] = v.z; tile[r][c4 + 3] = v.w;
    }
    __syncthreads();
    {
        const int n = t >> 3, k4 = (t & 7) * 4;
        unsigned short o[4];
        #pragma unroll
        for (int i = 0; i < 4; i++) o[i] = f2bf(tile[k4 + i][n]);
        *reinterpret_cast<ushort4*>(Wt + (size_t)(nt + n) * K + kt + k4) =
            *reinterpret_cast<ushort4*>(o);
    }
}

// =============== 256^2 2-phase dbuf GEMM: C = A[M][K] @ Bt[N][K]^T, bf16 out =============
// 8 waves (2Mx4N), BK=64, 128KiB LDS double-buffer, st_16x32 swizzle via pre-swizzled
// global source + swizzled ds_read. ONE __syncthreads() per K-tile (vmcnt0+lgkm0+barrier):
// RAW (prefetch certified) and WAR (prior reads drained) both safe by construction.
__global__ __launch_bounds__(512, 2)
void gemm256(const unsigned short* __restrict__ A, const unsigned short* __restrict__ Bt,
             unsigned short* __restrict__ C, int M, int N, int K, int nm) {
    __shared__ __align__(16) char lds[131072];
    const int tid = threadIdx.x;
    const int lane = tid & 63, w = tid >> 6;
    const int lm = lane & 15, lg = lane >> 4;
    const int wr = w >> 2, wc = w & 3;
    const int nwg = gridDim.x;
    const int cpx = nwg >> 3;                         // nwg % 8 == 0 (caller guarantees)
    const int bid = blockIdx.x;
    const int swz = (bid & 7) * cpx + (bid >> 3);     // bijective XCD swizzle
    const int m0 = (swz % nm) * 256;
    const int n0 = (swz / nm) * 256;

    f32x4 acc[8][4];
    #pragma unroll
    for (int i = 0; i < 8; ++i)
        #pragma unroll
        for (int j = 0; j < 4; ++j) acc[i][j] = (f32x4){0.f, 0.f, 0.f, 0.f};

    // stage: rows srow+64c, phys k-block tid&7 holds logical block ((tid&7) ^ 2*rowbit2)
    const int srow = tid >> 3;                                     // 0..63
    const int skel = ((tid & 7) * 8) ^ (((tid >> 5) & 1) << 4);    // pre-swizzled k-elem
    const int flip = ((lm >> 2) & 1) << 5;                         // read-side swizzle
    const int abase = (wr * 128 + lm) * 128 + ((lg * 16) ^ flip);
    const int bbase = (wc * 64 + lm) * 128 + ((lg * 16) ^ flip);

    auto stage = [&](int kt, int d) {
        const unsigned short* ga = A + (size_t)(m0 + srow) * K + kt * 64 + skel;
        const unsigned short* gb = Bt + (size_t)(n0 + srow) * K + kt * 64 + skel;
        char* la = lds + d * 65536 + (w << 10);
        char* lb = la + 32768;
        #pragma unroll
        for (int c = 0; c < 4; ++c) {
            gload_lds16(ga + (size_t)(c * 64) * K, la + c * 8192);
            gload_lds16(gb + (size_t)(c * 64) * K, lb + c * 8192);
        }
    };

    stage(0, 0);
    __syncthreads();

    const int ntile = K >> 6;
    for (int kt = 0; kt < ntile; ++kt) {
        const int d = kt & 1;
        if (kt + 1 < ntile) stage(kt + 1, d ^ 1);   // prefetch hides under compute
        const char* Ar = lds + d * 65536;
        const char* Br = Ar + 32768;
        bf16x8 bb[4][2];
        #pragma unroll
        for (int nf = 0; nf < 4; ++nf)
            #pragma unroll
            for (int s = 0; s < 2; ++s)
                bb[nf][s] = *reinterpret_cast<const bf16x8*>(Br + bbase + nf * 2048 + s * 64);
        bf16x8 aH[4][2];
        #pragma unroll
        for (int f = 0; f < 4; ++f)
            #pragma unroll
            for (int s = 0; s < 2; ++s)
                aH[f][s] = *reinterpret_cast<const bf16x8*>(Ar + abase + f * 2048 + s * 64);
        #pragma unroll
        for (int f = 0; f < 4; ++f)
            #pragma unroll
            for (int nf = 0; nf < 4; ++nf)
                #pragma unroll
                for (int s = 0; s < 2; ++s)
                    acc[f][nf] = __builtin_amdgcn_mfma_f32_16x16x32_bf16(
                        aH[f][s], bb[nf][s], acc[f][nf], 0, 0, 0);
        #pragma unroll
        for (int f = 0; f < 4; ++f)
            #pragma unroll
            for (int s = 0; s < 2; ++s)
                aH[f][s] = *reinterpret_cast<const bf16x8*>(Ar + abase + 8192 + f * 2048 + s * 64);
        #pragma unroll
        for (int f = 0; f < 4; ++f)
            #pragma unroll
            for (int nf = 0; nf < 4; ++nf)
                #pragma unroll
                for (int s = 0; s < 2; ++s)
                    acc[4 + f][nf] = __builtin_amdgcn_mfma_f32_16x16x32_bf16(
                        aH[f][s], bb[nf][s], acc[4 + f][nf], 0, 0, 0);
        __syncthreads();
    }

    #pragma unroll
    for (int mf = 0; mf < 8; ++mf)
        #pragma unroll
        for (int nf = 0; nf < 4; ++nf)
            #pragma unroll
            for (int r = 0; r < 4; ++r)
                C[(size_t)(m0 + wr * 128 + mf * 16 + lg * 4 + r) * N +
                  (n0 + wc * 64 + nf * 16 + lm)] = f2bf(acc[mf][nf][r]);
}

// ---------------- m97-structure GEMM: C[M,N] = A(bf16 [M][lda]) @ Bt(bf16 [N][K])^T ------
template<int EPI>
__global__ __launch_bounds__(256)
void gemm_bt(const unsigned short* __restrict__ A, const unsigned short* __restrict__ Bt,
             void* __restrict__ Cout, const float* __restrict__ resid,
             int M, int N, int K, int lda) {
    constexpr int SMB = (EPI == 2) ? 34816 : 16384;
    __shared__ __align__(16) char sm[SMB];
    const int t = threadIdx.x;
    const int lane = t & 63, w = t >> 6;
    const int m0 = blockIdx.x * 128, n0 = blockIdx.y * 128;
    const int wr = w >> 1, wc = w & 1;
    const int lm = lane & 15, lg = lane >> 4;

    f32x4 acc[4][4];
    #pragma unroll
    for (int i = 0; i < 4; i++)
        #pragma unroll
        for (int j = 0; j < 4; j++) acc[i][j] = (f32x4){0.f, 0.f, 0.f, 0.f};

    const int row0 = t >> 2, kseg = (t & 3) * 8;
    const unsigned short* Ab = A + (size_t)(m0 + row0) * lda + kseg;
    const unsigned short* Bb = Bt + (size_t)(n0 + row0) * K + kseg;
    const size_t rstepA = (size_t)64 * lda;
    const size_t rstepB = (size_t)64 * K;
    char* ldsA = sm + w * 1024;
    char* ldsB = sm + 8192 + w * 1024;

    for (int k0 = 0; k0 < K; k0 += 32) {
        gload_lds16(Ab + k0, ldsA);
        gload_lds16(Ab + rstepA + k0, ldsA + 4096);
        gload_lds16(Bb + k0, ldsB);
        gload_lds16(Bb + rstepB + k0, ldsB + 4096);
        __syncthreads();
        bf16x8 aF[4], bF[4];
        #pragma unroll
        for (int i = 0; i < 4; i++)
            aF[i] = *reinterpret_cast<const bf16x8*>(sm + (wr * 64 + i * 16 + lm) * 64 + lg * 16);
        #pragma unroll
        for (int j = 0; j < 4; j++)
            bF[j] = *reinterpret_cast<const bf16x8*>(sm + 8192 + (wc * 64 + j * 16 + lm) * 64 + lg * 16);
        #pragma unroll
        for (int i = 0; i < 4; i++)
            #pragma unroll
            for (int j = 0; j < 4; j++)
                acc[i][j] = __builtin_amdgcn_mfma_f32_16x16x32_bf16(aF[i], bF[j], acc[i][j], 0, 0, 0);
        __syncthreads();
    }

    if (EPI == 2) {
        unsigned short (*Ct)[136] = reinterpret_cast<unsigned short(*)[136]>(sm);
        #pragma unroll
        for (int i = 0; i < 4; i++)
            #pragma unroll
            for (int j = 0; j < 4; j++)
                #pragma unroll
                for (int r = 0; r < 4; r++)
                    Ct[wc * 64 + j * 16 + lm][wr * 64 + i * 16 + lg * 4 + r] = f2bf(acc[i][j][r]);
        __syncthreads();
        const int colr = t >> 1, seg = t & 1;
        unsigned short* dst = reinterpret_cast<unsigned short*>(Cout) +
                              (size_t)(n0 + colr) * M + m0 + seg * 64;
        const unsigned short* srcp = &Ct[colr][seg * 64];
        #pragma unroll
        for (int i = 0; i < 8; i++)
            reinterpret_cast<uint4*>(dst)[i] = reinterpret_cast<const uint4*>(srcp)[i];
        return;
    }

    #pragma unroll
    for (int i = 0; i < 4; i++) {
        #pragma unroll
        for (int j = 0; j < 4; j++) {
            #pragma unroll
            for (int r = 0; r < 4; r++) {
                const int row = m0 + wr * 64 + i * 16 + lg * 4 + r;
                const int col = n0 + wc * 64 + j * 16 + lm;
                const size_t idx = (size_t)row * N + col;
                if (EPI == 0) {
                    reinterpret_cast<unsigned short*>(Cout)[idx] = f2bf(acc[i][j][r]);
                } else {
                    reinterpret_cast<float*>(Cout)[idx] = resid[idx] + acc[i][j][r];
                }
            }
        }
    }
}

// ---------------- per-head rmsnorm + rope, in-place on strided bf16 q/k ----------------
__global__ __launch_bounds__(128)
void qknorm_rope_kernel(unsigned short* __restrict__ qk, const float* __restrict__ scale,
                        const float* __restrict__ cosb, const float* __restrict__ sinb,
                        int ld) {
    const int row = blockIdx.x;
    const int head = blockIdx.y;
    const int s = row & (S_ - 1);
    const int t = threadIdx.x;
    unsigned short* p = qk + (size_t)row * ld + head * HD_;
    const float v = bf2f(p[t]);
    float ss = v * v;
    #pragma unroll
    for (int o = 32; o; o >>= 1) ss += __shfl_down(ss, o);
    __shared__ float red[2];
    __shared__ float vals[HD_];
    const int lane = t & 63, wid = t >> 6;
    if (lane == 0) red[wid] = ss;
    __syncthreads();
    ss = red[0] + red[1];
    const float rn = rsqrtf(ss * (1.0f / HD_) + 1e-6f);
    const float nv = v * rn * scale[t];
    vals[t] = nv;
    __syncthreads();
    const float rot = (t < 64) ? -vals[t + 64] : vals[t - 64];
    const float c = cosb[(size_t)s * HD_ + t];
    const float sn = sinb[(size_t)s * HD_ + t];
    p[t] = f2bf(nv * c + rot * sn);
}

// ---------------- MFMA flash attention v2: LPT order + dbuf pipeline, causal GQA --------
__global__ __launch_bounds__(256)
void fattn_kernel(const unsigned short* __restrict__ qg,
                  const unsigned short* __restrict__ kg,
                  const unsigned short* __restrict__ vtg,
                  unsigned short* __restrict__ out, int qld, int kld) {
    __shared__ __align__(16) char klds[2 * 8192];    // [buf][32 rows x 256B], xor-swizzled
    __shared__ __align__(16) char vtlds[2 * 9216];   // [buf][128 rows x 72B pitch]
    const int t = threadIdx.x;
    const int lane = t & 63, w = t >> 6;
    const int lm = lane & 15, lg = lane >> 4;
    const int g = blockIdx.x;                 // (b,h) group -> XCD locality
    const int h = g & 15, b = g >> 4;
    const int qt = (int)gridDim.y - 1 - (int)blockIdx.y;   // LPT: big blocks first
    const int kvh = h >> 1;
    const int q0b = qt * 64;
    const int q0w = q0b + w * 16;
    const float CS = 0.12752409731504826f;    // (1/sqrt(128)) * log2(e)

    const unsigned short* qbase = qg + (size_t)(b * S_ + q0w + lm) * qld + h * HD_;
    bf16x8 qf[4];
    #pragma unroll
    for (int kk = 0; kk < 4; ++kk)
        qf[kk] = *reinterpret_cast<const bf16x8*>(qbase + kk * 32 + lg * 8);

    f32x4 acc[8];
    #pragma unroll
    for (int i = 0; i < 8; ++i) acc[i] = (f32x4){0.f, 0.f, 0.f, 0.f};
    float m = -3e38f, l = 0.f;

    const int nt = 2 * qt + 2;
    const int skv = t >> 3, sd8 = t & 7;   // K staging coords
    const int vd = t >> 1, vseg = t & 1;   // V staging coords
    const unsigned short* kgb = kg + (size_t)b * S_ * kld + kvh * HD_;
    const unsigned short* vgb = vtg + (size_t)(kvh * HD_) * (B_ * S_) + (size_t)b * S_;

    uint4 kr0, kr1, vr0, vr1;
    auto LOADR = [&](int kt) {
        const int kv0 = kt * KVB;
        const unsigned short* ksrc = kgb + (size_t)(kv0 + skv) * kld + sd8 * 16;
        kr0 = *reinterpret_cast<const uint4*>(ksrc);
        kr1 = *reinterpret_cast<const uint4*>(ksrc + 8);
        const unsigned short* vsrc = vgb + (size_t)vd * (B_ * S_) + kv0 + vseg * 16;
        vr0 = *reinterpret_cast<const uint4*>(vsrc);
        vr1 = *reinterpret_cast<const uint4*>(vsrc + 8);
    };
    auto WRITELDS = [&](int bufi) {
        char* kd = klds + bufi * 8192 + skv * 256;
        const int sw = (skv & 7) << 4;
        *reinterpret_cast<uint4*>(kd + ((sd8 * 32) ^ sw)) = kr0;
        *reinterpret_cast<uint4*>(kd + ((sd8 * 32 + 16) ^ sw)) = kr1;
        char* vdst = vtlds + bufi * 9216 + vd * 72 + vseg * 32;
        *reinterpret_cast<uint2*>(vdst)      = make_uint2(vr0.x, vr0.y);
        *reinterpret_cast<uint2*>(vdst + 8)  = make_uint2(vr0.z, vr0.w);
        *reinterpret_cast<uint2*>(vdst + 16) = make_uint2(vr1.x, vr1.y);
        *reinterpret_cast<uint2*>(vdst + 24) = make_uint2(vr1.z, vr1.w);
    };

    LOADR(0);
    WRITELDS(0);
    __syncthreads();

    for (int kt = 0; kt < nt; ++kt) {
        const int kv0 = kt * KVB;
        const int bufi = kt & 1;
        const bool havenext = (kt + 1 < nt);
        if (havenext) LOADR(kt + 1);
        if (kv0 <= q0w + 15) {
            f32x4 st[2];
            st[0] = (f32x4){0.f, 0.f, 0.f, 0.f};
            st[1] = (f32x4){0.f, 0.f, 0.f, 0.f};
            #pragma unroll
            for (int sub = 0; sub < 2; ++sub) {
                const int kvl = sub * 16 + lm;
                const char* krow = klds + bufi * 8192 + kvl * 256;
                const int sw = (kvl & 7) << 4;
                #pragma unroll
                for (int kk = 0; kk < 4; ++kk) {
                    const bf16x8 kf = *reinterpret_cast<const bf16x8*>(krow + ((kk * 64 + lg * 16) ^ sw));
                    st[sub] = __builtin_amdgcn_mfma_f32_16x16x32_bf16(kf, qf[kk], st[sub], 0, 0, 0);
                }
            }
            if (kv0 + KVB - 1 > q0w) {
                const int qa = q0w + lm;
                #pragma unroll
                for (int sub = 0; sub < 2; ++sub)
                    #pragma unroll
                    for (int r = 0; r < 4; ++r)
                        if (kv0 + sub * 16 + lg * 4 + r > qa) st[sub][r] = -3e38f;
            }
            float pmax = st[0][0];
            #pragma unroll
            for (int r = 1; r < 4; ++r) pmax = fmaxf(pmax, st[0][r]);
            #pragma unroll
            for (int r = 0; r < 4; ++r) pmax = fmaxf(pmax, st[1][r]);
            pmax = fmaxf(pmax, __shfl_xor(pmax, 16));
            pmax = fmaxf(pmax, __shfl_xor(pmax, 32));
            if (__any(pmax - m > 8.0f)) {       // defer-max (T13)
                const float mn = fmaxf(pmax, m);
                const float corr = exp2f((m - mn) * CS);
                l *= corr;
                #pragma unroll
                for (int i = 0; i < 8; ++i) acc[i] *= corr;
                m = mn;
            }
            float ps = 0.f;
            bf16x4 pb[2];
            #pragma unroll
            for (int sub = 0; sub < 2; ++sub)
                #pragma unroll
                for (int r = 0; r < 4; ++r) {
                    const float pv = exp2f((st[sub][r] - m) * CS);
                    ps += pv;
                    pb[sub][r] = (short)f2bf(pv);
                }
            ps += __shfl_xor(ps, 16);
            ps += __shfl_xor(ps, 32);
            l += ps;
            #pragma unroll
            for (int sub = 0; sub < 2; ++sub) {
                const char* vb2 = vtlds + bufi * 9216 + sub * 32 + lg * 8;
                #pragma unroll
                for (int db = 0; db < 8; ++db) {
                    const bf16x4 vf = *reinterpret_cast<const bf16x4*>(vb2 + (db * 16 + lm) * 72);
                    acc[db] = pv_mfma(vf, pb[sub], acc[db]);
                }
            }
        }
        if (havenext) WRITELDS((kt + 1) & 1);
        __syncthreads();
    }
    const float inv = 1.0f / l;
    unsigned short* ob = out + (size_t)(b * S_ + q0w + lm) * qld + h * HD_ + lg * 4;
    #pragma unroll
    for (int db = 0; db < 8; ++db) {
        unsigned short r4[4];
        #pragma unroll
        for (int r = 0; r < 4; ++r) r4[r] = f2bf(acc[db][r] * inv);
        *reinterpret_cast<uint2*>(ob + db * 16) = *reinterpret_cast<uint2*>(r4);
    }
}

// ---------------- silu(g12[:, :3072]) * g12[:, 3072:] -> g12[:, :3072] in place ----------
__global__ __launch_bounds__(256)
void silu_mul_kernel(unsigned short* __restrict__ g, int n4) {
    const int i = blockIdx.x * 256 + threadIdx.x;
    if (i >= n4) return;
    const int r = i / (FF_ / 4);
    const int c = (i - r * (FF_ / 4)) * 4;
    const size_t off = (size_t)r * (2 * FF_) + c;
    const uint2 a = *reinterpret_cast<const uint2*>(g + off);
    const uint2 bv = *reinterpret_cast<const uint2*>(g + off + FF_);
    const unsigned int au[2] = {a.x, a.y}, bu[2] = {bv.x, bv.y};
    unsigned int rr[2];
    #pragma unroll
    for (int j = 0; j < 2; j++) {
        const float a0 = bf2f((unsigned short)(au[j] & 0xffff));
        const float a1 = bf2f((unsigned short)(au[j] >> 16));
        const float b0 = bf2f((unsigned short)(bu[j] & 0xffff));
        const float b1 = bf2f((unsigned short)(bu[j] >> 16));
        const float s0 = a0 / (1.f + __expf(-a0)) * b0;
        const float s1 = a1 / (1.f + __expf(-a1)) * b1;
        rr[j] = ((unsigned int)f2bf(s1) << 16) | (unsigned int)f2bf(s0);
    }
    *reinterpret_cast<uint2*>(g + off) = make_uint2(rr[0], rr[1]);
}

extern "C" void kernel_launch(void* const* d_in, const int* in_sizes, int n_in,
                              void* d_out, int out_size, void* d_ws, size_t ws_size,
                              hipStream_t stream) {
    const float* x    = (const float*)d_in[0];
    const float* cosb = (const float*)d_in[2];
    const float* sinb = (const float*)d_in[3];
    const float* wq   = (const float*)d_in[4];
    const float* wk   = (const float*)d_in[5];
    const float* wv   = (const float*)d_in[6];
    const float* wo   = (const float*)d_in[7];
    const float* fc1  = (const float*)d_in[8];
    const float* fc2  = (const float*)d_in[9];
    const float* fc3  = (const float*)d_in[10];
    const float* n1s  = (const float*)d_in[11];
    const float* n2s  = (const float*)d_in[12];
    const float* qns  = (const float*)d_in[13];
    const float* kns  = (const float*)d_in[14];

    char* ws = (char*)d_ws;
    const int M = B_ * S_;  // 4096
    float* outf = (float*)d_out;

    // ws layout (bytes), total 106,954,752:
    //  h    @0         8 MiB  (bf16 4096x1024)
    //  qkb  @8388608   24 MiB (bf16 4096x3072: q cols 0-2047, k cols 2048-3071)
    //  vtb  @33554432  8 MiB  (bf16 V^T [1024][4096])
    //  g12  @8388608   48 MiB (bf16 4096x6144; aliases qkb+vtb, both dead by fc12)
    //  x2   @58720256  16 MiB (fp32)
    //  wqt|wkt @75497472 contiguous -> fused QK weight [3072][1024]
    //  wvt @81788928  wot @83886080
    //  f1t|f2t @88080384 contiguous -> fused fc12 weight [6144][1024]
    //  f3t @100663296
    unsigned short* h    = (unsigned short*)(ws);
    unsigned short* qkb  = (unsigned short*)(ws + 8388608);
    unsigned short* vtb  = (unsigned short*)(ws + 33554432);
    unsigned short* g12  = (unsigned short*)(ws + 8388608);
    float*          x2   = (float*)(ws + 58720256);
    unsigned short* wqkt = (unsigned short*)(ws + 75497472);
    unsigned short* wvt  = (unsigned short*)(ws + 81788928);
    unsigned short* wot  = (unsigned short*)(ws + 83886080);
    unsigned short* f12t = (unsigned short*)(ws + 88080384);
    unsigned short* f3t  = (unsigned short*)(ws + 100663296);
    unsigned short* wqt = wqkt;
    unsigned short* wkt = wqkt + (size_t)2048 * 1024;
    unsigned short* f1t = f12t;
    unsigned short* f2t = f12t + (size_t)3072 * 1024;

    wtrans_kernel<<<dim3(D_ / 32, (H_ * HD_) / 32), 256, 0, stream>>>(wq, wqt, D_, H_ * HD_);
    wtrans_kernel<<<dim3(D_ / 32, (KV_ * HD_) / 32), 256, 0, stream>>>(wk, wkt, D_, KV_ * HD_);
    wtrans_kernel<<<dim3(D_ / 32, (KV_ * HD_) / 32), 256, 0, stream>>>(wv, wvt, D_, KV_ * HD_);
    wtrans_kernel<<<dim3((H_ * HD_) / 32, D_ / 32), 256, 0, stream>>>(wo, wot, H_ * HD_, D_);
    wtrans_kernel<<<dim3(D_ / 32, FF_ / 32), 256, 0, stream>>>(fc1, f1t, D_, FF_);
    wtrans_kernel<<<dim3(D_ / 32, FF_ / 32), 256, 0, stream>>>(fc2, f2t, D_, FF_);
    wtrans_kernel<<<dim3(FF_ / 32, D_ / 32), 256, 0, stream>>>(fc3, f3t, FF_, D_);

    rmsnorm_kernel<<<M, 256, 0, stream>>>(x, n1s, h);
    // fused Q+K projection: [4096][3072] = h @ [wq|wk]^T   (grid 192 % 8 == 0)
    gemm256<<<(M / 256) * (3072 / 256), 512, 0, stream>>>(h, wqkt, qkb, M, 3072, D_, M / 256);
    gemm_bt<2><<<dim3(M / 128, (KV_ * HD_) / 128), 256, 0, stream>>>(h, wvt, vtb, nullptr, M, KV_ * HD_, D_, D_);
    qknorm_rope_kernel<<<dim3(M, H_), 128, 0, stream>>>(qkb, qns, cosb, sinb, 3072);
    qknorm_rope_kernel<<<dim3(M, KV_), 128, 0, stream>>>(qkb + 2048, kns, cosb, sinb, 3072);
    fattn_kernel<<<dim3(H_ * B_, S_ / 64), 256, 0, stream>>>(qkb, qkb + 2048, vtb, qkb, 3072, 3072);
    gemm_bt<1><<<dim3(M / 128, D_ / 128), 256, 0, stream>>>(qkb, wot, x2, x, M, D_, H_ * HD_, 3072);
    rmsnorm_kernel<<<M, 256, 0, stream>>>(x2, n2s, h);
    // fused fc1+fc2: [4096][6144] = h2 @ [fc1|fc2]^T   (grid 384 % 8 == 0)
    gemm256<<<(M / 256) * (6144 / 256), 512, 0, stream>>>(h, f12t, g12, M, 6144, D_, M / 256);
    silu_mul_kernel<<<(M * FF_ / 4 + 255) / 256, 256, 0, stream>>>(g12, M * FF_ / 4);
    gemm_bt<1><<<dim3(M / 128, D_ / 128), 256, 0, stream>>>(g12, f3t, outf, x2, M, D_, FF_, 2 * FF_);
}

// Round 8
// 422.310 us; speedup vs baseline: 12.9312x; 1.0037x over previous
//
#include <hip/hip_runtime.h>

#define B_  2
#define S_  2048
#define D_  1024
#define H_  16
#define KV_ 8
#define HD_ 128
#define FF_ 3072
#define KVB 32

typedef short bf16x8 __attribute__((ext_vector_type(8)));
typedef short bf16x4 __attribute__((ext_vector_type(4)));
typedef float f32x4 __attribute__((ext_vector_type(4)));

__device__ __forceinline__ float bf2f(unsigned short u) {
    union { float f; unsigned int i; } c; c.i = ((unsigned int)u) << 16; return c.f;
}
__device__ __forceinline__ unsigned short f2bf(float f) {
    union { float f; unsigned int i; } c; c.f = f;
    unsigned int r = c.i + 0x7fffu + ((c.i >> 16) & 1u);
    return (unsigned short)(r >> 16);
}

__device__ __forceinline__ void gload_lds16(const unsigned short* g, char* ldsbase) {
    __builtin_amdgcn_global_load_lds(
        (const __attribute__((address_space(1))) unsigned int*)g,
        (__attribute__((address_space(3))) unsigned int*)ldsbase, 16, 0, 0);
}

__device__ __forceinline__ f32x4 pv_mfma(bf16x4 a, bf16x4 b, f32x4 c) {
#if __has_builtin(__builtin_amdgcn_mfma_f32_16x16x16bf16_1k)
    return __builtin_amdgcn_mfma_f32_16x16x16bf16_1k(a, b, c, 0, 0, 0);
#elif __has_builtin(__builtin_amdgcn_mfma_f32_16x16x16_bf16)
    return __builtin_amdgcn_mfma_f32_16x16x16_bf16(a, b, c, 0, 0, 0);
#else
    f32x4 d;
    asm("v_mfma_f32_16x16x16_bf16 %0, %1, %2, %3" : "=v"(d) : "v"(a), "v"(b), "v"(c));
    return d;
#endif
}

// ---------------- rmsnorm: fp32 in -> bf16 out, D=1024, one block per row ----------------
__global__ __launch_bounds__(256)
void rmsnorm_kernel(const float* __restrict__ in, const float* __restrict__ scale,
                    unsigned short* __restrict__ out) {
    const int row = blockIdx.x;
    const int t = threadIdx.x;
    const float4 v = *reinterpret_cast<const float4*>(in + (size_t)row * D_ + t * 4);
    float s = v.x * v.x + v.y * v.y + v.z * v.z + v.w * v.w;
    #pragma unroll
    for (int o = 32; o; o >>= 1) s += __shfl_down(s, o);
    __shared__ float red[4];
    const int lane = t & 63, wid = t >> 6;
    if (lane == 0) red[wid] = s;
    __syncthreads();
    s = red[0] + red[1] + red[2] + red[3];
    const float rn = rsqrtf(s * (1.0f / D_) + 1e-6f);
    const float4 sc = *reinterpret_cast<const float4*>(scale + t * 4);
    unsigned short o4[4];
    o4[0] = f2bf(v.x * rn * sc.x);
    o4[1] = f2bf(v.y * rn * sc.y);
    o4[2] = f2bf(v.z * rn * sc.z);
    o4[3] = f2bf(v.w * rn * sc.w);
    *reinterpret_cast<ushort4*>(out + (size_t)row * D_ + t * 4) =
        *reinterpret_cast<ushort4*>(o4);
}

// ---------------- weight convert+transpose: W[K][N] fp32 -> Wt[N][K] bf16 ----------------
__global__ __launch_bounds__(256)
void wtrans_kernel(const float* __restrict__ W, unsigned short* __restrict__ Wt,
                   int K, int N) {
    __shared__ float tile[32][33];
    const int t = threadIdx.x;
    const int kt = blockIdx.x * 32, nt = blockIdx.y * 32;
    {
        const int r = t >> 3, c4 = (t & 7) * 4;
        const float4 v = *reinterpret_cast<const float4*>(W + (size_t)(kt + r) * N + nt + c4);
        tile[r][c4] = v.x; tile[r][c4 + 1] = v.y; tile[r][c4 + 2] = v.z; tile[r][c4 + 3] = v.w;
    }
    __syncthreads();
    {
        const int n = t >> 3, k4 = (t & 7) * 4;
        unsigned short o[4];
        #pragma unroll
        for (int i = 0; i < 4; i++) o[i] = f2bf(tile[k4 + i][n]);
        *reinterpret_cast<ushort4*>(Wt + (size_t)(nt + n) * K + kt + k4) =
            *reinterpret_cast<ushort4*>(o);
    }
}

// =============== 256^2 GEMM, 2-phase counted-vmcnt pipeline =============================
// 8 waves (2Mx4N), BK=64, 128KiB LDS dbuf, st_16x32 swizzle (pre-swizzled source +
// swizzled ds_read). Consumption sets: phase alpha reads ALL B chunks + A-chunk 2wr;
// phase beta reads A-chunk 2wr+1. Staging split accordingly:
//   part1 = {B0,B1,B2,B3,A0,A2} (6 loads), part2 = {A1,A3} (2 loads), issue-order pinned.
// Steady state: end-of-tile vmcnt(2) certifies part1(t+1); mid-tile vmcnt(6) certifies
// part2(t). Never vmcnt(0) in-loop (prologue/epilogue only). MFMA order identical to the
// verified 2-phase kernel -> bit-identical numerics.
__global__ __launch_bounds__(512, 2)
void gemm256(const unsigned short* __restrict__ A, const unsigned short* __restrict__ Bt,
             unsigned short* __restrict__ C, int M, int N, int K, int nm) {
    __shared__ __align__(16) char lds[131072];
    const int tid = threadIdx.x;
    const int lane = tid & 63, w = tid >> 6;
    const int lm = lane & 15, lg = lane >> 4;
    const int wr = w >> 2, wc = w & 3;
    const int nwg = gridDim.x;
    const int cpx = nwg >> 3;                         // nwg % 8 == 0 (caller guarantees)
    const int bid = blockIdx.x;
    const int swz = (bid & 7) * cpx + (bid >> 3);     // bijective XCD swizzle
    const int m0 = (swz % nm) * 256;
    const int n0 = (swz / nm) * 256;

    f32x4 acc[8][4];
    #pragma unroll
    for (int i = 0; i < 8; ++i)
        #pragma unroll
        for (int j = 0; j < 4; ++j) acc[i][j] = (f32x4){0.f, 0.f, 0.f, 0.f};

    const int srow = tid >> 3;                                     // 0..63
    const int skel = ((tid & 7) * 8) ^ (((tid >> 5) & 1) << 4);    // pre-swizzled k-elem
    const int flip = ((lm >> 2) & 1) << 5;                         // read-side swizzle
    const int abase = (wr * 128 + lm) * 128 + ((lg * 16) ^ flip);
    const int bbase = (wc * 64 + lm) * 128 + ((lg * 16) ^ flip);

    auto part1 = [&](int kt, int d) {   // B0,B1,B2,B3,A0,A2 — this issue order matters
        const unsigned short* ga = A + (size_t)(m0 + srow) * K + kt * 64 + skel;
        const unsigned short* gb = Bt + (size_t)(n0 + srow) * K + kt * 64 + skel;
        char* la = lds + d * 65536 + (w << 10);
        char* lb = la + 32768;
        gload_lds16(gb,                      lb);
        gload_lds16(gb + (size_t)64 * K,     lb + 8192);
        gload_lds16(gb + (size_t)128 * K,    lb + 16384);
        gload_lds16(gb + (size_t)192 * K,    lb + 24576);
        gload_lds16(ga,                      la);
        gload_lds16(ga + (size_t)128 * K,    la + 16384);
    };
    auto part2 = [&](int kt, int d) {   // A1,A3
        const unsigned short* ga = A + (size_t)(m0 + srow) * K + kt * 64 + skel;
        char* la = lds + d * 65536 + (w << 10);
        gload_lds16(ga + (size_t)64 * K,     la + 8192);
        gload_lds16(ga + (size_t)192 * K,    la + 24576);
    };

    // prologue: full tile 0, drain once (allowed outside the loop)
    part1(0, 0);
    part2(0, 0);
    asm volatile("s_waitcnt vmcnt(0)" ::: "memory");
    __builtin_amdgcn_s_barrier();

    const int ntile = K >> 6;
    for (int kt = 0; kt < ntile; ++kt) {
        const int d = kt & 1;
        const bool pf = (kt + 1 < ntile);
        const char* Ar = lds + d * 65536;
        const char* Br = Ar + 32768;
        // ---- phase alpha: all B + A-chunk 2wr; issue part1(t+1); MFMA acc[0..3]
        bf16x8 bb[4][2];
        #pragma unroll
        for (int nf = 0; nf < 4; ++nf)
            #pragma unroll
            for (int s = 0; s < 2; ++s)
                bb[nf][s] = *reinterpret_cast<const bf16x8*>(Br + bbase + nf * 2048 + s * 64);
        bf16x8 aH[4][2];
        #pragma unroll
        for (int f = 0; f < 4; ++f)
            #pragma unroll
            for (int s = 0; s < 2; ++s)
                aH[f][s] = *reinterpret_cast<const bf16x8*>(Ar + abase + f * 2048 + s * 64);
        if (pf) part1(kt + 1, d ^ 1);
        __builtin_amdgcn_s_setprio(1);
        #pragma unroll
        for (int f = 0; f < 4; ++f)
            #pragma unroll
            for (int nf = 0; nf < 4; ++nf)
                #pragma unroll
                for (int s = 0; s < 2; ++s)
                    acc[f][nf] = __builtin_amdgcn_mfma_f32_16x16x32_bf16(
                        aH[f][s], bb[nf][s], acc[f][nf], 0, 0, 0);
        __builtin_amdgcn_s_setprio(0);
        // certify part2(t): outstanding = 2 old (part2 t) + [6 new if pf]
        if (pf) asm volatile("s_waitcnt vmcnt(6)" ::: "memory");
        else    asm volatile("s_waitcnt vmcnt(0)" ::: "memory");
        __builtin_amdgcn_s_barrier();
        // ---- phase beta: A-chunk 2wr+1; issue part2(t+1); MFMA acc[4..7]
        #pragma unroll
        for (int f = 0; f < 4; ++f)
            #pragma unroll
            for (int s = 0; s < 2; ++s)
                aH[f][s] = *reinterpret_cast<const bf16x8*>(Ar + abase + 8192 + f * 2048 + s * 64);
        if (pf) part2(kt + 1, d ^ 1);
        __builtin_amdgcn_s_setprio(1);
        #pragma unroll
        for (int f = 0; f < 4; ++f)
            #pragma unroll
            for (int nf = 0; nf < 4; ++nf)
                #pragma unroll
                for (int s = 0; s < 2; ++s)
                    acc[4 + f][nf] = __builtin_amdgcn_mfma_f32_16x16x32_bf16(
                        aH[f][s], bb[nf][s], acc[4 + f][nf], 0, 0, 0);
        __builtin_amdgcn_s_setprio(0);
        if (pf) {
            // certify part1(t+1): outstanding = 6 (part1 t+1) + 2 (part2 t+1)
            asm volatile("s_waitcnt vmcnt(2)" ::: "memory");
            __builtin_amdgcn_s_barrier();
        }
    }

    #pragma unroll
    for (int mf = 0; mf < 8; ++mf)
        #pragma unroll
        for (int nf = 0; nf < 4; ++nf)
            #pragma unroll
            for (int r = 0; r < 4; ++r)
                C[(size_t)(m0 + wr * 128 + mf * 16 + lg * 4 + r) * N +
                  (n0 + wc * 64 + nf * 16 + lm)] = f2bf(acc[mf][nf][r]);
}

// ---------------- m97-structure GEMM: C[M,N] = A(bf16 [M][lda]) @ Bt(bf16 [N][K])^T ------
template<int EPI>
__global__ __launch_bounds__(256)
void gemm_bt(const unsigned short* __restrict__ A, const unsigned short* __restrict__ Bt,
             void* __restrict__ Cout, const float* __restrict__ resid,
             int M, int N, int K, int lda) {
    constexpr int SMB = (EPI == 2) ? 34816 : 16384;
    __shared__ __align__(16) char sm[SMB];
    const int t = threadIdx.x;
    const int lane = t & 63, w = t >> 6;
    const int m0 = blockIdx.x * 128, n0 = blockIdx.y * 128;
    const int wr = w >> 1, wc = w & 1;
    const int lm = lane & 15, lg = lane >> 4;

    f32x4 acc[4][4];
    #pragma unroll
    for (int i = 0; i < 4; i++)
        #pragma unroll
        for (int j = 0; j < 4; j++) acc[i][j] = (f32x4){0.f, 0.f, 0.f, 0.f};

    const int row0 = t >> 2, kseg = (t & 3) * 8;
    const unsigned short* Ab = A + (size_t)(m0 + row0) * lda + kseg;
    const unsigned short* Bb = Bt + (size_t)(n0 + row0) * K + kseg;
    const size_t rstepA = (size_t)64 * lda;
    const size_t rstepB = (size_t)64 * K;
    char* ldsA = sm + w * 1024;
    char* ldsB = sm + 8192 + w * 1024;

    for (int k0 = 0; k0 < K; k0 += 32) {
        gload_lds16(Ab + k0, ldsA);
        gload_lds16(Ab + rstepA + k0, ldsA + 4096);
        gload_lds16(Bb + k0, ldsB);
        gload_lds16(Bb + rstepB + k0, ldsB + 4096);
        __syncthreads();
        bf16x8 aF[4], bF[4];
        #pragma unroll
        for (int i = 0; i < 4; i++)
            aF[i] = *reinterpret_cast<const bf16x8*>(sm + (wr * 64 + i * 16 + lm) * 64 + lg * 16);
        #pragma unroll
        for (int j = 0; j < 4; j++)
            bF[j] = *reinterpret_cast<const bf16x8*>(sm + 8192 + (wc * 64 + j * 16 + lm) * 64 + lg * 16);
        #pragma unroll
        for (int i = 0; i < 4; i++)
            #pragma unroll
            for (int j = 0; j < 4; j++)
                acc[i][j] = __builtin_amdgcn_mfma_f32_16x16x32_bf16(aF[i], bF[j], acc[i][j], 0, 0, 0);
        __syncthreads();
    }

    if (EPI == 2) {
        unsigned short (*Ct)[136] = reinterpret_cast<unsigned short(*)[136]>(sm);
        #pragma unroll
        for (int i = 0; i < 4; i++)
            #pragma unroll
            for (int j = 0; j < 4; j++)
                #pragma unroll
                for (int r = 0; r < 4; r++)
                    Ct[wc * 64 + j * 16 + lm][wr * 64 + i * 16 + lg * 4 + r] = f2bf(acc[i][j][r]);
        __syncthreads();
        const int colr = t >> 1, seg = t & 1;
        unsigned short* dst = reinterpret_cast<unsigned short*>(Cout) +
                              (size_t)(n0 + colr) * M + m0 + seg * 64;
        const unsigned short* srcp = &Ct[colr][seg * 64];
        #pragma unroll
        for (int i = 0; i < 8; i++)
            reinterpret_cast<uint4*>(dst)[i] = reinterpret_cast<const uint4*>(srcp)[i];
        return;
    }

    #pragma unroll
    for (int i = 0; i < 4; i++) {
        #pragma unroll
        for (int j = 0; j < 4; j++) {
            #pragma unroll
            for (int r = 0; r < 4; r++) {
                const int row = m0 + wr * 64 + i * 16 + lg * 4 + r;
                const int col = n0 + wc * 64 + j * 16 + lm;
                const size_t idx = (size_t)row * N + col;
                if (EPI == 0) {
                    reinterpret_cast<unsigned short*>(Cout)[idx] = f2bf(acc[i][j][r]);
                } else {
                    reinterpret_cast<float*>(Cout)[idx] = resid[idx] + acc[i][j][r];
                }
            }
        }
    }
}

// ---------------- per-head rmsnorm + rope, in-place on strided bf16 q/k ----------------
__global__ __launch_bounds__(128)
void qknorm_rope_kernel(unsigned short* __restrict__ qk, const float* __restrict__ scale,
                        const float* __restrict__ cosb, const float* __restrict__ sinb,
                        int ld) {
    const int row = blockIdx.x;
    const int head = blockIdx.y;
    const int s = row & (S_ - 1);
    const int t = threadIdx.x;
    unsigned short* p = qk + (size_t)row * ld + head * HD_;
    const float v = bf2f(p[t]);
    float ss = v * v;
    #pragma unroll
    for (int o = 32; o; o >>= 1) ss += __shfl_down(ss, o);
    __shared__ float red[2];
    __shared__ float vals[HD_];
    const int lane = t & 63, wid = t >> 6;
    if (lane == 0) red[wid] = ss;
    __syncthreads();
    ss = red[0] + red[1];
    const float rn = rsqrtf(ss * (1.0f / HD_) + 1e-6f);
    const float nv = v * rn * scale[t];
    vals[t] = nv;
    __syncthreads();
    const float rot = (t < 64) ? -vals[t + 64] : vals[t - 64];
    const float c = cosb[(size_t)s * HD_ + t];
    const float sn = sinb[(size_t)s * HD_ + t];
    p[t] = f2bf(nv * c + rot * sn);
}

// ---------------- MFMA flash attention v2: LPT order + dbuf pipeline, causal GQA --------
__global__ __launch_bounds__(256)
void fattn_kernel(const unsigned short* __restrict__ qg,
                  const unsigned short* __restrict__ kg,
                  const unsigned short* __restrict__ vtg,
                  unsigned short* __restrict__ out, int qld, int kld) {
    __shared__ __align__(16) char klds[2 * 8192];    // [buf][32 rows x 256B], xor-swizzled
    __shared__ __align__(16) char vtlds[2 * 9216];   // [buf][128 rows x 72B pitch]
    const int t = threadIdx.x;
    const int lane = t & 63, w = t >> 6;
    const int lm = lane & 15, lg = lane >> 4;
    const int g = blockIdx.x;                 // (b,h) group -> XCD locality
    const int h = g & 15, b = g >> 4;
    const int qt = (int)gridDim.y - 1 - (int)blockIdx.y;   // LPT: big blocks first
    const int kvh = h >> 1;
    const int q0b = qt * 64;
    const int q0w = q0b + w * 16;
    const float CS = 0.12752409731504826f;    // (1/sqrt(128)) * log2(e)

    const unsigned short* qbase = qg + (size_t)(b * S_ + q0w + lm) * qld + h * HD_;
    bf16x8 qf[4];
    #pragma unroll
    for (int kk = 0; kk < 4; ++kk)
        qf[kk] = *reinterpret_cast<const bf16x8*>(qbase + kk * 32 + lg * 8);

    f32x4 acc[8];
    #pragma unroll
    for (int i = 0; i < 8; ++i) acc[i] = (f32x4){0.f, 0.f, 0.f, 0.f};
    float m = -3e38f, l = 0.f;

    const int nt = 2 * qt + 2;
    const int skv = t >> 3, sd8 = t & 7;   // K staging coords
    const int vd = t >> 1, vseg = t & 1;   // V staging coords
    const unsigned short* kgb = kg + (size_t)b * S_ * kld + kvh * HD_;
    const unsigned short* vgb = vtg + (size_t)(kvh * HD_) * (B_ * S_) + (size_t)b * S_;

    uint4 kr0, kr1, vr0, vr1;
    auto LOADR = [&](int kt) {
        const int kv0 = kt * KVB;
        const unsigned short* ksrc = kgb + (size_t)(kv0 + skv) * kld + sd8 * 16;
        kr0 = *reinterpret_cast<const uint4*>(ksrc);
        kr1 = *reinterpret_cast<const uint4*>(ksrc + 8);
        const unsigned short* vsrc = vgb + (size_t)vd * (B_ * S_) + kv0 + vseg * 16;
        vr0 = *reinterpret_cast<const uint4*>(vsrc);
        vr1 = *reinterpret_cast<const uint4*>(vsrc + 8);
    };
    auto WRITELDS = [&](int bufi) {
        char* kd = klds + bufi * 8192 + skv * 256;
        const int sw = (skv & 7) << 4;
        *reinterpret_cast<uint4*>(kd + ((sd8 * 32) ^ sw)) = kr0;
        *reinterpret_cast<uint4*>(kd + ((sd8 * 32 + 16) ^ sw)) = kr1;
        char* vdst = vtlds + bufi * 9216 + vd * 72 + vseg * 32;
        *reinterpret_cast<uint2*>(vdst)      = make_uint2(vr0.x, vr0.y);
        *reinterpret_cast<uint2*>(vdst + 8)  = make_uint2(vr0.z, vr0.w);
        *reinterpret_cast<uint2*>(vdst + 16) = make_uint2(vr1.x, vr1.y);
        *reinterpret_cast<uint2*>(vdst + 24) = make_uint2(vr1.z, vr1.w);
    };

    LOADR(0);
    WRITELDS(0);
    __syncthreads();

    for (int kt = 0; kt < nt; ++kt) {
        const int kv0 = kt * KVB;
        const int bufi = kt & 1;
        const bool havenext = (kt + 1 < nt);
        if (havenext) LOADR(kt + 1);
        if (kv0 <= q0w + 15) {
            f32x4 st[2];
            st[0] = (f32x4){0.f, 0.f, 0.f, 0.f};
            st[1] = (f32x4){0.f, 0.f, 0.f, 0.f};
            #pragma unroll
            for (int sub = 0; sub < 2; ++sub) {
                const int kvl = sub * 16 + lm;
                const char* krow = klds + bufi * 8192 + kvl * 256;
                const int sw = (kvl & 7) << 4;
                #pragma unroll
                for (int kk = 0; kk < 4; ++kk) {
                    const bf16x8 kf = *reinterpret_cast<const bf16x8*>(krow + ((kk * 64 + lg * 16) ^ sw));
                    st[sub] = __builtin_amdgcn_mfma_f32_16x16x32_bf16(kf, qf[kk], st[sub], 0, 0, 0);
                }
            }
            if (kv0 + KVB - 1 > q0w) {
                const int qa = q0w + lm;
                #pragma unroll
                for (int sub = 0; sub < 2; ++sub)
                    #pragma unroll
                    for (int r = 0; r < 4; ++r)
                        if (kv0 + sub * 16 + lg * 4 + r > qa) st[sub][r] = -3e38f;
            }
            float pmax = st[0][0];
            #pragma unroll
            for (int r = 1; r < 4; ++r) pmax = fmaxf(pmax, st[0][r]);
            #pragma unroll
            for (int r = 0; r < 4; ++r) pmax = fmaxf(pmax, st[1][r]);
            pmax = fmaxf(pmax, __shfl_xor(pmax, 16));
            pmax = fmaxf(pmax, __shfl_xor(pmax, 32));
            if (__any(pmax - m > 8.0f)) {       // defer-max (T13)
                const float mn = fmaxf(pmax, m);
                const float corr = exp2f((m - mn) * CS);
                l *= corr;
                #pragma unroll
                for (int i = 0; i < 8; ++i) acc[i] *= corr;
                m = mn;
            }
            float ps = 0.f;
            bf16x4 pb[2];
            #pragma unroll
            for (int sub = 0; sub < 2; ++sub)
                #pragma unroll
                for (int r = 0; r < 4; ++r) {
                    const float pv = exp2f((st[sub][r] - m) * CS);
                    ps += pv;
                    pb[sub][r] = (short)f2bf(pv);
                }
            ps += __shfl_xor(ps, 16);
            ps += __shfl_xor(ps, 32);
            l += ps;
            #pragma unroll
            for (int sub = 0; sub < 2; ++sub) {
                const char* vb2 = vtlds + bufi * 9216 + sub * 32 + lg * 8;
                #pragma unroll
                for (int db = 0; db < 8; ++db) {
                    const bf16x4 vf = *reinterpret_cast<const bf16x4*>(vb2 + (db * 16 + lm) * 72);
                    acc[db] = pv_mfma(vf, pb[sub], acc[db]);
                }
            }
        }
        if (havenext) WRITELDS((kt + 1) & 1);
        __syncthreads();
    }
    const float inv = 1.0f / l;
    unsigned short* ob = out + (size_t)(b * S_ + q0w + lm) * qld + h * HD_ + lg * 4;
    #pragma unroll
    for (int db = 0; db < 8; ++db) {
        unsigned short r4[4];
        #pragma unroll
        for (int r = 0; r < 4; ++r) r4[r] = f2bf(acc[db][r] * inv);
        *reinterpret_cast<uint2*>(ob + db * 16) = *reinterpret_cast<uint2*>(r4);
    }
}

// ---------------- silu(g12[:, :3072]) * g12[:, 3072:] -> g12[:, :3072] in place ----------
__global__ __launch_bounds__(256)
void silu_mul_kernel(unsigned short* __restrict__ g, int n4) {
    const int i = blockIdx.x * 256 + threadIdx.x;
    if (i >= n4) return;
    const int r = i / (FF_ / 4);
    const int c = (i - r * (FF_ / 4)) * 4;
    const size_t off = (size_t)r * (2 * FF_) + c;
    const uint2 a = *reinterpret_cast<const uint2*>(g + off);
    const uint2 bv = *reinterpret_cast<const uint2*>(g + off + FF_);
    const unsigned int au[2] = {a.x, a.y}, bu[2] = {bv.x, bv.y};
    unsigned int rr[2];
    #pragma unroll
    for (int j = 0; j < 2; j++) {
        const float a0 = bf2f((unsigned short)(au[j] & 0xffff));
        const float a1 = bf2f((unsigned short)(au[j] >> 16));
        const float b0 = bf2f((unsigned short)(bu[j] & 0xffff));
        const float b1 = bf2f((unsigned short)(bu[j] >> 16));
        const float s0 = a0 / (1.f + __expf(-a0)) * b0;
        const float s1 = a1 / (1.f + __expf(-a1)) * b1;
        rr[j] = ((unsigned int)f2bf(s1) << 16) | (unsigned int)f2bf(s0);
    }
    *reinterpret_cast<uint2*>(g + off) = make_uint2(rr[0], rr[1]);
}

extern "C" void kernel_launch(void* const* d_in, const int* in_sizes, int n_in,
                              void* d_out, int out_size, void* d_ws, size_t ws_size,
                              hipStream_t stream) {
    const float* x    = (const float*)d_in[0];
    const float* cosb = (const float*)d_in[2];
    const float* sinb = (const float*)d_in[3];
    const float* wq   = (const float*)d_in[4];
    const float* wk   = (const float*)d_in[5];
    const float* wv   = (const float*)d_in[6];
    const float* wo   = (const float*)d_in[7];
    const float* fc1  = (const float*)d_in[8];
    const float* fc2  = (const float*)d_in[9];
    const float* fc3  = (const float*)d_in[10];
    const float* n1s  = (const float*)d_in[11];
    const float* n2s  = (const float*)d_in[12];
    const float* qns  = (const float*)d_in[13];
    const float* kns  = (const float*)d_in[14];

    char* ws = (char*)d_ws;
    const int M = B_ * S_;  // 4096
    float* outf = (float*)d_out;

    // ws layout (bytes), total 106,954,752:
    //  h    @0         8 MiB  (bf16 4096x1024)
    //  qkb  @8388608   24 MiB (bf16 4096x3072: q cols 0-2047, k cols 2048-3071)
    //  vtb  @33554432  8 MiB  (bf16 V^T [1024][4096])
    //  g12  @8388608   48 MiB (bf16 4096x6144; aliases qkb+vtb, both dead by fc12)
    //  x2   @58720256  16 MiB (fp32)
    //  wqt|wkt @75497472 contiguous -> fused QK weight [3072][1024]
    //  wvt @81788928  wot @83886080
    //  f1t|f2t @88080384 contiguous -> fused fc12 weight [6144][1024]
    //  f3t @100663296
    unsigned short* h    = (unsigned short*)(ws);
    unsigned short* qkb  = (unsigned short*)(ws + 8388608);
    unsigned short* vtb  = (unsigned short*)(ws + 33554432);
    unsigned short* g12  = (unsigned short*)(ws + 8388608);
    float*          x2   = (float*)(ws + 58720256);
    unsigned short* wqkt = (unsigned short*)(ws + 75497472);
    unsigned short* wvt  = (unsigned short*)(ws + 81788928);
    unsigned short* wot  = (unsigned short*)(ws + 83886080);
    unsigned short* f12t = (unsigned short*)(ws + 88080384);
    unsigned short* f3t  = (unsigned short*)(ws + 100663296);
    unsigned short* wqt = wqkt;
    unsigned short* wkt = wqkt + (size_t)2048 * 1024;
    unsigned short* f1t = f12t;
    unsigned short* f2t = f12t + (size_t)3072 * 1024;

    wtrans_kernel<<<dim3(D_ / 32, (H_ * HD_) / 32), 256, 0, stream>>>(wq, wqt, D_, H_ * HD_);
    wtrans_kernel<<<dim3(D_ / 32, (KV_ * HD_) / 32), 256, 0, stream>>>(wk, wkt, D_, KV_ * HD_);
    wtrans_kernel<<<dim3(D_ / 32, (KV_ * HD_) / 32), 256, 0, stream>>>(wv, wvt, D_, KV_ * HD_);
    wtrans_kernel<<<dim3((H_ * HD_) / 32, D_ / 32), 256, 0, stream>>>(wo, wot, H_ * HD_, D_);
    wtrans_kernel<<<dim3(D_ / 32, FF_ / 32), 256, 0, stream>>>(fc1, f1t, D_, FF_);
    wtrans_kernel<<<dim3(D_ / 32, FF_ / 32), 256, 0, stream>>>(fc2, f2t, D_, FF_);
    wtrans_kernel<<<dim3(FF_ / 32, D_ / 32), 256, 0, stream>>>(fc3, f3t, FF_, D_);

    rmsnorm_kernel<<<M, 256, 0, stream>>>(x, n1s, h);
    // fused Q+K projection: [4096][3072] = h @ [wq|wk]^T   (grid 192 % 8 == 0)
    gemm256<<<(M / 256) * (3072 / 256), 512, 0, stream>>>(h, wqkt, qkb, M, 3072, D_, M / 256);
    gemm_bt<2><<<dim3(M / 128, (KV_ * HD_) / 128), 256, 0, stream>>>(h, wvt, vtb, nullptr, M, KV_ * HD_, D_, D_);
    qknorm_rope_kernel<<<dim3(M, H_), 128, 0, stream>>>(qkb, qns, cosb, sinb, 3072);
    qknorm_rope_kernel<<<dim3(M, KV_), 128, 0, stream>>>(qkb + 2048, kns, cosb, sinb, 3072);
    fattn_kernel<<<dim3(H_ * B_, S_ / 64), 256, 0, stream>>>(qkb, qkb + 2048, vtb, qkb, 3072, 3072);
    gemm_bt<1><<<dim3(M / 128, D_ / 128), 256, 0, stream>>>(qkb, wot, x2, x, M, D_, H_ * HD_, 3072);
    rmsnorm_kernel<<<M, 256, 0, stream>>>(x2, n2s, h);
    // fused fc1+fc2: [4096][6144] = h2 @ [fc1|fc2]^T   (grid 384 % 8 == 0)
    gemm256<<<(M / 256) * (6144 / 256), 512, 0, stream>>>(h, f12t, g12, M, 6144, D_, M / 256);
    silu_mul_kernel<<<(M * FF_ / 4 + 255) / 256, 256, 0, stream>>>(g12, M * FF_ / 4);
    gemm_bt<1><<<dim3(M / 128, D_ / 128), 256, 0, stream>>>(g12, f3t, outf, x2, M, D_, FF_, 2 * FF_);
}

// Round 9
// 393.791 us; speedup vs baseline: 13.8677x; 1.0724x over previous
//
#include <hip/hip_runtime.h>

#define B_  2
#define S_  2048
#define D_  1024
#define H_  16
#define KV_ 8
#define HD_ 128
#define FF_ 3072
#define KVB 32

typedef short bf16x8 __attribute__((ext_vector_type(8)));
typedef short bf16x4 __attribute__((ext_vector_type(4)));
typedef float f32x4 __attribute__((ext_vector_type(4)));

__device__ __forceinline__ float bf2f(unsigned short u) {
    union { float f; unsigned int i; } c; c.i = ((unsigned int)u) << 16; return c.f;
}
__device__ __forceinline__ unsigned short f2bf(float f) {
    union { float f; unsigned int i; } c; c.f = f;
    unsigned int r = c.i + 0x7fffu + ((c.i >> 16) & 1u);
    return (unsigned short)(r >> 16);
}

__device__ __forceinline__ void gload_lds16(const unsigned short* g, char* ldsbase) {
    __builtin_amdgcn_global_load_lds(
        (const __attribute__((address_space(1))) unsigned int*)g,
        (__attribute__((address_space(3))) unsigned int*)ldsbase, 16, 0, 0);
}

__device__ __forceinline__ f32x4 pv_mfma(bf16x4 a, bf16x4 b, f32x4 c) {
#if __has_builtin(__builtin_amdgcn_mfma_f32_16x16x16bf16_1k)
    return __builtin_amdgcn_mfma_f32_16x16x16bf16_1k(a, b, c, 0, 0, 0);
#elif __has_builtin(__builtin_amdgcn_mfma_f32_16x16x16_bf16)
    return __builtin_amdgcn_mfma_f32_16x16x16_bf16(a, b, c, 0, 0, 0);
#else
    f32x4 d;
    asm("v_mfma_f32_16x16x16_bf16 %0, %1, %2, %3" : "=v"(d) : "v"(a), "v"(b), "v"(c));
    return d;
#endif
}

// ---------------- rmsnorm: fp32 in -> bf16 out, D=1024, one block per row ----------------
__global__ __launch_bounds__(256)
void rmsnorm_kernel(const float* __restrict__ in, const float* __restrict__ scale,
                    unsigned short* __restrict__ out) {
    const int row = blockIdx.x;
    const int t = threadIdx.x;
    const float4 v = *reinterpret_cast<const float4*>(in + (size_t)row * D_ + t * 4);
    float s = v.x * v.x + v.y * v.y + v.z * v.z + v.w * v.w;
    #pragma unroll
    for (int o = 32; o; o >>= 1) s += __shfl_down(s, o);
    __shared__ float red[4];
    const int lane = t & 63, wid = t >> 6;
    if (lane == 0) red[wid] = s;
    __syncthreads();
    s = red[0] + red[1] + red[2] + red[3];
    const float rn = rsqrtf(s * (1.0f / D_) + 1e-6f);
    const float4 sc = *reinterpret_cast<const float4*>(scale + t * 4);
    unsigned short o4[4];
    o4[0] = f2bf(v.x * rn * sc.x);
    o4[1] = f2bf(v.y * rn * sc.y);
    o4[2] = f2bf(v.z * rn * sc.z);
    o4[3] = f2bf(v.w * rn * sc.w);
    *reinterpret_cast<ushort4*>(out + (size_t)row * D_ + t * 4) =
        *reinterpret_cast<ushort4*>(o4);
}

// ---------------- batched weight transpose: 7 weights, one launch ----------------
struct WTDesc {
    const float* src[7];
    unsigned short* dst[7];
    int K[7];
    int N[7];
    int start[8];
};

__global__ __launch_bounds__(256)
void wtrans_all_kernel(WTDesc d) {
    __shared__ float tile[32][33];
    const int blk = blockIdx.x;
    int i = 0;
    #pragma unroll
    for (int j = 0; j < 7; ++j) if (blk >= d.start[j + 1]) i = j + 1;
    const int local = blk - d.start[i];
    const int K = d.K[i], N = d.N[i];
    const int nkt = K >> 5;
    const int kt = (local % nkt) * 32, nt = (local / nkt) * 32;
    const float* W = d.src[i];
    unsigned short* Wt = d.dst[i];
    const int t = threadIdx.x;
    {
        const int r = t >> 3, c4 = (t & 7) * 4;
        const float4 v = *reinterpret_cast<const float4*>(W + (size_t)(kt + r) * N + nt + c4);
        tile[r][c4] = v.x; tile[r][c4 + 1] = v.y; tile[r][c4 + 2] = v.z; tile[r][c4 + 3] = v.w;
    }
    __syncthreads();
    {
        const int n = t >> 3, k4 = (t & 7) * 4;
        unsigned short o[4];
        #pragma unroll
        for (int q = 0; q < 4; q++) o[q] = f2bf(tile[k4 + q][n]);
        *reinterpret_cast<ushort4*>(Wt + (size_t)(nt + n) * K + kt + k4) =
            *reinterpret_cast<ushort4*>(o);
    }
}

// ---------------- V transpose: vin[m][n] (ld 4096) -> vt[n][m] (ld 4096), bf16 ----------
__global__ __launch_bounds__(256)
void vtrans_kernel(const unsigned short* __restrict__ vin, unsigned short* __restrict__ vt) {
    __shared__ unsigned short tile[32][36];
    const int t = threadIdx.x;
    const int mt = blockIdx.x * 32, nt = blockIdx.y * 32;
    {
        const int r = t >> 3, c4 = (t & 7) * 4;
        *reinterpret_cast<ushort4*>(&tile[r][c4]) =
            *reinterpret_cast<const ushort4*>(vin + (size_t)(mt + r) * 4096 + nt + c4);
    }
    __syncthreads();
    {
        const int n = t >> 3, m4 = (t & 7) * 4;
        unsigned short o[4];
        #pragma unroll
        for (int q = 0; q < 4; q++) o[q] = tile[m4 + q][n];
        *reinterpret_cast<ushort4*>(vt + (size_t)(nt + n) * 4096 + mt + m4) =
            *reinterpret_cast<ushort4*>(o);
    }
}

// =============== 256^2 GEMM, 2-phase counted-vmcnt pipeline =============================
// 8 waves (2Mx4N), BK=64, 128KiB LDS dbuf, st_16x32 swizzle (pre-swizzled source +
// swizzled ds_read). part1 = {B0..B3,A0,A2}, part2 = {A1,A3}; mid-tile vmcnt(6) certifies
// part2(t), end-tile vmcnt(2) certifies part1(t+1). Verified passing (round 8).
__global__ __launch_bounds__(512, 2)
void gemm256(const unsigned short* __restrict__ A, const unsigned short* __restrict__ Bt,
             unsigned short* __restrict__ C, int M, int N, int K, int nm) {
    __shared__ __align__(16) char lds[131072];
    const int tid = threadIdx.x;
    const int lane = tid & 63, w = tid >> 6;
    const int lm = lane & 15, lg = lane >> 4;
    const int wr = w >> 2, wc = w & 3;
    const int nwg = gridDim.x;
    const int cpx = nwg >> 3;                         // nwg % 8 == 0 (caller guarantees)
    const int bid = blockIdx.x;
    const int swz = (bid & 7) * cpx + (bid >> 3);     // bijective XCD swizzle
    const int m0 = (swz % nm) * 256;
    const int n0 = (swz / nm) * 256;

    f32x4 acc[8][4];
    #pragma unroll
    for (int i = 0; i < 8; ++i)
        #pragma unroll
        for (int j = 0; j < 4; ++j) acc[i][j] = (f32x4){0.f, 0.f, 0.f, 0.f};

    const int srow = tid >> 3;                                     // 0..63
    const int skel = ((tid & 7) * 8) ^ (((tid >> 5) & 1) << 4);    // pre-swizzled k-elem
    const int flip = ((lm >> 2) & 1) << 5;                         // read-side swizzle
    const int abase = (wr * 128 + lm) * 128 + ((lg * 16) ^ flip);
    const int bbase = (wc * 64 + lm) * 128 + ((lg * 16) ^ flip);

    auto part1 = [&](int kt, int d) {   // B0,B1,B2,B3,A0,A2 — issue order pinned
        const unsigned short* ga = A + (size_t)(m0 + srow) * K + kt * 64 + skel;
        const unsigned short* gb = Bt + (size_t)(n0 + srow) * K + kt * 64 + skel;
        char* la = lds + d * 65536 + (w << 10);
        char* lb = la + 32768;
        gload_lds16(gb,                      lb);
        gload_lds16(gb + (size_t)64 * K,     lb + 8192);
        gload_lds16(gb + (size_t)128 * K,    lb + 16384);
        gload_lds16(gb + (size_t)192 * K,    lb + 24576);
        gload_lds16(ga,                      la);
        gload_lds16(ga + (size_t)128 * K,    la + 16384);
    };
    auto part2 = [&](int kt, int d) {   // A1,A3
        const unsigned short* ga = A + (size_t)(m0 + srow) * K + kt * 64 + skel;
        char* la = lds + d * 65536 + (w << 10);
        gload_lds16(ga + (size_t)64 * K,     la + 8192);
        gload_lds16(ga + (size_t)192 * K,    la + 24576);
    };

    part1(0, 0);
    part2(0, 0);
    asm volatile("s_waitcnt vmcnt(0)" ::: "memory");
    __builtin_amdgcn_s_barrier();

    const int ntile = K >> 6;
    for (int kt = 0; kt < ntile; ++kt) {
        const int d = kt & 1;
        const bool pf = (kt + 1 < ntile);
        const char* Ar = lds + d * 65536;
        const char* Br = Ar + 32768;
        bf16x8 bb[4][2];
        #pragma unroll
        for (int nf = 0; nf < 4; ++nf)
            #pragma unroll
            for (int s = 0; s < 2; ++s)
                bb[nf][s] = *reinterpret_cast<const bf16x8*>(Br + bbase + nf * 2048 + s * 64);
        bf16x8 aH[4][2];
        #pragma unroll
        for (int f = 0; f < 4; ++f)
            #pragma unroll
            for (int s = 0; s < 2; ++s)
                aH[f][s] = *reinterpret_cast<const bf16x8*>(Ar + abase + f * 2048 + s * 64);
        if (pf) part1(kt + 1, d ^ 1);
        __builtin_amdgcn_s_setprio(1);
        #pragma unroll
        for (int f = 0; f < 4; ++f)
            #pragma unroll
            for (int nf = 0; nf < 4; ++nf)
                #pragma unroll
                for (int s = 0; s < 2; ++s)
                    acc[f][nf] = __builtin_amdgcn_mfma_f32_16x16x32_bf16(
                        aH[f][s], bb[nf][s], acc[f][nf], 0, 0, 0);
        __builtin_amdgcn_s_setprio(0);
        if (pf) asm volatile("s_waitcnt vmcnt(6)" ::: "memory");
        else    asm volatile("s_waitcnt vmcnt(0)" ::: "memory");
        __builtin_amdgcn_s_barrier();
        #pragma unroll
        for (int f = 0; f < 4; ++f)
            #pragma unroll
            for (int s = 0; s < 2; ++s)
                aH[f][s] = *reinterpret_cast<const bf16x8*>(Ar + abase + 8192 + f * 2048 + s * 64);
        if (pf) part2(kt + 1, d ^ 1);
        __builtin_amdgcn_s_setprio(1);
        #pragma unroll
        for (int f = 0; f < 4; ++f)
            #pragma unroll
            for (int nf = 0; nf < 4; ++nf)
                #pragma unroll
                for (int s = 0; s < 2; ++s)
                    acc[4 + f][nf] = __builtin_amdgcn_mfma_f32_16x16x32_bf16(
                        aH[f][s], bb[nf][s], acc[4 + f][nf], 0, 0, 0);
        __builtin_amdgcn_s_setprio(0);
        if (pf) {
            asm volatile("s_waitcnt vmcnt(2)" ::: "memory");
            __builtin_amdgcn_s_barrier();
        }
    }

    #pragma unroll
    for (int mf = 0; mf < 8; ++mf)
        #pragma unroll
        for (int nf = 0; nf < 4; ++nf)
            #pragma unroll
            for (int r = 0; r < 4; ++r)
                C[(size_t)(m0 + wr * 128 + mf * 16 + lg * 4 + r) * N +
                  (n0 + wc * 64 + nf * 16 + lm)] = f2bf(acc[mf][nf][r]);
}

// ---------------- m97-structure GEMM: C[M,N] = A(bf16 [M][lda]) @ Bt(bf16 [N][K])^T ------
// EPI 1: fp32 C = resid + acc.
template<int EPI>
__global__ __launch_bounds__(256)
void gemm_bt(const unsigned short* __restrict__ A, const unsigned short* __restrict__ Bt,
             void* __restrict__ Cout, const float* __restrict__ resid,
             int M, int N, int K, int lda) {
    __shared__ __align__(16) char sm[16384];
    const int t = threadIdx.x;
    const int lane = t & 63, w = t >> 6;
    const int m0 = blockIdx.x * 128, n0 = blockIdx.y * 128;
    const int wr = w >> 1, wc = w & 1;
    const int lm = lane & 15, lg = lane >> 4;

    f32x4 acc[4][4];
    #pragma unroll
    for (int i = 0; i < 4; i++)
        #pragma unroll
        for (int j = 0; j < 4; j++) acc[i][j] = (f32x4){0.f, 0.f, 0.f, 0.f};

    const int row0 = t >> 2, kseg = (t & 3) * 8;
    const unsigned short* Ab = A + (size_t)(m0 + row0) * lda + kseg;
    const unsigned short* Bb = Bt + (size_t)(n0 + row0) * K + kseg;
    const size_t rstepA = (size_t)64 * lda;
    const size_t rstepB = (size_t)64 * K;
    char* ldsA = sm + w * 1024;
    char* ldsB = sm + 8192 + w * 1024;

    for (int k0 = 0; k0 < K; k0 += 32) {
        gload_lds16(Ab + k0, ldsA);
        gload_lds16(Ab + rstepA + k0, ldsA + 4096);
        gload_lds16(Bb + k0, ldsB);
        gload_lds16(Bb + rstepB + k0, ldsB + 4096);
        __syncthreads();
        bf16x8 aF[4], bF[4];
        #pragma unroll
        for (int i = 0; i < 4; i++)
            aF[i] = *reinterpret_cast<const bf16x8*>(sm + (wr * 64 + i * 16 + lm) * 64 + lg * 16);
        #pragma unroll
        for (int j = 0; j < 4; j++)
            bF[j] = *reinterpret_cast<const bf16x8*>(sm + 8192 + (wc * 64 + j * 16 + lm) * 64 + lg * 16);
        #pragma unroll
        for (int i = 0; i < 4; i++)
            #pragma unroll
            for (int j = 0; j < 4; j++)
                acc[i][j] = __builtin_amdgcn_mfma_f32_16x16x32_bf16(aF[i], bF[j], acc[i][j], 0, 0, 0);
        __syncthreads();
    }

    #pragma unroll
    for (int i = 0; i < 4; i++) {
        #pragma unroll
        for (int j = 0; j < 4; j++) {
            #pragma unroll
            for (int r = 0; r < 4; r++) {
                const int row = m0 + wr * 64 + i * 16 + lg * 4 + r;
                const int col = n0 + wc * 64 + j * 16 + lm;
                const size_t idx = (size_t)row * N + col;
                if (EPI == 0) {
                    reinterpret_cast<unsigned short*>(Cout)[idx] = f2bf(acc[i][j][r]);
                } else {
                    reinterpret_cast<float*>(Cout)[idx] = resid[idx] + acc[i][j][r];
                }
            }
        }
    }
}

// ---------------- per-head rmsnorm + rope, in-place on strided bf16 q/k ----------------
__global__ __launch_bounds__(128)
void qknorm_rope_kernel(unsigned short* __restrict__ qk, const float* __restrict__ scale,
                        const float* __restrict__ cosb, const float* __restrict__ sinb,
                        int ld) {
    const int row = blockIdx.x;
    const int head = blockIdx.y;
    const int s = row & (S_ - 1);
    const int t = threadIdx.x;
    unsigned short* p = qk + (size_t)row * ld + head * HD_;
    const float v = bf2f(p[t]);
    float ss = v * v;
    #pragma unroll
    for (int o = 32; o; o >>= 1) ss += __shfl_down(ss, o);
    __shared__ float red[2];
    __shared__ float vals[HD_];
    const int lane = t & 63, wid = t >> 6;
    if (lane == 0) red[wid] = ss;
    __syncthreads();
    ss = red[0] + red[1];
    const float rn = rsqrtf(ss * (1.0f / HD_) + 1e-6f);
    const float nv = v * rn * scale[t];
    vals[t] = nv;
    __syncthreads();
    const float rot = (t < 64) ? -vals[t + 64] : vals[t - 64];
    const float c = cosb[(size_t)s * HD_ + t];
    const float sn = sinb[(size_t)s * HD_ + t];
    p[t] = f2bf(nv * c + rot * sn);
}

// ---------------- MFMA flash attention v2: LPT order + dbuf pipeline, causal GQA --------
__global__ __launch_bounds__(256)
void fattn_kernel(const unsigned short* __restrict__ qg,
                  const unsigned short* __restrict__ kg,
                  const unsigned short* __restrict__ vtg,
                  unsigned short* __restrict__ out, int qld, int kld) {
    __shared__ __align__(16) char klds[2 * 8192];    // [buf][32 rows x 256B], xor-swizzled
    __shared__ __align__(16) char vtlds[2 * 9216];   // [buf][128 rows x 72B pitch]
    const int t = threadIdx.x;
    const int lane = t & 63, w = t >> 6;
    const int lm = lane & 15, lg = lane >> 4;
    const int g = blockIdx.x;                 // (b,h) group -> XCD locality
    const int h = g & 15, b = g >> 4;
    const int qt = (int)gridDim.y - 1 - (int)blockIdx.y;   // LPT: big blocks first
    const int kvh = h >> 1;
    const int q0b = qt * 64;
    const int q0w = q0b + w * 16;
    const float CS = 0.12752409731504826f;    // (1/sqrt(128)) * log2(e)

    const unsigned short* qbase = qg + (size_t)(b * S_ + q0w + lm) * qld + h * HD_;
    bf16x8 qf[4];
    #pragma unroll
    for (int kk = 0; kk < 4; ++kk)
        qf[kk] = *reinterpret_cast<const bf16x8*>(qbase + kk * 32 + lg * 8);

    f32x4 acc[8];
    #pragma unroll
    for (int i = 0; i < 8; ++i) acc[i] = (f32x4){0.f, 0.f, 0.f, 0.f};
    float m = -3e38f, l = 0.f;

    const int nt = 2 * qt + 2;
    const int skv = t >> 3, sd8 = t & 7;   // K staging coords
    const int vd = t >> 1, vseg = t & 1;   // V staging coords
    const unsigned short* kgb = kg + (size_t)b * S_ * kld + kvh * HD_;
    const unsigned short* vgb = vtg + (size_t)(kvh * HD_) * (B_ * S_) + (size_t)b * S_;

    uint4 kr0, kr1, vr0, vr1;
    auto LOADR = [&](int kt) {
        const int kv0 = kt * KVB;
        const unsigned short* ksrc = kgb + (size_t)(kv0 + skv) * kld + sd8 * 16;
        kr0 = *reinterpret_cast<const uint4*>(ksrc);
        kr1 = *reinterpret_cast<const uint4*>(ksrc + 8);
        const unsigned short* vsrc = vgb + (size_t)vd * (B_ * S_) + kv0 + vseg * 16;
        vr0 = *reinterpret_cast<const uint4*>(vsrc);
        vr1 = *reinterpret_cast<const uint4*>(vsrc + 8);
    };
    auto WRITELDS = [&](int bufi) {
        char* kd = klds + bufi * 8192 + skv * 256;
        const int sw = (skv & 7) << 4;
        *reinterpret_cast<uint4*>(kd + ((sd8 * 32) ^ sw)) = kr0;
        *reinterpret_cast<uint4*>(kd + ((sd8 * 32 + 16) ^ sw)) = kr1;
        char* vdst = vtlds + bufi * 9216 + vd * 72 + vseg * 32;
        *reinterpret_cast<uint2*>(vdst)      = make_uint2(vr0.x, vr0.y);
        *reinterpret_cast<uint2*>(vdst + 8)  = make_uint2(vr0.z, vr0.w);
        *reinterpret_cast<uint2*>(vdst + 16) = make_uint2(vr1.x, vr1.y);
        *reinterpret_cast<uint2*>(vdst + 24) = make_uint2(vr1.z, vr1.w);
    };

    LOADR(0);
    WRITELDS(0);
    __syncthreads();

    for (int kt = 0; kt < nt; ++kt) {
        const int kv0 = kt * KVB;
        const int bufi = kt & 1;
        const bool havenext = (kt + 1 < nt);
        if (havenext) LOADR(kt + 1);
        if (kv0 <= q0w + 15) {
            f32x4 st[2];
            st[0] = (f32x4){0.f, 0.f, 0.f, 0.f};
            st[1] = (f32x4){0.f, 0.f, 0.f, 0.f};
            #pragma unroll
            for (int sub = 0; sub < 2; ++sub) {
                const int kvl = sub * 16 + lm;
                const char* krow = klds + bufi * 8192 + kvl * 256;
                const int sw = (kvl & 7) << 4;
                #pragma unroll
                for (int kk = 0; kk < 4; ++kk) {
                    const bf16x8 kf = *reinterpret_cast<const bf16x8*>(krow + ((kk * 64 + lg * 16) ^ sw));
                    st[sub] = __builtin_amdgcn_mfma_f32_16x16x32_bf16(kf, qf[kk], st[sub], 0, 0, 0);
                }
            }
            if (kv0 + KVB - 1 > q0w) {
                const int qa = q0w + lm;
                #pragma unroll
                for (int sub = 0; sub < 2; ++sub)
                    #pragma unroll
                    for (int r = 0; r < 4; ++r)
                        if (kv0 + sub * 16 + lg * 4 + r > qa) st[sub][r] = -3e38f;
            }
            float pmax = st[0][0];
            #pragma unroll
            for (int r = 1; r < 4; ++r) pmax = fmaxf(pmax, st[0][r]);
            #pragma unroll
            for (int r = 0; r < 4; ++r) pmax = fmaxf(pmax, st[1][r]);
            pmax = fmaxf(pmax, __shfl_xor(pmax, 16));
            pmax = fmaxf(pmax, __shfl_xor(pmax, 32));
            if (__any(pmax - m > 8.0f)) {       // defer-max (T13)
                const float mn = fmaxf(pmax, m);
                const float corr = exp2f((m - mn) * CS);
                l *= corr;
                #pragma unroll
                for (int i = 0; i < 8; ++i) acc[i] *= corr;
                m = mn;
            }
            float ps = 0.f;
            bf16x4 pb[2];
            #pragma unroll
            for (int sub = 0; sub < 2; ++sub)
                #pragma unroll
                for (int r = 0; r < 4; ++r) {
                    const float pv = exp2f((st[sub][r] - m) * CS);
                    ps += pv;
                    pb[sub][r] = (short)f2bf(pv);
                }
            ps += __shfl_xor(ps, 16);
            ps += __shfl_xor(ps, 32);
            l += ps;
            #pragma unroll
            for (int sub = 0; sub < 2; ++sub) {
                const char* vb2 = vtlds + bufi * 9216 + sub * 32 + lg * 8;
                #pragma unroll
                for (int db = 0; db < 8; ++db) {
                    const bf16x4 vf = *reinterpret_cast<const bf16x4*>(vb2 + (db * 16 + lm) * 72);
                    acc[db] = pv_mfma(vf, pb[sub], acc[db]);
                }
            }
        }
        if (havenext) WRITELDS((kt + 1) & 1);
        __syncthreads();
    }
    const float inv = 1.0f / l;
    unsigned short* ob = out + (size_t)(b * S_ + q0w + lm) * qld + h * HD_ + lg * 4;
    #pragma unroll
    for (int db = 0; db < 8; ++db) {
        unsigned short r4[4];
        #pragma unroll
        for (int r = 0; r < 4; ++r) r4[r] = f2bf(acc[db][r] * inv);
        *reinterpret_cast<uint2*>(ob + db * 16) = *reinterpret_cast<uint2*>(r4);
    }
}

// ---------------- silu(g12[:, :3072]) * g12[:, 3072:] -> g12[:, :3072] in place ----------
__global__ __launch_bounds__(256)
void silu_mul_kernel(unsigned short* __restrict__ g, int n4) {
    const int i = blockIdx.x * 256 + threadIdx.x;
    if (i >= n4) return;
    const int r = i / (FF_ / 4);
    const int c = (i - r * (FF_ / 4)) * 4;
    const size_t off = (size_t)r * (2 * FF_) + c;
    const uint2 a = *reinterpret_cast<const uint2*>(g + off);
    const uint2 bv = *reinterpret_cast<const uint2*>(g + off + FF_);
    const unsigned int au[2] = {a.x, a.y}, bu[2] = {bv.x, bv.y};
    unsigned int rr[2];
    #pragma unroll
    for (int j = 0; j < 2; j++) {
        const float a0 = bf2f((unsigned short)(au[j] & 0xffff));
        const float a1 = bf2f((unsigned short)(au[j] >> 16));
        const float b0 = bf2f((unsigned short)(bu[j] & 0xffff));
        const float b1 = bf2f((unsigned short)(bu[j] >> 16));
        const float s0 = a0 / (1.f + __expf(-a0)) * b0;
        const float s1 = a1 / (1.f + __expf(-a1)) * b1;
        rr[j] = ((unsigned int)f2bf(s1) << 16) | (unsigned int)f2bf(s0);
    }
    *reinterpret_cast<uint2*>(g + off) = make_uint2(rr[0], rr[1]);
}

extern "C" void kernel_launch(void* const* d_in, const int* in_sizes, int n_in,
                              void* d_out, int out_size, void* d_ws, size_t ws_size,
                              hipStream_t stream) {
    const float* x    = (const float*)d_in[0];
    const float* cosb = (const float*)d_in[2];
    const float* sinb = (const float*)d_in[3];
    const float* wq   = (const float*)d_in[4];
    const float* wk   = (const float*)d_in[5];
    const float* wv   = (const float*)d_in[6];
    const float* wo   = (const float*)d_in[7];
    const float* fc1  = (const float*)d_in[8];
    const float* fc2  = (const float*)d_in[9];
    const float* fc3  = (const float*)d_in[10];
    const float* n1s  = (const float*)d_in[11];
    const float* n2s  = (const float*)d_in[12];
    const float* qns  = (const float*)d_in[13];
    const float* kns  = (const float*)d_in[14];

    char* ws = (char*)d_ws;
    const int M = B_ * S_;  // 4096
    float* outf = (float*)d_out;

    // ws layout (bytes), total 106,954,752:
    //  h     @0         8 MiB  (bf16 4096x1024)
    //  qkvb  @8388608   32 MiB (bf16 4096x4096: q [0,2048) k [2048,3072) v [3072,4096))
    //  vtb   @41943040  8 MiB  (bf16 V^T [1024][4096])
    //  g12   @8388608   48 MiB (bf16 4096x6144; aliases qkvb+vtb, dead by fc12)
    //  x2    @58720256  16 MiB (fp32)
    //  wqkvt @75497472  8 MiB  ([wq|wk|wv]^T [4096][1024])
    //  wot   @83886080  4 MiB  f12t @88080384 12 MiB  f3t @100663296 6 MiB
    unsigned short* h     = (unsigned short*)(ws);
    unsigned short* qkvb  = (unsigned short*)(ws + 8388608);
    unsigned short* vtb   = (unsigned short*)(ws + 41943040);
    unsigned short* g12   = (unsigned short*)(ws + 8388608);
    float*          x2    = (float*)(ws + 58720256);
    unsigned short* wqkvt = (unsigned short*)(ws + 75497472);
    unsigned short* wot   = (unsigned short*)(ws + 83886080);
    unsigned short* f12t  = (unsigned short*)(ws + 88080384);
    unsigned short* f3t   = (unsigned short*)(ws + 100663296);

    // batched weight transpose: block counts = (K/32)*(N/32)
    WTDesc wd;
    wd.src[0] = wq;  wd.dst[0] = wqkvt;                         wd.K[0] = D_;       wd.N[0] = 2048;
    wd.src[1] = wk;  wd.dst[1] = wqkvt + (size_t)2048 * 1024;   wd.K[1] = D_;       wd.N[1] = 1024;
    wd.src[2] = wv;  wd.dst[2] = wqkvt + (size_t)3072 * 1024;   wd.K[2] = D_;       wd.N[2] = 1024;
    wd.src[3] = wo;  wd.dst[3] = wot;                           wd.K[3] = H_ * HD_; wd.N[3] = D_;
    wd.src[4] = fc1; wd.dst[4] = f12t;                          wd.K[4] = D_;       wd.N[4] = FF_;
    wd.src[5] = fc2; wd.dst[5] = f12t + (size_t)3072 * 1024;    wd.K[5] = D_;       wd.N[5] = FF_;
    wd.src[6] = fc3; wd.dst[6] = f3t;                           wd.K[6] = FF_;      wd.N[6] = D_;
    wd.start[0] = 0;
    for (int i = 0; i < 7; ++i)
        wd.start[i + 1] = wd.start[i] + (wd.K[i] / 32) * (wd.N[i] / 32);
    wtrans_all_kernel<<<wd.start[7], 256, 0, stream>>>(wd);

    rmsnorm_kernel<<<M, 256, 0, stream>>>(x, n1s, h);
    // fused Q+K+V projection: [4096][4096] = h @ [wq|wk|wv]^T  (grid 256, %8==0, 1 blk/CU)
    gemm256<<<(M / 256) * (4096 / 256), 512, 0, stream>>>(h, wqkvt, qkvb, M, 4096, D_, M / 256);
    vtrans_kernel<<<dim3(M / 32, 1024 / 32), 256, 0, stream>>>(qkvb + 3072, vtb);
    qknorm_rope_kernel<<<dim3(M, H_), 128, 0, stream>>>(qkvb, qns, cosb, sinb, 4096);
    qknorm_rope_kernel<<<dim3(M, KV_), 128, 0, stream>>>(qkvb + 2048, kns, cosb, sinb, 4096);
    fattn_kernel<<<dim3(H_ * B_, S_ / 64), 256, 0, stream>>>(qkvb, qkvb + 2048, vtb, qkvb, 4096, 4096);
    gemm_bt<1><<<dim3(M / 128, D_ / 128), 256, 0, stream>>>(qkvb, wot, x2, x, M, D_, H_ * HD_, 4096);
    rmsnorm_kernel<<<M, 256, 0, stream>>>(x2, n2s, h);
    // fused fc1+fc2: [4096][6144] = h2 @ [fc1|fc2]^T   (grid 384 % 8 == 0)
    gemm256<<<(M / 256) * (6144 / 256), 512, 0, stream>>>(h, f12t, g12, M, 6144, D_, M / 256);
    silu_mul_kernel<<<(M * FF_ / 4 + 255) / 256, 256, 0, stream>>>(g12, M * FF_ / 4);
    gemm_bt<1><<<dim3(M / 128, D_ / 128), 256, 0, stream>>>(g12, f3t, outf, x2, M, D_, FF_, 2 * FF_);
}

// Round 10
// 392.225 us; speedup vs baseline: 13.9230x; 1.0040x over previous
//
#include <hip/hip_runtime.h>

#define B_  2
#define S_  2048
#define D_  1024
#define H_  16
#define KV_ 8
#define HD_ 128
#define FF_ 3072
#define KVB 32

typedef short bf16x8 __attribute__((ext_vector_type(8)));
typedef short bf16x4 __attribute__((ext_vector_type(4)));
typedef float f32x4 __attribute__((ext_vector_type(4)));

__device__ __forceinline__ float bf2f(unsigned short u) {
    union { float f; unsigned int i; } c; c.i = ((unsigned int)u) << 16; return c.f;
}
__device__ __forceinline__ unsigned short f2bf(float f) {
    union { float f; unsigned int i; } c; c.f = f;
    unsigned int r = c.i + 0x7fffu + ((c.i >> 16) & 1u);
    return (unsigned short)(r >> 16);
}
__device__ __forceinline__ unsigned int cvtpk_bf16(float lo, float hi) {
    unsigned int r;
    asm("v_cvt_pk_bf16_f32 %0, %1, %2" : "=v"(r) : "v"(lo), "v"(hi));
    return r;
}

__device__ __forceinline__ void gload_lds16(const unsigned short* g, char* ldsbase) {
    __builtin_amdgcn_global_load_lds(
        (const __attribute__((address_space(1))) unsigned int*)g,
        (__attribute__((address_space(3))) unsigned int*)ldsbase, 16, 0, 0);
}

__device__ __forceinline__ f32x4 pv_mfma(bf16x4 a, bf16x4 b, f32x4 c) {
#if __has_builtin(__builtin_amdgcn_mfma_f32_16x16x16bf16_1k)
    return __builtin_amdgcn_mfma_f32_16x16x16bf16_1k(a, b, c, 0, 0, 0);
#elif __has_builtin(__builtin_amdgcn_mfma_f32_16x16x16_bf16)
    return __builtin_amdgcn_mfma_f32_16x16x16_bf16(a, b, c, 0, 0, 0);
#else
    f32x4 d;
    asm("v_mfma_f32_16x16x16_bf16 %0, %1, %2, %3" : "=v"(d) : "v"(a), "v"(b), "v"(c));
    return d;
#endif
}

// ---------------- rmsnorm: fp32 in -> bf16 out, D=1024, one block per row ----------------
__global__ __launch_bounds__(256)
void rmsnorm_kernel(const float* __restrict__ in, const float* __restrict__ scale,
                    unsigned short* __restrict__ out) {
    const int row = blockIdx.x;
    const int t = threadIdx.x;
    const float4 v = *reinterpret_cast<const float4*>(in + (size_t)row * D_ + t * 4);
    float s = v.x * v.x + v.y * v.y + v.z * v.z + v.w * v.w;
    #pragma unroll
    for (int o = 32; o; o >>= 1) s += __shfl_down(s, o);
    __shared__ float red[4];
    const int lane = t & 63, wid = t >> 6;
    if (lane == 0) red[wid] = s;
    __syncthreads();
    s = red[0] + red[1] + red[2] + red[3];
    const float rn = rsqrtf(s * (1.0f / D_) + 1e-6f);
    const float4 sc = *reinterpret_cast<const float4*>(scale + t * 4);
    unsigned short o4[4];
    o4[0] = f2bf(v.x * rn * sc.x);
    o4[1] = f2bf(v.y * rn * sc.y);
    o4[2] = f2bf(v.z * rn * sc.z);
    o4[3] = f2bf(v.w * rn * sc.w);
    *reinterpret_cast<ushort4*>(out + (size_t)row * D_ + t * 4) =
        *reinterpret_cast<ushort4*>(o4);
}

// ---------------- batched weight transpose: 7 weights, one launch ----------------
struct WTDesc {
    const float* src[7];
    unsigned short* dst[7];
    int K[7];
    int N[7];
    int start[8];
};

__global__ __launch_bounds__(256)
void wtrans_all_kernel(WTDesc d) {
    __shared__ float tile[32][33];
    const int blk = blockIdx.x;
    int i = 0;
    #pragma unroll
    for (int j = 0; j < 7; ++j) if (blk >= d.start[j + 1]) i = j + 1;
    const int local = blk - d.start[i];
    const int K = d.K[i], N = d.N[i];
    const int nkt = K >> 5;
    const int kt = (local % nkt) * 32, nt = (local / nkt) * 32;
    const float* W = d.src[i];
    unsigned short* Wt = d.dst[i];
    const int t = threadIdx.x;
    {
        const int r = t >> 3, c4 = (t & 7) * 4;
        const float4 v = *reinterpret_cast<const float4*>(W + (size_t)(kt + r) * N + nt + c4);
        tile[r][c4] = v.x; tile[r][c4 + 1] = v.y; tile[r][c4 + 2] = v.z; tile[r][c4 + 3] = v.w;
    }
    __syncthreads();
    {
        const int n = t >> 3, k4 = (t & 7) * 4;
        unsigned short o[4];
        #pragma unroll
        for (int q = 0; q < 4; q++) o[q] = f2bf(tile[k4 + q][n]);
        *reinterpret_cast<ushort4*>(Wt + (size_t)(nt + n) * K + kt + k4) =
            *reinterpret_cast<ushort4*>(o);
    }
}

// ---------------- V transpose: vin[m][n] (ld 4096) -> vt[n][m] (ld 4096), bf16 ----------
__global__ __launch_bounds__(256)
void vtrans_kernel(const unsigned short* __restrict__ vin, unsigned short* __restrict__ vt) {
    __shared__ unsigned short tile[32][36];
    const int t = threadIdx.x;
    const int mt = blockIdx.x * 32, nt = blockIdx.y * 32;
    {
        const int r = t >> 3, c4 = (t & 7) * 4;
        *reinterpret_cast<ushort4*>(&tile[r][c4]) =
            *reinterpret_cast<const ushort4*>(vin + (size_t)(mt + r) * 4096 + nt + c4);
    }
    __syncthreads();
    {
        const int n = t >> 3, m4 = (t & 7) * 4;
        unsigned short o[4];
        #pragma unroll
        for (int q = 0; q < 4; q++) o[q] = tile[m4 + q][n];
        *reinterpret_cast<ushort4*>(vt + (size_t)(nt + n) * 4096 + mt + m4) =
            *reinterpret_cast<ushort4*>(o);
    }
}

// =============== 256^2 GEMM, 2-phase counted-vmcnt pipeline (verified round 8) ===========
__global__ __launch_bounds__(512, 2)
void gemm256(const unsigned short* __restrict__ A, const unsigned short* __restrict__ Bt,
             unsigned short* __restrict__ C, int M, int N, int K, int nm) {
    __shared__ __align__(16) char lds[131072];
    const int tid = threadIdx.x;
    const int lane = tid & 63, w = tid >> 6;
    const int lm = lane & 15, lg = lane >> 4;
    const int wr = w >> 2, wc = w & 3;
    const int nwg = gridDim.x;
    const int cpx = nwg >> 3;                         // nwg % 8 == 0 (caller guarantees)
    const int bid = blockIdx.x;
    const int swz = (bid & 7) * cpx + (bid >> 3);     // bijective XCD swizzle
    const int m0 = (swz % nm) * 256;
    const int n0 = (swz / nm) * 256;

    f32x4 acc[8][4];
    #pragma unroll
    for (int i = 0; i < 8; ++i)
        #pragma unroll
        for (int j = 0; j < 4; ++j) acc[i][j] = (f32x4){0.f, 0.f, 0.f, 0.f};

    const int srow = tid >> 3;                                     // 0..63
    const int skel = ((tid & 7) * 8) ^ (((tid >> 5) & 1) << 4);    // pre-swizzled k-elem
    const int flip = ((lm >> 2) & 1) << 5;                         // read-side swizzle
    const int abase = (wr * 128 + lm) * 128 + ((lg * 16) ^ flip);
    const int bbase = (wc * 64 + lm) * 128 + ((lg * 16) ^ flip);

    auto part1 = [&](int kt, int d) {   // B0,B1,B2,B3,A0,A2 — issue order pinned
        const unsigned short* ga = A + (size_t)(m0 + srow) * K + kt * 64 + skel;
        const unsigned short* gb = Bt + (size_t)(n0 + srow) * K + kt * 64 + skel;
        char* la = lds + d * 65536 + (w << 10);
        char* lb = la + 32768;
        gload_lds16(gb,                      lb);
        gload_lds16(gb + (size_t)64 * K,     lb + 8192);
        gload_lds16(gb + (size_t)128 * K,    lb + 16384);
        gload_lds16(gb + (size_t)192 * K,    lb + 24576);
        gload_lds16(ga,                      la);
        gload_lds16(ga + (size_t)128 * K,    la + 16384);
    };
    auto part2 = [&](int kt, int d) {   // A1,A3
        const unsigned short* ga = A + (size_t)(m0 + srow) * K + kt * 64 + skel;
        char* la = lds + d * 65536 + (w << 10);
        gload_lds16(ga + (size_t)64 * K,     la + 8192);
        gload_lds16(ga + (size_t)192 * K,    la + 24576);
    };

    part1(0, 0);
    part2(0, 0);
    asm volatile("s_waitcnt vmcnt(0)" ::: "memory");
    __builtin_amdgcn_s_barrier();

    const int ntile = K >> 6;
    for (int kt = 0; kt < ntile; ++kt) {
        const int d = kt & 1;
        const bool pf = (kt + 1 < ntile);
        const char* Ar = lds + d * 65536;
        const char* Br = Ar + 32768;
        bf16x8 bb[4][2];
        #pragma unroll
        for (int nf = 0; nf < 4; ++nf)
            #pragma unroll
            for (int s = 0; s < 2; ++s)
                bb[nf][s] = *reinterpret_cast<const bf16x8*>(Br + bbase + nf * 2048 + s * 64);
        bf16x8 aH[4][2];
        #pragma unroll
        for (int f = 0; f < 4; ++f)
            #pragma unroll
            for (int s = 0; s < 2; ++s)
                aH[f][s] = *reinterpret_cast<const bf16x8*>(Ar + abase + f * 2048 + s * 64);
        if (pf) part1(kt + 1, d ^ 1);
        __builtin_amdgcn_s_setprio(1);
        #pragma unroll
        for (int f = 0; f < 4; ++f)
            #pragma unroll
            for (int nf = 0; nf < 4; ++nf)
                #pragma unroll
                for (int s = 0; s < 2; ++s)
                    acc[f][nf] = __builtin_amdgcn_mfma_f32_16x16x32_bf16(
                        aH[f][s], bb[nf][s], acc[f][nf], 0, 0, 0);
        __builtin_amdgcn_s_setprio(0);
        if (pf) asm volatile("s_waitcnt vmcnt(6)" ::: "memory");
        else    asm volatile("s_waitcnt vmcnt(0)" ::: "memory");
        __builtin_amdgcn_s_barrier();
        #pragma unroll
        for (int f = 0; f < 4; ++f)
            #pragma unroll
            for (int s = 0; s < 2; ++s)
                aH[f][s] = *reinterpret_cast<const bf16x8*>(Ar + abase + 8192 + f * 2048 + s * 64);
        if (pf) part2(kt + 1, d ^ 1);
        __builtin_amdgcn_s_setprio(1);
        #pragma unroll
        for (int f = 0; f < 4; ++f)
            #pragma unroll
            for (int nf = 0; nf < 4; ++nf)
                #pragma unroll
                for (int s = 0; s < 2; ++s)
                    acc[4 + f][nf] = __builtin_amdgcn_mfma_f32_16x16x32_bf16(
                        aH[f][s], bb[nf][s], acc[4 + f][nf], 0, 0, 0);
        __builtin_amdgcn_s_setprio(0);
        if (pf) {
            asm volatile("s_waitcnt vmcnt(2)" ::: "memory");
            __builtin_amdgcn_s_barrier();
        }
    }

    #pragma unroll
    for (int mf = 0; mf < 8; ++mf)
        #pragma unroll
        for (int nf = 0; nf < 4; ++nf)
            #pragma unroll
            for (int r = 0; r < 4; ++r)
                C[(size_t)(m0 + wr * 128 + mf * 16 + lg * 4 + r) * N +
                  (n0 + wc * 64 + nf * 16 + lm)] = f2bf(acc[mf][nf][r]);
}

// ---------------- m97-structure GEMM: C[M,N] = A(bf16 [M][lda]) @ Bt(bf16 [N][K])^T ------
template<int EPI>
__global__ __launch_bounds__(256)
void gemm_bt(const unsigned short* __restrict__ A, const unsigned short* __restrict__ Bt,
             void* __restrict__ Cout, const float* __restrict__ resid,
             int M, int N, int K, int lda) {
    __shared__ __align__(16) char sm[16384];
    const int t = threadIdx.x;
    const int lane = t & 63, w = t >> 6;
    const int m0 = blockIdx.x * 128, n0 = blockIdx.y * 128;
    const int wr = w >> 1, wc = w & 1;
    const int lm = lane & 15, lg = lane >> 4;

    f32x4 acc[4][4];
    #pragma unroll
    for (int i = 0; i < 4; i++)
        #pragma unroll
        for (int j = 0; j < 4; j++) acc[i][j] = (f32x4){0.f, 0.f, 0.f, 0.f};

    const int row0 = t >> 2, kseg = (t & 3) * 8;
    const unsigned short* Ab = A + (size_t)(m0 + row0) * lda + kseg;
    const unsigned short* Bb = Bt + (size_t)(n0 + row0) * K + kseg;
    const size_t rstepA = (size_t)64 * lda;
    const size_t rstepB = (size_t)64 * K;
    char* ldsA = sm + w * 1024;
    char* ldsB = sm + 8192 + w * 1024;

    for (int k0 = 0; k0 < K; k0 += 32) {
        gload_lds16(Ab + k0, ldsA);
        gload_lds16(Ab + rstepA + k0, ldsA + 4096);
        gload_lds16(Bb + k0, ldsB);
        gload_lds16(Bb + rstepB + k0, ldsB + 4096);
        __syncthreads();
        bf16x8 aF[4], bF[4];
        #pragma unroll
        for (int i = 0; i < 4; i++)
            aF[i] = *reinterpret_cast<const bf16x8*>(sm + (wr * 64 + i * 16 + lm) * 64 + lg * 16);
        #pragma unroll
        for (int j = 0; j < 4; j++)
            bF[j] = *reinterpret_cast<const bf16x8*>(sm + 8192 + (wc * 64 + j * 16 + lm) * 64 + lg * 16);
        #pragma unroll
        for (int i = 0; i < 4; i++)
            #pragma unroll
            for (int j = 0; j < 4; j++)
                acc[i][j] = __builtin_amdgcn_mfma_f32_16x16x32_bf16(aF[i], bF[j], acc[i][j], 0, 0, 0);
        __syncthreads();
    }

    #pragma unroll
    for (int i = 0; i < 4; i++) {
        #pragma unroll
        for (int j = 0; j < 4; j++) {
            #pragma unroll
            for (int r = 0; r < 4; r++) {
                const int row = m0 + wr * 64 + i * 16 + lg * 4 + r;
                const int col = n0 + wc * 64 + j * 16 + lm;
                const size_t idx = (size_t)row * N + col;
                if (EPI == 0) {
                    reinterpret_cast<unsigned short*>(Cout)[idx] = f2bf(acc[i][j][r]);
                } else {
                    reinterpret_cast<float*>(Cout)[idx] = resid[idx] + acc[i][j][r];
                }
            }
        }
    }
}

// ---------------- per-head rmsnorm + rope, in-place, with output scale ----------------
__global__ __launch_bounds__(128)
void qknorm_rope_kernel(unsigned short* __restrict__ qk, const float* __restrict__ scale,
                        const float* __restrict__ cosb, const float* __restrict__ sinb,
                        int ld, float oscale) {
    const int row = blockIdx.x;
    const int head = blockIdx.y;
    const int s = row & (S_ - 1);
    const int t = threadIdx.x;
    unsigned short* p = qk + (size_t)row * ld + head * HD_;
    const float v = bf2f(p[t]);
    float ss = v * v;
    #pragma unroll
    for (int o = 32; o; o >>= 1) ss += __shfl_down(ss, o);
    __shared__ float red[2];
    __shared__ float vals[HD_];
    const int lane = t & 63, wid = t >> 6;
    if (lane == 0) red[wid] = ss;
    __syncthreads();
    ss = red[0] + red[1];
    const float rn = rsqrtf(ss * (1.0f / HD_) + 1e-6f);
    const float nv = v * rn * scale[t];
    vals[t] = nv;
    __syncthreads();
    const float rot = (t < 64) ? -vals[t + 64] : vals[t - 64];
    const float c = cosb[(size_t)s * HD_ + t];
    const float sn = sinb[(size_t)s * HD_ + t];
    p[t] = f2bf((nv * c + rot * sn) * oscale);
}

// ---------------- MFMA flash attention v3: VALU-diet (cvt_pk + log2-domain Q) ----------
// Q pre-scaled by log2(e)/sqrt(128) at rope time -> scores in log2 domain; exp2 direct.
__global__ __launch_bounds__(256)
void fattn_kernel(const unsigned short* __restrict__ qg,
                  const unsigned short* __restrict__ kg,
                  const unsigned short* __restrict__ vtg,
                  unsigned short* __restrict__ out, int qld, int kld) {
    __shared__ __align__(16) char klds[2 * 8192];    // [buf][32 rows x 256B], xor-swizzled
    __shared__ __align__(16) char vtlds[2 * 9216];   // [buf][128 rows x 72B pitch]
    const int t = threadIdx.x;
    const int lane = t & 63, w = t >> 6;
    const int lm = lane & 15, lg = lane >> 4;
    const int g = blockIdx.x;                 // (b,h) group -> XCD locality
    const int h = g & 15, b = g >> 4;
    const int qt = (int)gridDim.y - 1 - (int)blockIdx.y;   // LPT: big blocks first
    const int kvh = h >> 1;
    const int q0b = qt * 64;
    const int q0w = q0b + w * 16;

    const unsigned short* qbase = qg + (size_t)(b * S_ + q0w + lm) * qld + h * HD_;
    bf16x8 qf[4];
    #pragma unroll
    for (int kk = 0; kk < 4; ++kk)
        qf[kk] = *reinterpret_cast<const bf16x8*>(qbase + kk * 32 + lg * 8);

    f32x4 acc[8];
    #pragma unroll
    for (int i = 0; i < 8; ++i) acc[i] = (f32x4){0.f, 0.f, 0.f, 0.f};
    float m = -3e38f, l = 0.f;

    const int nt = 2 * qt + 2;
    const int skv = t >> 3, sd8 = t & 7;   // K staging coords
    const int vd = t >> 1, vseg = t & 1;   // V staging coords
    const unsigned short* kgb = kg + (size_t)b * S_ * kld + kvh * HD_;
    const unsigned short* vgb = vtg + (size_t)(kvh * HD_) * (B_ * S_) + (size_t)b * S_;

    uint4 kr0, kr1, vr0, vr1;
    auto LOADR = [&](int kt) {
        const int kv0 = kt * KVB;
        const unsigned short* ksrc = kgb + (size_t)(kv0 + skv) * kld + sd8 * 16;
        kr0 = *reinterpret_cast<const uint4*>(ksrc);
        kr1 = *reinterpret_cast<const uint4*>(ksrc + 8);
        const unsigned short* vsrc = vgb + (size_t)vd * (B_ * S_) + kv0 + vseg * 16;
        vr0 = *reinterpret_cast<const uint4*>(vsrc);
        vr1 = *reinterpret_cast<const uint4*>(vsrc + 8);
    };
    auto WRITELDS = [&](int bufi) {
        char* kd = klds + bufi * 8192 + skv * 256;
        const int sw = (skv & 7) << 4;
        *reinterpret_cast<uint4*>(kd + ((sd8 * 32) ^ sw)) = kr0;
        *reinterpret_cast<uint4*>(kd + ((sd8 * 32 + 16) ^ sw)) = kr1;
        char* vdst = vtlds + bufi * 9216 + vd * 72 + vseg * 32;
        *reinterpret_cast<uint2*>(vdst)      = make_uint2(vr0.x, vr0.y);
        *reinterpret_cast<uint2*>(vdst + 8)  = make_uint2(vr0.z, vr0.w);
        *reinterpret_cast<uint2*>(vdst + 16) = make_uint2(vr1.x, vr1.y);
        *reinterpret_cast<uint2*>(vdst + 24) = make_uint2(vr1.z, vr1.w);
    };

    LOADR(0);
    WRITELDS(0);
    __syncthreads();

    for (int kt = 0; kt < nt; ++kt) {
        const int kv0 = kt * KVB;
        const int bufi = kt & 1;
        const bool havenext = (kt + 1 < nt);
        if (havenext) LOADR(kt + 1);
        if (kv0 <= q0w + 15) {
            f32x4 st[2];
            st[0] = (f32x4){0.f, 0.f, 0.f, 0.f};
            st[1] = (f32x4){0.f, 0.f, 0.f, 0.f};
            #pragma unroll
            for (int sub = 0; sub < 2; ++sub) {
                const int kvl = sub * 16 + lm;
                const char* krow = klds + bufi * 8192 + kvl * 256;
                const int sw = (kvl & 7) << 4;
                #pragma unroll
                for (int kk = 0; kk < 4; ++kk) {
                    const bf16x8 kf = *reinterpret_cast<const bf16x8*>(krow + ((kk * 64 + lg * 16) ^ sw));
                    st[sub] = __builtin_amdgcn_mfma_f32_16x16x32_bf16(kf, qf[kk], st[sub], 0, 0, 0);
                }
            }
            if (kv0 + KVB - 1 > q0w) {
                const int qa = q0w + lm;
                #pragma unroll
                for (int sub = 0; sub < 2; ++sub)
                    #pragma unroll
                    for (int r = 0; r < 4; ++r)
                        if (kv0 + sub * 16 + lg * 4 + r > qa) st[sub][r] = -3e38f;
            }
            float pmax = st[0][0];
            #pragma unroll
            for (int r = 1; r < 4; ++r) pmax = fmaxf(pmax, st[0][r]);
            #pragma unroll
            for (int r = 0; r < 4; ++r) pmax = fmaxf(pmax, st[1][r]);
            pmax = fmaxf(pmax, __shfl_xor(pmax, 16));
            pmax = fmaxf(pmax, __shfl_xor(pmax, 32));
            if (__any(pmax - m > 1.0f)) {       // defer-max (T13), log2 units
                const float mn = fmaxf(pmax, m);
                const float corr = exp2f(m - mn);
                l *= corr;
                #pragma unroll
                for (int i = 0; i < 8; ++i) acc[i] *= corr;
                m = mn;
            }
            float p[8];
            #pragma unroll
            for (int sub = 0; sub < 2; ++sub)
                #pragma unroll
                for (int r = 0; r < 4; ++r)
                    p[sub * 4 + r] = exp2f(st[sub][r] - m);   // log2 domain: no mul
            float ps = (p[0] + p[1]) + (p[2] + p[3]) + (p[4] + p[5]) + (p[6] + p[7]);
            ps += __shfl_xor(ps, 16);
            ps += __shfl_xor(ps, 32);
            l += ps;
            bf16x4 pb[2];
            #pragma unroll
            for (int sub = 0; sub < 2; ++sub) {
                union { unsigned int u[2]; bf16x4 v; } pk;
                pk.u[0] = cvtpk_bf16(p[sub * 4 + 0], p[sub * 4 + 1]);
                pk.u[1] = cvtpk_bf16(p[sub * 4 + 2], p[sub * 4 + 3]);
                pb[sub] = pk.v;
            }
            #pragma unroll
            for (int sub = 0; sub < 2; ++sub) {
                const char* vb2 = vtlds + bufi * 9216 + sub * 32 + lg * 8;
                #pragma unroll
                for (int db = 0; db < 8; ++db) {
                    const bf16x4 vf = *reinterpret_cast<const bf16x4*>(vb2 + (db * 16 + lm) * 72);
                    acc[db] = pv_mfma(vf, pb[sub], acc[db]);
                }
            }
        }
        if (havenext) WRITELDS((kt + 1) & 1);
        __syncthreads();
    }
    const float inv = 1.0f / l;
    unsigned short* ob = out + (size_t)(b * S_ + q0w + lm) * qld + h * HD_ + lg * 4;
    #pragma unroll
    for (int db = 0; db < 8; ++db) {
        uint2 o2;
        o2.x = cvtpk_bf16(acc[db][0] * inv, acc[db][1] * inv);
        o2.y = cvtpk_bf16(acc[db][2] * inv, acc[db][3] * inv);
        *reinterpret_cast<uint2*>(ob + db * 16) = o2;
    }
}

// ---------------- silu(g12[:, :3072]) * g12[:, 3072:] -> g12[:, :3072] in place ----------
__global__ __launch_bounds__(256)
void silu_mul_kernel(unsigned short* __restrict__ g, int n4) {
    const int i = blockIdx.x * 256 + threadIdx.x;
    if (i >= n4) return;
    const int r = i / (FF_ / 4);
    const int c = (i - r * (FF_ / 4)) * 4;
    const size_t off = (size_t)r * (2 * FF_) + c;
    const uint2 a = *reinterpret_cast<const uint2*>(g + off);
    const uint2 bv = *reinterpret_cast<const uint2*>(g + off + FF_);
    const unsigned int au[2] = {a.x, a.y}, bu[2] = {bv.x, bv.y};
    unsigned int rr[2];
    #pragma unroll
    for (int j = 0; j < 2; j++) {
        const float a0 = bf2f((unsigned short)(au[j] & 0xffff));
        const float a1 = bf2f((unsigned short)(au[j] >> 16));
        const float b0 = bf2f((unsigned short)(bu[j] & 0xffff));
        const float b1 = bf2f((unsigned short)(bu[j] >> 16));
        const float s0 = a0 / (1.f + __expf(-a0)) * b0;
        const float s1 = a1 / (1.f + __expf(-a1)) * b1;
        rr[j] = ((unsigned int)f2bf(s1) << 16) | (unsigned int)f2bf(s0);
    }
    *reinterpret_cast<uint2*>(g + off) = make_uint2(rr[0], rr[1]);
}

extern "C" void kernel_launch(void* const* d_in, const int* in_sizes, int n_in,
                              void* d_out, int out_size, void* d_ws, size_t ws_size,
                              hipStream_t stream) {
    const float* x    = (const float*)d_in[0];
    const float* cosb = (const float*)d_in[2];
    const float* sinb = (const float*)d_in[3];
    const float* wq   = (const float*)d_in[4];
    const float* wk   = (const float*)d_in[5];
    const float* wv   = (const float*)d_in[6];
    const float* wo   = (const float*)d_in[7];
    const float* fc1  = (const float*)d_in[8];
    const float* fc2  = (const float*)d_in[9];
    const float* fc3  = (const float*)d_in[10];
    const float* n1s  = (const float*)d_in[11];
    const float* n2s  = (const float*)d_in[12];
    const float* qns  = (const float*)d_in[13];
    const float* kns  = (const float*)d_in[14];

    char* ws = (char*)d_ws;
    const int M = B_ * S_;  // 4096
    float* outf = (float*)d_out;
    const float CS = 0.12752409731504826f;   // (1/sqrt(128)) * log2(e)

    // ws layout (bytes), total 106,954,752:
    //  h     @0         8 MiB  (bf16 4096x1024)
    //  qkvb  @8388608   32 MiB (bf16 4096x4096: q [0,2048) k [2048,3072) v [3072,4096))
    //  vtb   @41943040  8 MiB  (bf16 V^T [1024][4096])
    //  g12   @8388608   48 MiB (bf16 4096x6144; aliases qkvb+vtb, dead by fc12)
    //  x2    @58720256  16 MiB (fp32)
    //  wqkvt @75497472  8 MiB  ([wq|wk|wv]^T [4096][1024])
    //  wot   @83886080  4 MiB  f12t @88080384 12 MiB  f3t @100663296 6 MiB
    unsigned short* h     = (unsigned short*)(ws);
    unsigned short* qkvb  = (unsigned short*)(ws + 8388608);
    unsigned short* vtb   = (unsigned short*)(ws + 41943040);
    unsigned short* g12   = (unsigned short*)(ws + 8388608);
    float*          x2    = (float*)(ws + 58720256);
    unsigned short* wqkvt = (unsigned short*)(ws + 75497472);
    unsigned short* wot   = (unsigned short*)(ws + 83886080);
    unsigned short* f12t  = (unsigned short*)(ws + 88080384);
    unsigned short* f3t   = (unsigned short*)(ws + 100663296);

    WTDesc wd;
    wd.src[0] = wq;  wd.dst[0] = wqkvt;                         wd.K[0] = D_;       wd.N[0] = 2048;
    wd.src[1] = wk;  wd.dst[1] = wqkvt + (size_t)2048 * 1024;   wd.K[1] = D_;       wd.N[1] = 1024;
    wd.src[2] = wv;  wd.dst[2] = wqkvt + (size_t)3072 * 1024;   wd.K[2] = D_;       wd.N[2] = 1024;
    wd.src[3] = wo;  wd.dst[3] = wot;                           wd.K[3] = H_ * HD_; wd.N[3] = D_;
    wd.src[4] = fc1; wd.dst[4] = f12t;                          wd.K[4] = D_;       wd.N[4] = FF_;
    wd.src[5] = fc2; wd.dst[5] = f12t + (size_t)3072 * 1024;    wd.K[5] = D_;       wd.N[5] = FF_;
    wd.src[6] = fc3; wd.dst[6] = f3t;                           wd.K[6] = FF_;      wd.N[6] = D_;
    wd.start[0] = 0;
    for (int i = 0; i < 7; ++i)
        wd.start[i + 1] = wd.start[i] + (wd.K[i] / 32) * (wd.N[i] / 32);
    wtrans_all_kernel<<<wd.start[7], 256, 0, stream>>>(wd);

    rmsnorm_kernel<<<M, 256, 0, stream>>>(x, n1s, h);
    gemm256<<<(M / 256) * (4096 / 256), 512, 0, stream>>>(h, wqkvt, qkvb, M, 4096, D_, M / 256);
    vtrans_kernel<<<dim3(M / 32, 1024 / 32), 256, 0, stream>>>(qkvb + 3072, vtb);
    qknorm_rope_kernel<<<dim3(M, H_), 128, 0, stream>>>(qkvb, qns, cosb, sinb, 4096, CS);
    qknorm_rope_kernel<<<dim3(M, KV_), 128, 0, stream>>>(qkvb + 2048, kns, cosb, sinb, 4096, 1.0f);
    fattn_kernel<<<dim3(H_ * B_, S_ / 64), 256, 0, stream>>>(qkvb, qkvb + 2048, vtb, qkvb, 4096, 4096);
    gemm_bt<1><<<dim3(M / 128, D_ / 128), 256, 0, stream>>>(qkvb, wot, x2, x, M, D_, H_ * HD_, 4096);
    rmsnorm_kernel<<<M, 256, 0, stream>>>(x2, n2s, h);
    gemm256<<<(M / 256) * (6144 / 256), 512, 0, stream>>>(h, f12t, g12, M, 6144, D_, M / 256);
    silu_mul_kernel<<<(M * FF_ / 4 + 255) / 256, 256, 0, stream>>>(g12, M * FF_ / 4);
    gemm_bt<1><<<dim3(M / 128, D_ / 128), 256, 0, stream>>>(g12, f3t, outf, x2, M, D_, FF_, 2 * FF_);
}